// Round 3
// baseline (333.649 us; speedup 1.0000x reference)
//
#include <hip/hip_runtime.h>

// Problem constants
#define B_    512
#define N_    64
#define FIN_  128
#define H_    256
#define K_    32
#define S_    4
#define SB_   2048

static constexpr float TINYF = 1.17549435e-38f;
typedef float fx4 __attribute__((ext_vector_type(4)));

// ---------------------------------------------------------------------------
// Threefry-2x32, key = (0, 42), partitionable path: bits(i) = y0^y1 of
// cipher(hi=0, lo=i).
// ---------------------------------------------------------------------------
__device__ __forceinline__ unsigned tf_bits(unsigned lo) {
  const unsigned ks0 = 0u, ks1 = 42u, ks2 = 0x1BD11BF0u;
  unsigned x0 = 0u + ks0;
  unsigned x1 = lo + ks1;
#define TFR(r) { x0 += x1; x1 = (x1 << r) | (x1 >> (32 - r)); x1 ^= x0; }
  TFR(13) TFR(15) TFR(26) TFR(6)
  x0 += ks1; x1 += ks2 + 1u;
  TFR(17) TFR(29) TFR(16) TFR(24)
  x0 += ks2; x1 += ks0 + 2u;
  TFR(13) TFR(15) TFR(26) TFR(6)
  x0 += ks0; x1 += ks1 + 3u;
  TFR(17) TFR(29) TFR(16) TFR(24)
  x0 += ks1; x1 += ks2 + 4u;
  TFR(13) TFR(15) TFR(26) TFR(6)
  x0 += ks2; x1 += ks0 + 5u;
#undef TFR
  return x0 ^ x1;
}

// ---------------------------------------------------------------------------
// Mask dtype auto-detect (0=int32, 1=float32, 2=byte)
// ---------------------------------------------------------------------------
__global__ void k_detect(const unsigned* __restrict__ w, int* __restrict__ flag) {
  __shared__ int s_notint, s_notflt;
  if (threadIdx.x == 0) { s_notint = 0; s_notflt = 0; }
  __syncthreads();
  int ni = 0, nf = 0;
  for (int i = threadIdx.x; i < 8192; i += 256) {
    unsigned v = w[i];
    if (v > 1u) ni = 1;
    if (v != 0u && v != 0x3f800000u) nf = 1;
  }
  if (ni) atomicOr(&s_notint, 1);
  if (nf) atomicOr(&s_notflt, 1);
  __syncthreads();
  if (threadIdx.x == 0) *flag = s_notint ? (s_notflt ? 2 : 1) : 0;
}

__global__ void k_mask(const void* __restrict__ mptr, const int* __restrict__ flag,
                       float* __restrict__ maskf) {
  int i = blockIdx.x * 256 + threadIdx.x;
  if (i >= B_ * N_) return;
  int fl = *flag;
  float r;
  if (fl == 0)      r = ((const int*)mptr)[i] ? 1.0f : 0.0f;
  else if (fl == 1) r = (((const float*)mptr)[i] != 0.0f) ? 1.0f : 0.0f;
  else              r = ((const unsigned char*)mptr)[i] ? 1.0f : 0.0f;
  maskf[i] = r;
}

// ---------------------------------------------------------------------------
// Per-batch prep: Ahat = D^-1/2 (A+I) D^-1/2, neighbor bitmasks.
// ---------------------------------------------------------------------------
__global__ __launch_bounds__(256) void k_prep(const float* __restrict__ adj,
                                              float* __restrict__ Ahat,
                                              unsigned long long* __restrict__ nbr) {
  __shared__ float adjS[4096];
  __shared__ float dis[64];
  int b = blockIdx.x, tid = threadIdx.x;
  const float* ab = adj + (size_t)b * 4096;
  for (int i = tid; i < 4096; i += 256) adjS[i] = ab[i];
  __syncthreads();
  if (tid < 64) {
    float s = 0.0f;
    unsigned long long m = 0ull;
    for (int j = 0; j < 64; ++j) {
      float v = adjS[j * 64 + tid];            // symmetric
      s += (j == tid) ? (v + 1.0f) : v;
      if (v != 0.0f) m |= (1ull << j);
    }
    dis[tid] = 1.0f / sqrtf(fmaxf(s, 1.0f));
    nbr[b * 64 + tid] = m;
  }
  __syncthreads();
  float* Ab = Ahat + (size_t)b * 4096;
  for (int i = tid; i < 4096; i += 256) {
    int r = i >> 6, c = i & 63;
    float a = adjS[i] + ((r == c) ? 1.0f : 0.0f);
    Ab[i] = (dis[r] * a) * dis[c];
  }
}

// ---------------------------------------------------------------------------
// Centroid squared norms (same fp32 order as round-0 cacc: f = l8 + 8m, then
// xor-tree 1,2,4 over the 8-lane group).
// ---------------------------------------------------------------------------
__global__ void k_cc(const float* __restrict__ cen, float* __restrict__ ccbuf) {
  int tid = threadIdx.x;
  int k = tid >> 3, l8 = tid & 7;
  float s = 0.0f;
  for (int m = 0; m < 32; ++m) { float v = cen[k * 256 + l8 + 8 * m]; s += v * v; }
#pragma unroll
  for (int d = 1; d < 8; d <<= 1) s += __shfl_xor(s, d, 64);
  if (l8 == 0) ccbuf[k] = s;
}

// ---------------------------------------------------------------------------
// Fused layer: per batch b, out = relu(maskf * (Ahat @ (A@W) + bias)).
// 64x256 tile, 8x8 micro (split cols tx*4 and 128+tx*4), double-buffered K.
// LDS ~122 KB -> 1 block/CU, 4 waves.
// ---------------------------------------------------------------------------
__global__ __launch_bounds__(256) void k_layer(const float* __restrict__ A,
                                               const float* __restrict__ W,
                                               const float* __restrict__ bias,
                                               const float* __restrict__ Ahat,
                                               const float* __restrict__ maskf,
                                               float* __restrict__ out, int K) {
  __shared__ float As[2][16][64];
  __shared__ float Bs[2][16][256];
  __shared__ float Ts[64][256];
  __shared__ float Aa[64][68];
  __shared__ float biaS[256];
  __shared__ float maskS[64];
  int b = blockIdx.x, tid = threadIdx.x;
  int ty = tid >> 5, tx = tid & 31;            // rows ty*8..+8, cols tx*4 / 128+tx*4
  const float* Ab = A + (size_t)b * 64 * K;

  for (int i = tid; i < 4096; i += 256) Aa[i >> 6][i & 63] = Ahat[(size_t)b * 4096 + i];
  biaS[tid] = bias[tid];
  if (tid < 64) maskS[tid] = maskf[b * 64 + tid];

  // prologue: tile 0
  {
    int ar = tid >> 2, ac = (tid & 3) * 4;
    float4 av = *(const float4*)&Ab[(size_t)ar * K + ac];
    As[0][ac + 0][ar] = av.x; As[0][ac + 1][ar] = av.y;
    As[0][ac + 2][ar] = av.z; As[0][ac + 3][ar] = av.w;
#pragma unroll
    for (int u = 0; u < 4; ++u) {
      int flat = tid * 4 + u * 1024;
      int r = flat >> 8, c = flat & 255;
      *(float4*)&Bs[0][r][c] = *(const float4*)&W[(size_t)r * 256 + c];
    }
  }
  __syncthreads();

  float acc[8][8] = {};
  int nsteps = K >> 4;
  int ar = tid >> 2, ac = (tid & 3) * 4;
  for (int s = 0; s < nsteps; ++s) {
    int cur = s & 1, nxt = cur ^ 1;
    float4 av; float4 bv[4];
    bool pf = (s + 1 < nsteps);
    if (pf) {
      int k0 = (s + 1) * 16;
      av = *(const float4*)&Ab[(size_t)ar * K + k0 + ac];
#pragma unroll
      for (int u = 0; u < 4; ++u) {
        int flat = tid * 4 + u * 1024;
        int r = flat >> 8, c = flat & 255;
        bv[u] = *(const float4*)&W[(size_t)(k0 + r) * 256 + c];
      }
    }
#pragma unroll
    for (int kk = 0; kk < 16; ++kk) {
      float a8[8], b8[8];
      *(float4*)&a8[0] = *(const float4*)&As[cur][kk][ty * 8];
      *(float4*)&a8[4] = *(const float4*)&As[cur][kk][ty * 8 + 4];
      *(float4*)&b8[0] = *(const float4*)&Bs[cur][kk][tx * 4];
      *(float4*)&b8[4] = *(const float4*)&Bs[cur][kk][128 + tx * 4];
#pragma unroll
      for (int i = 0; i < 8; ++i)
#pragma unroll
        for (int j = 0; j < 8; ++j) acc[i][j] += a8[i] * b8[j];
    }
    if (pf) {
      As[nxt][ac + 0][ar] = av.x; As[nxt][ac + 1][ar] = av.y;
      As[nxt][ac + 2][ar] = av.z; As[nxt][ac + 3][ar] = av.w;
#pragma unroll
      for (int u = 0; u < 4; ++u) {
        int flat = tid * 4 + u * 1024;
        int r = flat >> 8, c = flat & 255;
        *(float4*)&Bs[nxt][r][c] = bv[u];
      }
    }
    __syncthreads();
  }

  // stage XW tile
#pragma unroll
  for (int i = 0; i < 8; ++i) {
    *(float4*)&Ts[ty * 8 + i][tx * 4]       = *(float4*)&acc[i][0];
    *(float4*)&Ts[ty * 8 + i][128 + tx * 4] = *(float4*)&acc[i][4];
  }
  __syncthreads();

  // agg: reuse acc registers
#pragma unroll
  for (int i = 0; i < 8; ++i)
#pragma unroll
    for (int j = 0; j < 8; ++j) acc[i][j] = 0.0f;

  for (int j0 = 0; j0 < 64; j0 += 4) {
    float4 t1[4], t2[4], a4[8];
#pragma unroll
    for (int q = 0; q < 4; ++q) {
      t1[q] = *(const float4*)&Ts[j0 + q][tx * 4];
      t2[q] = *(const float4*)&Ts[j0 + q][128 + tx * 4];
    }
#pragma unroll
    for (int i = 0; i < 8; ++i) a4[i] = *(const float4*)&Aa[ty * 8 + i][j0];
#pragma unroll
    for (int i = 0; i < 8; ++i) {
      float aw[4] = {a4[i].x, a4[i].y, a4[i].z, a4[i].w};
#pragma unroll
      for (int q = 0; q < 4; ++q) {
        acc[i][0] += aw[q] * t1[q].x; acc[i][1] += aw[q] * t1[q].y;
        acc[i][2] += aw[q] * t1[q].z; acc[i][3] += aw[q] * t1[q].w;
        acc[i][4] += aw[q] * t2[q].x; acc[i][5] += aw[q] * t2[q].y;
        acc[i][6] += aw[q] * t2[q].z; acc[i][7] += aw[q] * t2[q].w;
      }
    }
  }

  // epilogue
#pragma unroll
  for (int i = 0; i < 8; ++i) {
    int r = ty * 8 + i;
    float m = maskS[r];
    float4 r1, r2;
    r1.x = fmaxf((acc[i][0] + biaS[tx * 4 + 0]) * m, 0.0f);
    r1.y = fmaxf((acc[i][1] + biaS[tx * 4 + 1]) * m, 0.0f);
    r1.z = fmaxf((acc[i][2] + biaS[tx * 4 + 2]) * m, 0.0f);
    r1.w = fmaxf((acc[i][3] + biaS[tx * 4 + 3]) * m, 0.0f);
    r2.x = fmaxf((acc[i][4] + biaS[128 + tx * 4 + 0]) * m, 0.0f);
    r2.y = fmaxf((acc[i][5] + biaS[128 + tx * 4 + 1]) * m, 0.0f);
    r2.z = fmaxf((acc[i][6] + biaS[128 + tx * 4 + 2]) * m, 0.0f);
    r2.w = fmaxf((acc[i][7] + biaS[128 + tx * 4 + 3]) * m, 0.0f);
    *(float4*)&out[((size_t)b * 64 + r) * 256 + tx * 4]       = r1;
    *(float4*)&out[((size_t)b * 64 + r) * 256 + 128 + tx * 4] = r2;
  }
}

// ---------------------------------------------------------------------------
// Per-batch cdist + softmin + Gumbel-max sampling. D[64,32] GEMM with
// f-major LDS operands (conflict-free b128), then per-node softmax + 4 draws.
// ---------------------------------------------------------------------------
__global__ __launch_bounds__(256) void k_cdist(const float* __restrict__ h,
                                               const float* __restrict__ cen,
                                               const float* __restrict__ ccbuf,
                                               int* __restrict__ conc,
                                               float* __restrict__ pp) {
  __shared__ float hsT[256][68];    // 69.6 KB, f-major
  __shared__ float cenT[256][36];   // 36.9 KB, f-major (lg aliased after GEMM)
  __shared__ float hhs[64];
  __shared__ float mxs[64];
  __shared__ float lgden[64];
  float (*lg)[33] = (float(*)[33])cenT;

  int b = blockIdx.x, tid = threadIdx.x;
  const float* hb = h + (size_t)b * 16384;
  for (int g = tid; g < 4096; g += 256) {
    float4 v = *(const float4*)&hb[g * 4];
    int n = g >> 6, f = (g & 63) * 4;
    hsT[f + 0][n] = v.x; hsT[f + 1][n] = v.y; hsT[f + 2][n] = v.z; hsT[f + 3][n] = v.w;
  }
  {
    int k = tid & 31, f0 = (tid >> 5) * 32;
    for (int j = 0; j < 32; ++j) cenT[f0 + j][k] = cen[k * 256 + f0 + j];
  }
  __syncthreads();

  // hh on threads 128..191 (parallel with GEMM waves 0-1)
  if (tid >= 128 && tid < 192) {
    int n = tid - 128;
    float s = 0.0f;
    for (int f = 0; f < 256; ++f) { float v = hsT[f][n]; s += v * v; }
    hhs[n] = s;
  }

  float acc[4][4] = {};
  int ty = (tid >> 3) & 15, tx = tid & 7;      // n0 = ty*4, k0 = tx*4
  if (tid < 128) {
    for (int f = 0; f < 256; ++f) {
      float4 a4 = *(const float4*)&hsT[f][ty * 4];
      float4 b4 = *(const float4*)&cenT[f][tx * 4];
      acc[0][0] += a4.x * b4.x; acc[0][1] += a4.x * b4.y; acc[0][2] += a4.x * b4.z; acc[0][3] += a4.x * b4.w;
      acc[1][0] += a4.y * b4.x; acc[1][1] += a4.y * b4.y; acc[1][2] += a4.y * b4.z; acc[1][3] += a4.y * b4.w;
      acc[2][0] += a4.z * b4.x; acc[2][1] += a4.z * b4.y; acc[2][2] += a4.z * b4.z; acc[2][3] += a4.z * b4.w;
      acc[3][0] += a4.w * b4.x; acc[3][1] += a4.w * b4.y; acc[3][2] += a4.w * b4.z; acc[3][3] += a4.w * b4.w;
    }
  }
  __syncthreads();          // GEMM reads of cenT done -> lg may alias

  if (tid < 128) {
    float cc0 = ccbuf[tx * 4 + 0], cc1 = ccbuf[tx * 4 + 1];
    float cc2 = ccbuf[tx * 4 + 2], cc3 = ccbuf[tx * 4 + 3];
#pragma unroll
    for (int i = 0; i < 4; ++i) {
      int n = ty * 4 + i;
      float hh = hhs[n];
      lg[n][tx * 4 + 0] = -10.0f * sqrtf(fmaxf((hh + cc0) - 2.0f * acc[i][0], 1e-12f));
      lg[n][tx * 4 + 1] = -10.0f * sqrtf(fmaxf((hh + cc1) - 2.0f * acc[i][1], 1e-12f));
      lg[n][tx * 4 + 2] = -10.0f * sqrtf(fmaxf((hh + cc2) - 2.0f * acc[i][2], 1e-12f));
      lg[n][tx * 4 + 3] = -10.0f * sqrtf(fmaxf((hh + cc3) - 2.0f * acc[i][3], 1e-12f));
    }
  }
  __syncthreads();

  if (tid < 64) {
    float mx = -1e30f;
    for (int k = 0; k < 32; ++k) mx = fmaxf(mx, lg[tid][k]);
    float den = 0.0f;
    for (int k = 0; k < 32; ++k) den += expf(lg[tid][k] - mx);
    mxs[tid] = mx; lgden[tid] = logf(den);
  }
  __syncthreads();
  for (int p = tid; p < 2048; p += 256) {
    int n = p >> 5, k = p & 31;
    lg[n][k] = (lg[n][k] - mxs[n]) - lgden[n];   // logp
  }
  __syncthreads();

  int hw = tid >> 5, k = tid & 31;
  for (int pass = 0; pass < 8; ++pass) {
    int n = hw * 8 + pass;
    float lp = lg[n][k];
#pragma unroll
    for (int s4 = 0; s4 < 4; ++s4) {
      unsigned flat = (unsigned)(s4 * 32768 + b * 64 + n) * 32u + (unsigned)k;
      unsigned bits = tf_bits(flat);
      float fu = __uint_as_float((bits >> 9) | 0x3f800000u) - 1.0f;
      float u = fmaxf(TINYF, fu * (1.0f - TINYF) + TINYF);
      float g = -logf(-logf(u));
      float v = lp + g;
      int bi = k;
#pragma unroll
      for (int d = 1; d < 32; d <<= 1) {        // max, first-index ties
        float ov = __shfl_xor(v, d, 32);
        int oi = __shfl_xor(bi, d, 32);
        if (ov > v || (ov == v && oi < bi)) { v = ov; bi = oi; }
      }
      if (k == 0) {
        conc[s4 * 32768 + b * 64 + n] = bi;
        pp[s4 * 32768 + b * 64 + n] = expf(lg[n][bi]);
      }
    }
  }
}

// ---------------------------------------------------------------------------
// Per (s,b): CC min-label fixpoint + graph_prob + labels + cluster bitmasks
// + pooled binarized adjacency. 256 threads (race-safe chg protocol).
// ---------------------------------------------------------------------------
__global__ __launch_bounds__(256) void k_post(const int* __restrict__ conc,
                                              const float* __restrict__ pp,
                                              const float* __restrict__ maskf,
                                              const unsigned long long* __restrict__ nbr,
                                              unsigned long long* __restrict__ clmask,
                                              float* __restrict__ out_gp,
                                              float* __restrict__ out_lab,
                                              float* __restrict__ out_newadj) {
  int sb = blockIdx.x, b = sb & 511, tid = threadIdx.x;
  __shared__ int cs[64];
  __shared__ int lab[64];
  __shared__ unsigned long long sm_[64];
  __shared__ unsigned long long nbs[64];
  __shared__ float o[4096];
  __shared__ int chg;

  for (int i = tid; i < 4096; i += 256) o[i] = 0.0f;
  bool mk = false;
  if (tid < 64) {
    cs[tid] = conc[sb * 64 + tid];
    nbs[tid] = nbr[b * 64 + tid];
    mk = maskf[b * 64 + tid] != 0.0f;
    lab[tid] = tid + 1;
  }
  if (tid == 0) chg = 0;
  __syncthreads();
  if (tid < 64) {
    unsigned long long nb = nbs[tid], s = 0ull;
    int c = cs[tid];
    while (nb) { int j = __ffsll(nb) - 1; if (cs[j] == c) s |= (1ull << j); nb &= nb - 1; }
    sm_[tid] = s;
  }
  __syncthreads();
  for (int it = 0; it < 64; ++it) {
    int m = 0;
    if (tid < 64) {
      m = lab[tid];
      unsigned long long t = sm_[tid];
      while (t) { int j = __ffsll(t) - 1; m = min(m, lab[j]); t &= t - 1; }
    }
    __syncthreads();                 // all reads of lab done
    if (tid < 64 && m < lab[tid]) { lab[tid] = m; chg = 1; }
    __syncthreads();                 // writes visible
    if (chg == 0) break;
    __syncthreads();                 // all have read chg
    if (tid == 0) chg = 0;
  }
  // labels, graph_prob, clmask (reuse cs for final labels)
  if (tid < 64) {
    int lf = mk ? lab[tid] : 0;
    cs[tid] = lf;
    out_lab[sb * 64 + tid] = (float)lf;
    float pv = mk ? pp[sb * 64 + tid] : 1.0f;
#pragma unroll
    for (int d = 1; d < 64; d <<= 1) pv *= __shfl_xor(pv, d, 64);
    if (tid == 0) out_gp[sb] = pv;
  }
  __syncthreads();
  if (tid < 64) {
    unsigned long long cm = 0ull;
    for (int j = 0; j < 64; ++j)
      if (cs[j] == tid + 1) cm |= (1ull << j);
    clmask[sb * 64 + tid] = cm;
  }
  // pooled adjacency
  for (int p = tid; p < 4096; p += 256) {
    int i = p >> 6, j = p & 63;
    int li = cs[i], lj = cs[j];
    if (li > 0 && lj > 0 && ((nbs[i] >> j) & 1ull))
      o[(li - 1) * 64 + (lj - 1)] = 1.0f;       // benign same-value races
  }
  __syncthreads();
  float* dst = out_newadj + (size_t)sb * 4096;
  for (int i = tid; i < 1024; i += 256) {
    fx4 v = ((const fx4*)o)[i];
    __builtin_nontemporal_store(v, (fx4*)dst + i);
  }
}

// ---------------------------------------------------------------------------
// new_x[sb,c,:] = mean over cluster-(c+1) members of h[b]. float4 + NT stores.
// ---------------------------------------------------------------------------
__global__ __launch_bounds__(256) void k_newx(const float* __restrict__ h,
                                              const unsigned long long* __restrict__ clmask,
                                              float* __restrict__ out_newx) {
  int sb = blockIdx.x, b = sb & 511;
  int q = threadIdx.x & 63, cp = threadIdx.x >> 6;
  const float* hb = h + (size_t)b * 16384;
  for (int step = 0; step < 16; ++step) {
    int c = cp * 16 + step;
    unsigned long long m = clmask[sb * 64 + c];
    float4 acc = make_float4(0.f, 0.f, 0.f, 0.f);
    unsigned long long t = m;
    while (t) {
      int j = __ffsll(t) - 1; t &= t - 1;
      float4 v = *(const float4*)&hb[j * 256 + q * 4];
      acc.x += v.x; acc.y += v.y; acc.z += v.z; acc.w += v.w;
    }
    int cnt = __popcll(m);
    float cf = (float)(cnt > 0 ? cnt : 1);
    fx4 r;
    r.x = acc.x / cf; r.y = acc.y / cf; r.z = acc.z / cf; r.w = acc.w / cf;
    __builtin_nontemporal_store(r, (fx4*)&out_newx[((size_t)sb * 64 + c) * 256 + q * 4]);
  }
}

// ---------------------------------------------------------------------------
extern "C" void kernel_launch(void* const* d_in, const int* in_sizes, int n_in,
                              void* d_out, int out_size, void* d_ws, size_t ws_size,
                              hipStream_t stream) {
  (void)in_sizes; (void)n_in; (void)out_size; (void)ws_size;
  const float* x   = (const float*)d_in[0];
  const float* adj = (const float*)d_in[1];
  const void*  mp  = d_in[2];
  const float* W1  = (const float*)d_in[3];
  const float* b1  = (const float*)d_in[4];
  const float* W2  = (const float*)d_in[5];
  const float* b2  = (const float*)d_in[6];
  const float* cen = (const float*)d_in[7];

  char* ws = (char*)d_ws;
  float* Ahat = (float*)ws;                                            // 8 MB
  float* bufA = (float*)(ws + (size_t)(8u  << 20));                    // 32 MB (h1)
  float* bufB = (float*)(ws + (size_t)(40u << 20));                    // 32 MB (h)
  unsigned long long* nbr = (unsigned long long*)(ws + (size_t)(72u << 20));     // 256 KB
  float* maskf = (float*)(ws + (size_t)(72u << 20) + (256u  << 10));   // 128 KB
  int*   conc  = (int*)  (ws + (size_t)(72u << 20) + (384u  << 10));   // 512 KB
  float* pp    = (float*)(ws + (size_t)(72u << 20) + (896u  << 10));   // 512 KB
  unsigned long long* clmask = (unsigned long long*)(ws + (size_t)(72u << 20) + (1408u << 10)); // 1 MB
  float* ccbuf = (float*)(ws + (size_t)(72u << 20) + (2432u << 10));
  int*   flag  = (int*)  (ws + (size_t)(72u << 20) + (2436u << 10));

  float* out        = (float*)d_out;
  float* out_newx   = out;                 // 2048*64*256
  float* out_newadj = out + 33554432;      // 2048*64*64
  float* out_gp     = out + 41943040;      // 2048
  float* out_lab    = out + 41945088;      // 2048*64

  hipLaunchKernelGGL(k_detect, dim3(1), dim3(256), 0, stream, (const unsigned*)mp, flag);
  hipLaunchKernelGGL(k_mask,   dim3(128), dim3(256), 0, stream, mp, flag, maskf);
  hipLaunchKernelGGL(k_prep,   dim3(512), dim3(256), 0, stream, adj, Ahat, nbr);
  hipLaunchKernelGGL(k_cc,     dim3(1), dim3(256), 0, stream, cen, ccbuf);
  hipLaunchKernelGGL(k_layer,  dim3(512), dim3(256), 0, stream, x,    W1, b1, Ahat, maskf, bufA, 128);
  hipLaunchKernelGGL(k_layer,  dim3(512), dim3(256), 0, stream, bufA, W2, b2, Ahat, maskf, bufB, 256);
  hipLaunchKernelGGL(k_cdist,  dim3(512), dim3(256), 0, stream, bufB, cen, ccbuf, conc, pp);
  hipLaunchKernelGGL(k_post,   dim3(2048), dim3(256), 0, stream, conc, pp, maskf, nbr,
                     clmask, out_gp, out_lab, out_newadj);
  hipLaunchKernelGGL(k_newx,   dim3(2048), dim3(256), 0, stream, bufB, clmask, out_newx);
}

// Round 4
// 205.096 us; speedup vs baseline: 1.6268x; 1.6268x over previous
//
#include <hip/hip_runtime.h>

// Problem constants
#define B_    512
#define SB_   2048

static constexpr float TINYF = 1.17549435e-38f;
typedef float fx4  __attribute__((ext_vector_type(4)));
typedef short bf16x8 __attribute__((ext_vector_type(8)));
typedef float f32x4 __attribute__((ext_vector_type(4)));

// ---------------------------------------------------------------------------
// Threefry-2x32, key = (0, 42), partitionable path: bits(i) = y0^y1 of
// cipher(hi=0, lo=i).
// ---------------------------------------------------------------------------
__device__ __forceinline__ unsigned tf_bits(unsigned lo) {
  const unsigned ks0 = 0u, ks1 = 42u, ks2 = 0x1BD11BF0u;
  unsigned x0 = 0u + ks0;
  unsigned x1 = lo + ks1;
#define TFR(r) { x0 += x1; x1 = (x1 << r) | (x1 >> (32 - r)); x1 ^= x0; }
  TFR(13) TFR(15) TFR(26) TFR(6)
  x0 += ks1; x1 += ks2 + 1u;
  TFR(17) TFR(29) TFR(16) TFR(24)
  x0 += ks2; x1 += ks0 + 2u;
  TFR(13) TFR(15) TFR(26) TFR(6)
  x0 += ks0; x1 += ks1 + 3u;
  TFR(17) TFR(29) TFR(16) TFR(24)
  x0 += ks1; x1 += ks2 + 4u;
  TFR(13) TFR(15) TFR(26) TFR(6)
  x0 += ks2; x1 += ks0 + 5u;
#undef TFR
  return x0 ^ x1;
}

// Exact fp32 -> 3x bf16 split (truncation; v == v1+v2+v3 exactly for normals)
__device__ __forceinline__ void split3(float v, unsigned& b1, unsigned& b2, unsigned& b3) {
  unsigned u1 = __float_as_uint(v) & 0xFFFF0000u;
  float r1 = v - __uint_as_float(u1);
  unsigned u2 = __float_as_uint(r1) & 0xFFFF0000u;
  float r2 = r1 - __uint_as_float(u2);
  unsigned u3 = __float_as_uint(r2) & 0xFFFF0000u;
  b1 = u1 >> 16; b2 = u2 >> 16; b3 = u3 >> 16;
}

// 8-product split accumulation (drops only a3*b3 ~ 2^-32)
#define MF8(A0, A1, A2, Bv0, Bv1, Bv2, ACC)                                   \
  ACC = __builtin_amdgcn_mfma_f32_16x16x32_bf16(A0, Bv0, ACC, 0, 0, 0);       \
  ACC = __builtin_amdgcn_mfma_f32_16x16x32_bf16(A0, Bv1, ACC, 0, 0, 0);       \
  ACC = __builtin_amdgcn_mfma_f32_16x16x32_bf16(A1, Bv0, ACC, 0, 0, 0);       \
  ACC = __builtin_amdgcn_mfma_f32_16x16x32_bf16(A0, Bv2, ACC, 0, 0, 0);       \
  ACC = __builtin_amdgcn_mfma_f32_16x16x32_bf16(A1, Bv1, ACC, 0, 0, 0);       \
  ACC = __builtin_amdgcn_mfma_f32_16x16x32_bf16(A2, Bv0, ACC, 0, 0, 0);       \
  ACC = __builtin_amdgcn_mfma_f32_16x16x32_bf16(A1, Bv2, ACC, 0, 0, 0);       \
  ACC = __builtin_amdgcn_mfma_f32_16x16x32_bf16(A2, Bv1, ACC, 0, 0, 0);

// ---------------------------------------------------------------------------
// Mask dtype auto-detect (0=int32, 1=float32, 2=byte)
// ---------------------------------------------------------------------------
__global__ void k_detect(const unsigned* __restrict__ w, int* __restrict__ flag) {
  __shared__ int s_notint, s_notflt;
  if (threadIdx.x == 0) { s_notint = 0; s_notflt = 0; }
  __syncthreads();
  int ni = 0, nf = 0;
  for (int i = threadIdx.x; i < 8192; i += 256) {
    unsigned v = w[i];
    if (v > 1u) ni = 1;
    if (v != 0u && v != 0x3f800000u) nf = 1;
  }
  if (ni) atomicOr(&s_notint, 1);
  if (nf) atomicOr(&s_notflt, 1);
  __syncthreads();
  if (threadIdx.x == 0) *flag = s_notint ? (s_notflt ? 2 : 1) : 0;
}

__global__ void k_mask(const void* __restrict__ mptr, const int* __restrict__ flag,
                       float* __restrict__ maskf) {
  int i = blockIdx.x * 256 + threadIdx.x;
  if (i >= B_ * 64) return;
  int fl = *flag;
  float r;
  if (fl == 0)      r = ((const int*)mptr)[i] ? 1.0f : 0.0f;
  else if (fl == 1) r = (((const float*)mptr)[i] != 0.0f) ? 1.0f : 0.0f;
  else              r = ((const unsigned char*)mptr)[i] ? 1.0f : 0.0f;
  maskf[i] = r;
}

// ---------------------------------------------------------------------------
// Per-batch prep: Ahat = D^-1/2 (A+I) D^-1/2 -> split planes in MFMA-frag
// layout Ahat3[b][s][m][g][i][jj] (j = 16*(2m+(jj>>2)) + 4g + (jj&3)),
// plus neighbor bitmasks.
// ---------------------------------------------------------------------------
__global__ __launch_bounds__(256) void k_prep(const float* __restrict__ adj,
                                              unsigned short* __restrict__ Ahat3,
                                              unsigned long long* __restrict__ nbr) {
  __shared__ float adjS[4096];
  __shared__ float AhS[64][65];
  __shared__ float dis[64];
  int b = blockIdx.x, tid = threadIdx.x;
  const float* ab = adj + (size_t)b * 4096;
  for (int i = tid; i < 4096; i += 256) adjS[i] = ab[i];
  __syncthreads();
  if (tid < 64) {
    float s = 0.0f;
    unsigned long long m = 0ull;
    for (int j = 0; j < 64; ++j) {
      float v = adjS[j * 64 + tid];            // symmetric
      s += (j == tid) ? (v + 1.0f) : v;
      if (v != 0.0f) m |= (1ull << j);
    }
    dis[tid] = 1.0f / sqrtf(fmaxf(s, 1.0f));
    nbr[b * 64 + tid] = m;
  }
  __syncthreads();
  for (int i = tid; i < 4096; i += 256) {
    int r = i >> 6, c = i & 63;
    float a = adjS[i] + ((r == c) ? 1.0f : 0.0f);
    AhS[r][c] = (dis[r] * a) * dis[c];
  }
  __syncthreads();
  unsigned short* dst = Ahat3 + (size_t)b * 12288;
  for (int ch = tid; ch < 1536; ch += 256) {
    int i = ch & 63, g = (ch >> 6) & 3, m = (ch >> 8) & 1, s = ch >> 9;
    bf16x8 hv;
#pragma unroll
    for (int jj = 0; jj < 8; ++jj) {
      int j = 16 * (2 * m + (jj >> 2)) + 4 * g + (jj & 3);
      unsigned h1, h2, h3;
      split3(AhS[i][j], h1, h2, h3);
      unsigned hh = (s == 0) ? h1 : ((s == 1) ? h2 : h3);
      hv[jj] = (short)hh;
    }
    *(bf16x8*)&dst[(size_t)ch * 8] = hv;
  }
}

// ---------------------------------------------------------------------------
// W -> split planes in frag layout: Wg[s][ks][g][n][jj] = split_s(W[ks*32+g*8+jj][n])
// grid 144: bi<48 -> W1 (nk=4), else W2 (nk=8). 256 threads = n.
// ---------------------------------------------------------------------------
__global__ void k_wsplit(const float* __restrict__ W1, const float* __restrict__ W2,
                         unsigned short* __restrict__ Wg1, unsigned short* __restrict__ Wg2) {
  int bi = blockIdx.x, n = threadIdx.x;
  const float* W; unsigned short* Wg; int nk, s, ks, g;
  if (bi < 48) { W = W1; Wg = Wg1; nk = 4; s = bi >> 4; ks = (bi >> 2) & 3; g = bi & 3; }
  else { int t = bi - 48; W = W2; Wg = Wg2; nk = 8; s = t >> 5; ks = (t >> 2) & 7; g = t & 3; }
  bf16x8 hv;
#pragma unroll
  for (int jj = 0; jj < 8; ++jj) {
    float v = W[(size_t)(ks * 32 + g * 8 + jj) * 256 + n];
    unsigned h1, h2, h3;
    split3(v, h1, h2, h3);
    unsigned hh = (s == 0) ? h1 : ((s == 1) ? h2 : h3);
    hv[jj] = (short)hh;
  }
  *(bf16x8*)&Wg[((((size_t)s * nk + ks) * 4 + g) * 256 + n) * 8] = hv;
}

// ---------------------------------------------------------------------------
// Centroid squared norms (round-0 fp32 order).
// ---------------------------------------------------------------------------
__global__ void k_cc(const float* __restrict__ cen, float* __restrict__ ccbuf) {
  int tid = threadIdx.x;
  int k = tid >> 3, l8 = tid & 7;
  float s = 0.0f;
  for (int m = 0; m < 32; ++m) { float v = cen[k * 256 + l8 + 8 * m]; s += v * v; }
#pragma unroll
  for (int d = 1; d < 8; d <<= 1) s += __shfl_xor(s, d, 64);
  if (l8 == 0) ccbuf[k] = s;
}

// ---------------------------------------------------------------------------
// MFMA layer: out = relu(maskf * (Ahat @ (A @ W) + bias)), exact ref order,
// fp32 emulated via 3-way bf16 split (8 products). Per-batch block, 4 waves,
// wave w owns output cols 64w..64w+63. GEMM#1 acc converts in-register to
// GEMM#2 B-frags via the position-bijection trick. LDS: only A-planes (25 KB).
// ---------------------------------------------------------------------------
__global__ __launch_bounds__(256) void k_layer(const float* __restrict__ A,
                                               const unsigned short* __restrict__ Wg,
                                               const float* __restrict__ bias,
                                               const unsigned short* __restrict__ Ahat3,
                                               const float* __restrict__ maskf,
                                               float* __restrict__ out, int nk) {
  __shared__ unsigned short Ap[2][3][2112];   // [buf][split][g*528 + row*8 + jj]
  __shared__ float biaS[256];
  __shared__ float maskS[64];
  int b = blockIdx.x, tid = threadIdx.x;
  int w = tid >> 6, l = tid & 63;
  int l15 = l & 15, lg = l >> 4;
  int K = nk * 32;
  const float* Ab = A + (size_t)b * 64 * K;
  biaS[tid] = bias[tid];
  if (tid < 64) maskS[tid] = maskf[b * 64 + tid];

  int srow = tid >> 2, sg = tid & 3;
  const float* sp = Ab + (size_t)srow * K + sg * 8;

  // stage K-step 0 into buffer 0
  {
    float4 v0 = *(const float4*)(sp);
    float4 v1 = *(const float4*)(sp + 4);
    float vv[8] = {v0.x, v0.y, v0.z, v0.w, v1.x, v1.y, v1.z, v1.w};
    bf16x8 p1, p2, p3;
#pragma unroll
    for (int jj = 0; jj < 8; ++jj) {
      unsigned h1, h2, h3; split3(vv[jj], h1, h2, h3);
      p1[jj] = (short)h1; p2[jj] = (short)h2; p3[jj] = (short)h3;
    }
    int off = sg * 528 + srow * 8;
    *(bf16x8*)&Ap[0][0][off] = p1;
    *(bf16x8*)&Ap[0][1][off] = p2;
    *(bf16x8*)&Ap[0][2][off] = p3;
  }
  __syncthreads();

  f32x4 acc1[4][4];
#pragma unroll
  for (int q = 0; q < 4; ++q)
#pragma unroll
    for (int c = 0; c < 4; ++c) acc1[q][c] = (f32x4){0.f, 0.f, 0.f, 0.f};

  const size_t wss = (size_t)nk * 8192;  // split-plane stride in Wg (shorts)

  for (int ks = 0; ks < nk; ++ks) {
    int cur = ks & 1;
    float4 v0, v1;
    bool pf = (ks + 1 < nk);
    if (pf) {
      v0 = *(const float4*)(sp + (ks + 1) * 32);
      v1 = *(const float4*)(sp + (ks + 1) * 32 + 4);
    }
    // a-frags from LDS
    bf16x8 af[4][3];
#pragma unroll
    for (int q = 0; q < 4; ++q) {
      int off = lg * 528 + (16 * q + l15) * 8;
#pragma unroll
      for (int s = 0; s < 3; ++s) af[q][s] = *(const bf16x8*)&Ap[cur][s][off];
    }
    // b-frags from global Wg (L2-resident) + MFMA
#pragma unroll
    for (int c = 0; c < 4; ++c) {
      size_t wbase = (((size_t)ks * 4 + lg) * 256 + (64 * w + 16 * c + l15)) * 8;
      bf16x8 b0 = *(const bf16x8*)&Wg[wbase];
      bf16x8 b1 = *(const bf16x8*)&Wg[wbase + wss];
      bf16x8 b2 = *(const bf16x8*)&Wg[wbase + 2 * wss];
#pragma unroll
      for (int q = 0; q < 4; ++q) {
        MF8(af[q][0], af[q][1], af[q][2], b0, b1, b2, acc1[q][c]);
      }
    }
    if (pf) {
      float vv[8] = {v0.x, v0.y, v0.z, v0.w, v1.x, v1.y, v1.z, v1.w};
      bf16x8 p1, p2, p3;
#pragma unroll
      for (int jj = 0; jj < 8; ++jj) {
        unsigned h1, h2, h3; split3(vv[jj], h1, h2, h3);
        p1[jj] = (short)h1; p2[jj] = (short)h2; p3[jj] = (short)h3;
      }
      int off = sg * 528 + srow * 8;
      *(bf16x8*)&Ap[cur ^ 1][0][off] = p1;
      *(bf16x8*)&Ap[cur ^ 1][1][off] = p2;
      *(bf16x8*)&Ap[cur ^ 1][2][off] = p3;
    }
    __syncthreads();
  }

  // GEMM#2: out = Ahat @ T. T-frags built in-register from acc1:
  // lane's acc1[q][c][r] holds T[16q + 4*lg + r][n]; choose position map
  // j(t,jj) = 16*(2m+(jj>>2)) + 4t + (jj&3)  (q = 2m + (jj>>2), r = jj&3).
  f32x4 acc2[4][4];
#pragma unroll
  for (int q = 0; q < 4; ++q)
#pragma unroll
    for (int c = 0; c < 4; ++c) acc2[q][c] = (f32x4){0.f, 0.f, 0.f, 0.f};

  const unsigned short* Ah = Ahat3 + (size_t)b * 12288;
#pragma unroll
  for (int m = 0; m < 2; ++m) {
    bf16x8 bfr[4][3];
#pragma unroll
    for (int c = 0; c < 4; ++c) {
#pragma unroll
      for (int jj = 0; jj < 8; ++jj) {
        int q = 2 * m + (jj >> 2), r = jj & 3;
        unsigned h1, h2, h3; split3(acc1[q][c][r], h1, h2, h3);
        bfr[c][0][jj] = (short)h1; bfr[c][1][jj] = (short)h2; bfr[c][2][jj] = (short)h3;
      }
    }
#pragma unroll
    for (int q2 = 0; q2 < 4; ++q2) {
      bf16x8 afr[3];
#pragma unroll
      for (int s = 0; s < 3; ++s)
        afr[s] = *(const bf16x8*)&Ah[(((size_t)s * 2 + m) * 4 + lg) * 512 + (16 * q2 + l15) * 8];
#pragma unroll
      for (int c = 0; c < 4; ++c) {
        MF8(afr[0], afr[1], afr[2], bfr[c][0], bfr[c][1], bfr[c][2], acc2[q2][c]);
      }
    }
  }

  // epilogue: (acc + bias) * mask, relu
#pragma unroll
  for (int q2 = 0; q2 < 4; ++q2) {
#pragma unroll
    for (int c = 0; c < 4; ++c) {
      int n = 64 * w + 16 * c + l15;
      float bv = biaS[n];
#pragma unroll
      for (int r = 0; r < 4; ++r) {
        int row = 16 * q2 + 4 * lg + r;
        float val = (acc2[q2][c][r] + bv) * maskS[row];
        out[((size_t)b * 64 + row) * 256 + n] = fmaxf(val, 0.0f);
      }
    }
  }
}

// ---------------------------------------------------------------------------
// Per-batch cdist + softmin + Gumbel-max sampling (unchanged from round 1).
// ---------------------------------------------------------------------------
__global__ __launch_bounds__(256) void k_cdist(const float* __restrict__ h,
                                               const float* __restrict__ cen,
                                               const float* __restrict__ ccbuf,
                                               int* __restrict__ conc,
                                               float* __restrict__ pp) {
  __shared__ float hsT[256][68];
  __shared__ float cenT[256][36];
  __shared__ float hhs[64];
  __shared__ float mxs[64];
  __shared__ float lgden[64];
  float (*lg)[33] = (float(*)[33])cenT;

  int b = blockIdx.x, tid = threadIdx.x;
  const float* hb = h + (size_t)b * 16384;
  for (int g = tid; g < 4096; g += 256) {
    float4 v = *(const float4*)&hb[g * 4];
    int n = g >> 6, f = (g & 63) * 4;
    hsT[f + 0][n] = v.x; hsT[f + 1][n] = v.y; hsT[f + 2][n] = v.z; hsT[f + 3][n] = v.w;
  }
  {
    int k = tid & 31, f0 = (tid >> 5) * 32;
    for (int j = 0; j < 32; ++j) cenT[f0 + j][k] = cen[k * 256 + f0 + j];
  }
  __syncthreads();

  if (tid >= 128 && tid < 192) {
    int n = tid - 128;
    float s = 0.0f;
    for (int f = 0; f < 256; ++f) { float v = hsT[f][n]; s += v * v; }
    hhs[n] = s;
  }

  float acc[4][4] = {};
  int ty = (tid >> 3) & 15, tx = tid & 7;
  if (tid < 128) {
    for (int f = 0; f < 256; ++f) {
      float4 a4 = *(const float4*)&hsT[f][ty * 4];
      float4 b4 = *(const float4*)&cenT[f][tx * 4];
      acc[0][0] += a4.x * b4.x; acc[0][1] += a4.x * b4.y; acc[0][2] += a4.x * b4.z; acc[0][3] += a4.x * b4.w;
      acc[1][0] += a4.y * b4.x; acc[1][1] += a4.y * b4.y; acc[1][2] += a4.y * b4.z; acc[1][3] += a4.y * b4.w;
      acc[2][0] += a4.z * b4.x; acc[2][1] += a4.z * b4.y; acc[2][2] += a4.z * b4.z; acc[2][3] += a4.z * b4.w;
      acc[3][0] += a4.w * b4.x; acc[3][1] += a4.w * b4.y; acc[3][2] += a4.w * b4.z; acc[3][3] += a4.w * b4.w;
    }
  }
  __syncthreads();

  if (tid < 128) {
    float cc0 = ccbuf[tx * 4 + 0], cc1 = ccbuf[tx * 4 + 1];
    float cc2 = ccbuf[tx * 4 + 2], cc3 = ccbuf[tx * 4 + 3];
#pragma unroll
    for (int i = 0; i < 4; ++i) {
      int n = ty * 4 + i;
      float hh = hhs[n];
      lg[n][tx * 4 + 0] = -10.0f * sqrtf(fmaxf((hh + cc0) - 2.0f * acc[i][0], 1e-12f));
      lg[n][tx * 4 + 1] = -10.0f * sqrtf(fmaxf((hh + cc1) - 2.0f * acc[i][1], 1e-12f));
      lg[n][tx * 4 + 2] = -10.0f * sqrtf(fmaxf((hh + cc2) - 2.0f * acc[i][2], 1e-12f));
      lg[n][tx * 4 + 3] = -10.0f * sqrtf(fmaxf((hh + cc3) - 2.0f * acc[i][3], 1e-12f));
    }
  }
  __syncthreads();

  if (tid < 64) {
    float mx = -1e30f;
    for (int k = 0; k < 32; ++k) mx = fmaxf(mx, lg[tid][k]);
    float den = 0.0f;
    for (int k = 0; k < 32; ++k) den += expf(lg[tid][k] - mx);
    mxs[tid] = mx; lgden[tid] = logf(den);
  }
  __syncthreads();
  for (int p = tid; p < 2048; p += 256) {
    int n = p >> 5, k = p & 31;
    lg[n][k] = (lg[n][k] - mxs[n]) - lgden[n];
  }
  __syncthreads();

  int hw = tid >> 5, k = tid & 31;
  for (int pass = 0; pass < 8; ++pass) {
    int n = hw * 8 + pass;
    float lp = lg[n][k];
#pragma unroll
    for (int s4 = 0; s4 < 4; ++s4) {
      unsigned flat = (unsigned)(s4 * 32768 + b * 64 + n) * 32u + (unsigned)k;
      unsigned bits = tf_bits(flat);
      float fu = __uint_as_float((bits >> 9) | 0x3f800000u) - 1.0f;
      float u = fmaxf(TINYF, fu * (1.0f - TINYF) + TINYF);
      float g = -logf(-logf(u));
      float v = lp + g;
      int bi = k;
#pragma unroll
      for (int d = 1; d < 32; d <<= 1) {
        float ov = __shfl_xor(v, d, 32);
        int oi = __shfl_xor(bi, d, 32);
        if (ov > v || (ov == v && oi < bi)) { v = ov; bi = oi; }
      }
      if (k == 0) {
        conc[s4 * 32768 + b * 64 + n] = bi;
        pp[s4 * 32768 + b * 64 + n] = expf(lg[n][bi]);
      }
    }
  }
}

// ---------------------------------------------------------------------------
// Per (s,b): CC min-label fixpoint + graph_prob + labels + cluster bitmasks
// + pooled binarized adjacency.
// ---------------------------------------------------------------------------
__global__ __launch_bounds__(256) void k_post(const int* __restrict__ conc,
                                              const float* __restrict__ pp,
                                              const float* __restrict__ maskf,
                                              const unsigned long long* __restrict__ nbr,
                                              unsigned long long* __restrict__ clmask,
                                              float* __restrict__ out_gp,
                                              float* __restrict__ out_lab,
                                              float* __restrict__ out_newadj) {
  int sb = blockIdx.x, b = sb & 511, tid = threadIdx.x;
  __shared__ int cs[64];
  __shared__ int lab[64];
  __shared__ unsigned long long sm_[64];
  __shared__ unsigned long long nbs[64];
  __shared__ float o[4096];
  __shared__ int chg;

  for (int i = tid; i < 4096; i += 256) o[i] = 0.0f;
  bool mk = false;
  if (tid < 64) {
    cs[tid] = conc[sb * 64 + tid];
    nbs[tid] = nbr[b * 64 + tid];
    mk = maskf[b * 64 + tid] != 0.0f;
    lab[tid] = tid + 1;
  }
  if (tid == 0) chg = 0;
  __syncthreads();
  if (tid < 64) {
    unsigned long long nb = nbs[tid], s = 0ull;
    int c = cs[tid];
    while (nb) { int j = __ffsll(nb) - 1; if (cs[j] == c) s |= (1ull << j); nb &= nb - 1; }
    sm_[tid] = s;
  }
  __syncthreads();
  for (int it = 0; it < 64; ++it) {
    int m = 0;
    if (tid < 64) {
      m = lab[tid];
      unsigned long long t = sm_[tid];
      while (t) { int j = __ffsll(t) - 1; m = min(m, lab[j]); t &= t - 1; }
    }
    __syncthreads();
    if (tid < 64 && m < lab[tid]) { lab[tid] = m; chg = 1; }
    __syncthreads();
    if (chg == 0) break;
    __syncthreads();
    if (tid == 0) chg = 0;
  }
  if (tid < 64) {
    int lf = mk ? lab[tid] : 0;
    cs[tid] = lf;
    out_lab[sb * 64 + tid] = (float)lf;
    float pv = mk ? pp[sb * 64 + tid] : 1.0f;
#pragma unroll
    for (int d = 1; d < 64; d <<= 1) pv *= __shfl_xor(pv, d, 64);
    if (tid == 0) out_gp[sb] = pv;
  }
  __syncthreads();
  if (tid < 64) {
    unsigned long long cm = 0ull;
    for (int j = 0; j < 64; ++j)
      if (cs[j] == tid + 1) cm |= (1ull << j);
    clmask[sb * 64 + tid] = cm;
  }
  for (int p = tid; p < 4096; p += 256) {
    int i = p >> 6, j = p & 63;
    int li = cs[i], lj = cs[j];
    if (li > 0 && lj > 0 && ((nbs[i] >> j) & 1ull))
      o[(li - 1) * 64 + (lj - 1)] = 1.0f;
  }
  __syncthreads();
  float* dst = out_newadj + (size_t)sb * 4096;
  for (int i = tid; i < 1024; i += 256) {
    fx4 v = ((const fx4*)o)[i];
    __builtin_nontemporal_store(v, (fx4*)dst + i);
  }
}

// ---------------------------------------------------------------------------
// new_x[sb,c,:] = mean over cluster-(c+1) members of h[b].
// ---------------------------------------------------------------------------
__global__ __launch_bounds__(256) void k_newx(const float* __restrict__ h,
                                              const unsigned long long* __restrict__ clmask,
                                              float* __restrict__ out_newx) {
  int sb = blockIdx.x, b = sb & 511;
  int q = threadIdx.x & 63, cp = threadIdx.x >> 6;
  const float* hb = h + (size_t)b * 16384;
  for (int step = 0; step < 16; ++step) {
    int c = cp * 16 + step;
    unsigned long long m = clmask[sb * 64 + c];
    float4 acc = make_float4(0.f, 0.f, 0.f, 0.f);
    unsigned long long t = m;
    while (t) {
      int j = __ffsll(t) - 1; t &= t - 1;
      float4 v = *(const float4*)&hb[j * 256 + q * 4];
      acc.x += v.x; acc.y += v.y; acc.z += v.z; acc.w += v.w;
    }
    int cnt = __popcll(m);
    float cf = (float)(cnt > 0 ? cnt : 1);
    fx4 r;
    r.x = acc.x / cf; r.y = acc.y / cf; r.z = acc.z / cf; r.w = acc.w / cf;
    __builtin_nontemporal_store(r, (fx4*)&out_newx[((size_t)sb * 64 + c) * 256 + q * 4]);
  }
}

// ---------------------------------------------------------------------------
extern "C" void kernel_launch(void* const* d_in, const int* in_sizes, int n_in,
                              void* d_out, int out_size, void* d_ws, size_t ws_size,
                              hipStream_t stream) {
  (void)in_sizes; (void)n_in; (void)out_size; (void)ws_size;
  const float* x   = (const float*)d_in[0];
  const float* adj = (const float*)d_in[1];
  const void*  mp  = d_in[2];
  const float* W1  = (const float*)d_in[3];
  const float* b1  = (const float*)d_in[4];
  const float* W2  = (const float*)d_in[5];
  const float* b2  = (const float*)d_in[6];
  const float* cen = (const float*)d_in[7];

  char* ws = (char*)d_ws;
  unsigned short* Ahat3 = (unsigned short*)(ws + 0);                 // 12.6 MB
  unsigned short* Wg1   = (unsigned short*)(ws + 13631488);          // 196.6 KB
  unsigned short* Wg2   = (unsigned short*)(ws + 13893632);          // 393.2 KB
  unsigned long long* nbr = (unsigned long long*)(ws + 14417920);    // 256 KB
  float* maskf = (float*)(ws + 14680064);                            // 128 KB
  float* ccbuf = (float*)(ws + 14811136);                            // 128 B
  int*   flag  = (int*)  (ws + 14811392);                            // 4 B
  int*   conc  = (int*)  (ws + 15728640);                            // 512 KB
  float* pp    = (float*)(ws + 16252928);                            // 512 KB
  unsigned long long* clmask = (unsigned long long*)(ws + 16777216); // 1 MB
  float* bufB  = (float*)(ws + 18874368);                            // 32 MB (h)

  float* out        = (float*)d_out;
  float* out_newx   = out;                 // 2048*64*256
  float* out_newadj = out + 33554432;      // 2048*64*64
  float* out_gp     = out + 41943040;      // 2048
  float* out_lab    = out + 41945088;      // 2048*64
  float* bufA       = out;                 // h1 scratch; overwritten by k_newx last

  hipLaunchKernelGGL(k_detect, dim3(1), dim3(256), 0, stream, (const unsigned*)mp, flag);
  hipLaunchKernelGGL(k_mask,   dim3(128), dim3(256), 0, stream, mp, flag, maskf);
  hipLaunchKernelGGL(k_prep,   dim3(512), dim3(256), 0, stream, adj, Ahat3, nbr);
  hipLaunchKernelGGL(k_cc,     dim3(1), dim3(256), 0, stream, cen, ccbuf);
  hipLaunchKernelGGL(k_wsplit, dim3(144), dim3(256), 0, stream, W1, W2, Wg1, Wg2);
  hipLaunchKernelGGL(k_layer,  dim3(512), dim3(256), 0, stream, x,    Wg1, b1, Ahat3, maskf, bufA, 4);
  hipLaunchKernelGGL(k_layer,  dim3(512), dim3(256), 0, stream, bufA, Wg2, b2, Ahat3, maskf, bufB, 8);
  hipLaunchKernelGGL(k_cdist,  dim3(512), dim3(256), 0, stream, bufB, cen, ccbuf, conc, pp);
  hipLaunchKernelGGL(k_post,   dim3(2048), dim3(256), 0, stream, conc, pp, maskf, nbr,
                     clmask, out_gp, out_lab, out_newadj);
  hipLaunchKernelGGL(k_newx,   dim3(2048), dim3(256), 0, stream, bufB, clmask, out_newx);
}

// Round 5
// 193.126 us; speedup vs baseline: 1.7276x; 1.0620x over previous
//
#include <hip/hip_runtime.h>

// Problem constants
#define B_    512
#define SB_   2048

static constexpr float TINYF = 1.17549435e-38f;
typedef float fx4  __attribute__((ext_vector_type(4)));
typedef short bf16x8 __attribute__((ext_vector_type(8)));
typedef float f32x4 __attribute__((ext_vector_type(4)));
typedef unsigned short u16x4 __attribute__((ext_vector_type(4)));

// ---------------------------------------------------------------------------
// Threefry-2x32, key = (0, 42), partitionable path: bits(i) = y0^y1 of
// cipher(hi=0, lo=i).
// ---------------------------------------------------------------------------
__device__ __forceinline__ unsigned tf_bits(unsigned lo) {
  const unsigned ks0 = 0u, ks1 = 42u, ks2 = 0x1BD11BF0u;
  unsigned x0 = 0u + ks0;
  unsigned x1 = lo + ks1;
#define TFR(r) { x0 += x1; x1 = (x1 << r) | (x1 >> (32 - r)); x1 ^= x0; }
  TFR(13) TFR(15) TFR(26) TFR(6)
  x0 += ks1; x1 += ks2 + 1u;
  TFR(17) TFR(29) TFR(16) TFR(24)
  x0 += ks2; x1 += ks0 + 2u;
  TFR(13) TFR(15) TFR(26) TFR(6)
  x0 += ks0; x1 += ks1 + 3u;
  TFR(17) TFR(29) TFR(16) TFR(24)
  x0 += ks1; x1 += ks2 + 4u;
  TFR(13) TFR(15) TFR(26) TFR(6)
  x0 += ks2; x1 += ks0 + 5u;
#undef TFR
  return x0 ^ x1;
}

// Exact fp32 -> 3x bf16 split (truncation; v == v1+v2+v3 exactly for normals)
__device__ __forceinline__ void split3(float v, unsigned& b1, unsigned& b2, unsigned& b3) {
  unsigned u1 = __float_as_uint(v) & 0xFFFF0000u;
  float r1 = v - __uint_as_float(u1);
  unsigned u2 = __float_as_uint(r1) & 0xFFFF0000u;
  float r2 = r1 - __uint_as_float(u2);
  unsigned u3 = __float_as_uint(r2) & 0xFFFF0000u;
  b1 = u1 >> 16; b2 = u2 >> 16; b3 = u3 >> 16;
}

// plane s of the split (recompute chain; s is compile-time after unroll)
__device__ __forceinline__ unsigned short planeOf(float v, int s) {
  unsigned u1 = __float_as_uint(v) & 0xFFFF0000u;
  if (s == 0) return (unsigned short)(u1 >> 16);
  float r1 = v - __uint_as_float(u1);
  unsigned u2 = __float_as_uint(r1) & 0xFFFF0000u;
  if (s == 1) return (unsigned short)(u2 >> 16);
  float r2 = r1 - __uint_as_float(u2);
  return (unsigned short)((__float_as_uint(r2) & 0xFFFF0000u) >> 16);
}

// 8-product split accumulation (drops only a3*b3 ~ 2^-32)
#define MF8(A0, A1, A2, Bv0, Bv1, Bv2, ACC)                                   \
  ACC = __builtin_amdgcn_mfma_f32_16x16x32_bf16(A0, Bv0, ACC, 0, 0, 0);       \
  ACC = __builtin_amdgcn_mfma_f32_16x16x32_bf16(A0, Bv1, ACC, 0, 0, 0);       \
  ACC = __builtin_amdgcn_mfma_f32_16x16x32_bf16(A1, Bv0, ACC, 0, 0, 0);       \
  ACC = __builtin_amdgcn_mfma_f32_16x16x32_bf16(A0, Bv2, ACC, 0, 0, 0);       \
  ACC = __builtin_amdgcn_mfma_f32_16x16x32_bf16(A1, Bv1, ACC, 0, 0, 0);       \
  ACC = __builtin_amdgcn_mfma_f32_16x16x32_bf16(A2, Bv0, ACC, 0, 0, 0);       \
  ACC = __builtin_amdgcn_mfma_f32_16x16x32_bf16(A1, Bv2, ACC, 0, 0, 0);       \
  ACC = __builtin_amdgcn_mfma_f32_16x16x32_bf16(A2, Bv1, ACC, 0, 0, 0);

// ---------------------------------------------------------------------------
// Fused mask-dtype detect (each block scans first 8 KB) + maskf conversion.
// ---------------------------------------------------------------------------
__global__ void k_dm(const void* __restrict__ mptr, float* __restrict__ maskf) {
  __shared__ int s_ni, s_nf;
  if (threadIdx.x == 0) { s_ni = 0; s_nf = 0; }
  __syncthreads();
  const unsigned* wp = (const unsigned*)mptr;
  int ni = 0, nf = 0;
  for (int i = threadIdx.x; i < 2048; i += 256) {
    unsigned v = wp[i];
    if (v > 1u) ni = 1;
    if (v != 0u && v != 0x3f800000u) nf = 1;
  }
  if (ni) atomicOr(&s_ni, 1);
  if (nf) atomicOr(&s_nf, 1);
  __syncthreads();
  int fl = s_ni ? (s_nf ? 2 : 1) : 0;
  int i = blockIdx.x * 256 + threadIdx.x;
  if (i >= B_ * 64) return;
  float r;
  if (fl == 0)      r = ((const int*)mptr)[i] ? 1.0f : 0.0f;
  else if (fl == 1) r = (((const float*)mptr)[i] != 0.0f) ? 1.0f : 0.0f;
  else              r = ((const unsigned char*)mptr)[i] ? 1.0f : 0.0f;
  maskf[i] = r;
}

// ---------------------------------------------------------------------------
// Per-batch prep: Ahat = D^-1/2 (A+I) D^-1/2 -> split planes in MFMA A-frag
// layout (standard k-map): chunk ch = (((s*2+mt)*4+q2)*4+lg)*16+l15,
// element jj = split_s(Ahat[16q2+l15][32mt+8lg+jj]). Plus neighbor bitmasks.
// ---------------------------------------------------------------------------
__global__ __launch_bounds__(256) void k_prep(const float* __restrict__ adj,
                                              unsigned short* __restrict__ Ahat3,
                                              unsigned long long* __restrict__ nbr) {
  __shared__ float adjS[4096];
  __shared__ float AhS[64][65];
  __shared__ float dis[64];
  int b = blockIdx.x, tid = threadIdx.x;
  const float* ab = adj + (size_t)b * 4096;
  for (int i = tid; i < 4096; i += 256) adjS[i] = ab[i];
  __syncthreads();
  if (tid < 64) {
    float s = 0.0f;
    unsigned long long m = 0ull;
    for (int j = 0; j < 64; ++j) {
      float v = adjS[j * 64 + tid];            // symmetric
      s += (j == tid) ? (v + 1.0f) : v;
      if (v != 0.0f) m |= (1ull << j);
    }
    dis[tid] = 1.0f / sqrtf(fmaxf(s, 1.0f));
    nbr[b * 64 + tid] = m;
  }
  __syncthreads();
  for (int i = tid; i < 4096; i += 256) {
    int r = i >> 6, c = i & 63;
    float a = adjS[i] + ((r == c) ? 1.0f : 0.0f);
    AhS[r][c] = (dis[r] * a) * dis[c];
  }
  __syncthreads();
  unsigned short* dst = Ahat3 + (size_t)b * 12288;
  for (int ch = tid; ch < 1536; ch += 256) {
    int l15v = ch & 15, lgv = (ch >> 4) & 3, q2 = (ch >> 6) & 3, mt = (ch >> 8) & 1, s = ch >> 9;
    bf16x8 hv;
#pragma unroll
    for (int jj = 0; jj < 8; ++jj)
      hv[jj] = (short)planeOf(AhS[16 * q2 + l15v][32 * mt + 8 * lgv + jj], s);
    *(bf16x8*)&dst[(size_t)ch * 8] = hv;
  }
}

// ---------------------------------------------------------------------------
// Setup: W1/W2 split planes (GEMM1 B-frag layout, unchanged), centroid
// squared norms, centroid split planes (cdist B-frag layout).
// ---------------------------------------------------------------------------
__global__ void k_setup(const float* __restrict__ W1, const float* __restrict__ W2,
                        const float* __restrict__ cen,
                        unsigned short* __restrict__ Wg1, unsigned short* __restrict__ Wg2,
                        unsigned short* __restrict__ cen3, float* __restrict__ ccbuf) {
  int bi = blockIdx.x, tid = threadIdx.x;
  if (bi < 144) {
    const float* W; unsigned short* Wg; int nk, s, ks, g;
    if (bi < 48) { W = W1; Wg = Wg1; nk = 4; s = bi >> 4; ks = (bi >> 2) & 3; g = bi & 3; }
    else { int t = bi - 48; W = W2; Wg = Wg2; nk = 8; s = t >> 5; ks = (t >> 2) & 7; g = t & 3; }
    int n = tid;
    bf16x8 hv;
#pragma unroll
    for (int jj = 0; jj < 8; ++jj) {
      float v = W[(size_t)(ks * 32 + g * 8 + jj) * 256 + n];
      hv[jj] = (short)planeOf(v, s);
    }
    *(bf16x8*)&Wg[((((size_t)s * nk + ks) * 4 + g) * 256 + n) * 8] = hv;
  } else if (bi == 144) {
    // centroid norms, round-0 fp32 order
    int k = tid >> 3, l8 = tid & 7;
    float s = 0.0f;
    for (int m = 0; m < 32; ++m) { float v = cen[k * 256 + l8 + 8 * m]; s += v * v; }
#pragma unroll
    for (int d = 1; d < 8; d <<= 1) s += __shfl_xor(s, d, 64);
    if (l8 == 0) ccbuf[k] = s;
  } else {
    // cen3 plane s = bi-145: chunk idx = ((ks*2+c)*64 + l15*4 + lg),
    // element jj = split_s(cen[16c+l15][32ks+8lg+jj])
    int s = bi - 145;
    for (int u = 0; u < 4; ++u) {
      int idx = tid + 256 * u;
      int ks = idx >> 7, c = (idx >> 6) & 1, rem = idx & 63;
      int l15v = rem >> 2, lgv = rem & 3;
      bf16x8 hv;
#pragma unroll
      for (int jj = 0; jj < 8; ++jj)
        hv[jj] = (short)planeOf(cen[(size_t)(16 * c + l15v) * 256 + 32 * ks + 8 * lgv + jj], s);
      *(bf16x8*)&cen3[(size_t)s * 8192 + (size_t)idx * 8] = hv;
    }
  }
}

// ---------------------------------------------------------------------------
// MFMA layer: out = relu(maskf * (Ahat @ (A @ W) + bias)), fp32 via 3-way
// bf16 split (8 products). GEMM1 -> T staged through LDS one split-plane at
// a time (union with Ap) -> GEMM2 vs Ahat3. 2 waves/SIMD via launch_bounds.
// ---------------------------------------------------------------------------
__global__ __launch_bounds__(256, 2) void k_layer(const float* __restrict__ A,
                                                  const unsigned short* __restrict__ Wg,
                                                  const float* __restrict__ bias,
                                                  const unsigned short* __restrict__ Ahat3,
                                                  const float* __restrict__ maskf,
                                                  float* __restrict__ out, int nk) {
  __shared__ char smem[36864];                 // union: Ap (25.3 KB) / Tbuf (36.9 KB)
  __shared__ float biaS[256];
  __shared__ float maskS[64];
  unsigned short (*Ap)[3][2112] = (unsigned short(*)[3][2112])smem;  // [2][3][2112]
  unsigned short (*Tbuf)[72]    = (unsigned short(*)[72])smem;       // [256][72]

  int b = blockIdx.x, tid = threadIdx.x;
  int w = tid >> 6, l = tid & 63;
  int l15 = l & 15, lg = l >> 4;
  int K = nk * 32;
  const float* Ab = A + (size_t)b * 64 * K;
  biaS[tid] = bias[tid];
  if (tid < 64) maskS[tid] = maskf[b * 64 + tid];

  int srow = tid >> 2, sg = tid & 3;
  const float* sp = Ab + (size_t)srow * K + sg * 8;

  // stage K-step 0 into buffer 0
  {
    float4 v0 = *(const float4*)(sp);
    float4 v1 = *(const float4*)(sp + 4);
    float vv[8] = {v0.x, v0.y, v0.z, v0.w, v1.x, v1.y, v1.z, v1.w};
    bf16x8 p1, p2, p3;
#pragma unroll
    for (int jj = 0; jj < 8; ++jj) {
      unsigned h1, h2, h3; split3(vv[jj], h1, h2, h3);
      p1[jj] = (short)h1; p2[jj] = (short)h2; p3[jj] = (short)h3;
    }
    int off = sg * 528 + srow * 8;
    *(bf16x8*)&Ap[0][0][off] = p1;
    *(bf16x8*)&Ap[0][1][off] = p2;
    *(bf16x8*)&Ap[0][2][off] = p3;
  }
  __syncthreads();

  f32x4 acc1[4][4];
#pragma unroll
  for (int q = 0; q < 4; ++q)
#pragma unroll
    for (int c = 0; c < 4; ++c) acc1[q][c] = (f32x4){0.f, 0.f, 0.f, 0.f};

  const size_t wss = (size_t)nk * 8192;  // split-plane stride in Wg (shorts)

  for (int ks = 0; ks < nk; ++ks) {
    int cur = ks & 1;
    float4 v0, v1;
    bool pf = (ks + 1 < nk);
    if (pf) {
      v0 = *(const float4*)(sp + (ks + 1) * 32);
      v1 = *(const float4*)(sp + (ks + 1) * 32 + 4);
    }
    bf16x8 af[4][3];
#pragma unroll
    for (int q = 0; q < 4; ++q) {
      int off = lg * 528 + (16 * q + l15) * 8;
#pragma unroll
      for (int s = 0; s < 3; ++s) af[q][s] = *(const bf16x8*)&Ap[cur][s][off];
    }
#pragma unroll
    for (int c = 0; c < 4; ++c) {
      size_t wbase = (((size_t)ks * 4 + lg) * 256 + (64 * w + 16 * c + l15)) * 8;
      bf16x8 b0 = *(const bf16x8*)&Wg[wbase];
      bf16x8 b1 = *(const bf16x8*)&Wg[wbase + wss];
      bf16x8 b2 = *(const bf16x8*)&Wg[wbase + 2 * wss];
#pragma unroll
      for (int q = 0; q < 4; ++q) {
        MF8(af[q][0], af[q][1], af[q][2], b0, b1, b2, acc1[q][c]);
      }
    }
    if (pf) {
      float vv[8] = {v0.x, v0.y, v0.z, v0.w, v1.x, v1.y, v1.z, v1.w};
      bf16x8 p1, p2, p3;
#pragma unroll
      for (int jj = 0; jj < 8; ++jj) {
        unsigned h1, h2, h3; split3(vv[jj], h1, h2, h3);
        p1[jj] = (short)h1; p2[jj] = (short)h2; p3[jj] = (short)h3;
      }
      int off = sg * 528 + srow * 8;
      *(bf16x8*)&Ap[cur ^ 1][0][off] = p1;
      *(bf16x8*)&Ap[cur ^ 1][1][off] = p2;
      *(bf16x8*)&Ap[cur ^ 1][2][off] = p3;
    }
    __syncthreads();
  }

  // GEMM#2 phased over T split-planes. Lane holds acc1[q][c][r] =
  // T[16q+4lg+r][64w+16c+l15]; Tbuf[col][node] gives jj-contiguous node runs.
  f32x4 acc2[4][4];
#pragma unroll
  for (int q = 0; q < 4; ++q)
#pragma unroll
    for (int c = 0; c < 4; ++c) acc2[q][c] = (f32x4){0.f, 0.f, 0.f, 0.f};

  const unsigned short* Ah = Ahat3 + (size_t)b * 12288;
#pragma unroll
  for (int sB = 0; sB < 3; ++sB) {
    const int nA = (sB < 2) ? 3 : 2;     // products: all (sA,sB) with sA+... = 8 total
    __syncthreads();                     // prior-phase reads (and GEMM1 Ap reads) done
#pragma unroll
    for (int q = 0; q < 4; ++q)
#pragma unroll
      for (int c = 0; c < 4; ++c) {
        u16x4 pv;
#pragma unroll
        for (int r = 0; r < 4; ++r) pv[r] = planeOf(acc1[q][c][r], sB);
        *(u16x4*)&Tbuf[64 * w + 16 * c + l15][16 * q + 4 * lg] = pv;
      }
    __syncthreads();
#pragma unroll
    for (int mt = 0; mt < 2; ++mt) {
      bf16x8 bf[4];
#pragma unroll
      for (int c = 0; c < 4; ++c)
        bf[c] = *(const bf16x8*)&Tbuf[64 * w + 16 * c + l15][32 * mt + 8 * lg];
#pragma unroll
      for (int q2 = 0; q2 < 4; ++q2) {
        bf16x8 afr[3];
#pragma unroll
        for (int sA = 0; sA < 3; ++sA)
          if (sA < nA)
            afr[sA] = *(const bf16x8*)&Ah[((((size_t)(sA * 2 + mt) * 4 + q2) * 4 + lg) * 16 + l15) * 8];
#pragma unroll
        for (int c = 0; c < 4; ++c)
#pragma unroll
          for (int sA = 0; sA < 3; ++sA)
            if (sA < nA)
              acc2[q2][c] = __builtin_amdgcn_mfma_f32_16x16x32_bf16(afr[sA], bf[c], acc2[q2][c], 0, 0, 0);
      }
    }
  }

  // epilogue: (acc + bias) * mask, relu
#pragma unroll
  for (int q2 = 0; q2 < 4; ++q2) {
#pragma unroll
    for (int c = 0; c < 4; ++c) {
      int n = 64 * w + 16 * c + l15;
      float bv = biaS[n];
#pragma unroll
      for (int r = 0; r < 4; ++r) {
        int row = 16 * q2 + 4 * lg + r;
        float val = (acc2[q2][c][r] + bv) * maskS[row];
        out[((size_t)b * 64 + row) * 256 + n] = fmaxf(val, 0.0f);
      }
    }
  }
}

// ---------------------------------------------------------------------------
// cdist + softmin + Gumbel-max: MFMA h@cenT with XOR-swizzled h in LDS,
// 4-wave K-split + LDS reduce; fp32 d2/softmax/sampling tail unchanged.
// ---------------------------------------------------------------------------
__global__ __launch_bounds__(256) void k_cdist(const float* __restrict__ h,
                                               const unsigned short* __restrict__ cen3,
                                               const float* __restrict__ ccbuf,
                                               int* __restrict__ conc,
                                               float* __restrict__ pp) {
  __shared__ float hS[16384];          // 64 KB, rows XOR-swizzled by ((row&7)<<4)
  __shared__ float Dred[4][64][36];    // 36.9 KB
  __shared__ float hhp[64][4];
  __shared__ float lgp[64][33];
  __shared__ float mxs[64], lgden[64];

  int b = blockIdx.x, tid = threadIdx.x;
  int w = tid >> 6, l = tid & 63, l15 = l & 15, lg = l >> 4;
  const float* hb = h + (size_t)b * 16384;

  // stage h with swizzle applied on write address (reg-staged)
#pragma unroll
  for (int i = 0; i < 16; ++i) {
    int g = tid + 256 * i;
    float4 v = *(const float4*)&hb[(size_t)g * 4];
    int row = g >> 6;
    int fb = ((g & 63) * 16) ^ ((row & 7) << 4);
    *(float4*)((char*)&hS[row * 256] + fb) = v;
  }
  __syncthreads();

#define LD4(row, fbyte) (*(const float4*)((const char*)&hS[(row) * 256] + ((fbyte) ^ (((row) & 7) << 4))))

  // hh partials: thread t -> row t&63, f-quarter t>>6
  {
    int row = tid & 63, qt = tid >> 6;
    float s = 0.0f;
    for (int u = 0; u < 16; ++u) {
      float4 v = LD4(row, qt * 256 + u * 16);
      s += v.x * v.x + v.y * v.y + v.z * v.z + v.w * v.w;
    }
    hhp[row][qt] = s;
  }

  // GEMM: wave w covers f = 64w..64w+63 (ksteps 2w, 2w+1)
  f32x4 acc[4][2];
#pragma unroll
  for (int qt = 0; qt < 4; ++qt)
#pragma unroll
    for (int c = 0; c < 2; ++c) acc[qt][c] = (f32x4){0.f, 0.f, 0.f, 0.f};

#pragma unroll
  for (int ks2 = 0; ks2 < 2; ++ks2) {
    int ks = 2 * w + ks2;
#pragma unroll
    for (int qt = 0; qt < 4; ++qt) {
      int row = 16 * qt + l15;
      int fb = (32 * ks + 8 * lg) * 4;
      float4 v0 = LD4(row, fb);
      float4 v1 = LD4(row, fb + 16);
      float vv[8] = {v0.x, v0.y, v0.z, v0.w, v1.x, v1.y, v1.z, v1.w};
      bf16x8 a0, a1, a2;
#pragma unroll
      for (int jj = 0; jj < 8; ++jj) {
        unsigned h1, h2, h3; split3(vv[jj], h1, h2, h3);
        a0[jj] = (short)h1; a1[jj] = (short)h2; a2[jj] = (short)h3;
      }
#pragma unroll
      for (int c = 0; c < 2; ++c) {
        const unsigned short* cb = cen3 + ((size_t)(ks * 2 + c) * 64 + l15 * 4 + lg) * 8;
        bf16x8 b0 = *(const bf16x8*)cb;
        bf16x8 b1 = *(const bf16x8*)(cb + 8192);
        bf16x8 b2 = *(const bf16x8*)(cb + 16384);
        MF8(a0, a1, a2, b0, b1, b2, acc[qt][c]);
      }
    }
  }

  // write partial D
#pragma unroll
  for (int qt = 0; qt < 4; ++qt)
#pragma unroll
    for (int c = 0; c < 2; ++c)
#pragma unroll
      for (int r = 0; r < 4; ++r)
        Dred[w][16 * qt + 4 * lg + r][16 * c + l15] = acc[qt][c][r];
  __syncthreads();

  // logits: thread -> (n = tid>>2, k-slice of 8)
  {
    int n = tid >> 2, kq = tid & 3;
    float hh = (hhp[n][0] + hhp[n][1]) + (hhp[n][2] + hhp[n][3]);
#pragma unroll
    for (int j = 0; j < 8; ++j) {
      int k = kq * 8 + j;
      float dot = (Dred[0][n][k] + Dred[1][n][k]) + (Dred[2][n][k] + Dred[3][n][k]);
      float d2 = (hh + ccbuf[k]) - 2.0f * dot;
      lgp[n][k] = -10.0f * sqrtf(fmaxf(d2, 1e-12f));
    }
  }
  __syncthreads();

  if (tid < 64) {
    float mx = -1e30f;
    for (int k = 0; k < 32; ++k) mx = fmaxf(mx, lgp[tid][k]);
    float den = 0.0f;
    for (int k = 0; k < 32; ++k) den += expf(lgp[tid][k] - mx);
    mxs[tid] = mx; lgden[tid] = logf(den);
  }
  __syncthreads();
  for (int p = tid; p < 2048; p += 256) {
    int n = p >> 5, k = p & 31;
    lgp[n][k] = (lgp[n][k] - mxs[n]) - lgden[n];   // logp
  }
  __syncthreads();

  int hw = tid >> 5, k = tid & 31;
  for (int pass = 0; pass < 8; ++pass) {
    int n = hw * 8 + pass;
    float lp = lgp[n][k];
#pragma unroll
    for (int s4 = 0; s4 < 4; ++s4) {
      unsigned flat = (unsigned)(s4 * 32768 + b * 64 + n) * 32u + (unsigned)k;
      unsigned bits = tf_bits(flat);
      float fu = __uint_as_float((bits >> 9) | 0x3f800000u) - 1.0f;
      float u = fmaxf(TINYF, fu * (1.0f - TINYF) + TINYF);
      float g = -logf(-logf(u));
      float v = lp + g;
      int bi = k;
#pragma unroll
      for (int d = 1; d < 32; d <<= 1) {        // max, first-index ties
        float ov = __shfl_xor(v, d, 32);
        int oi = __shfl_xor(bi, d, 32);
        if (ov > v || (ov == v && oi < bi)) { v = ov; bi = oi; }
      }
      if (k == 0) {
        conc[s4 * 32768 + b * 64 + n] = bi;
        pp[s4 * 32768 + b * 64 + n] = expf(lgp[n][bi]);
      }
    }
  }
#undef LD4
}

// ---------------------------------------------------------------------------
// Per (s,b): CC min-label fixpoint + graph_prob + labels + cluster bitmasks
// + pooled binarized adjacency.
// ---------------------------------------------------------------------------
__global__ __launch_bounds__(256) void k_post(const int* __restrict__ conc,
                                              const float* __restrict__ pp,
                                              const float* __restrict__ maskf,
                                              const unsigned long long* __restrict__ nbr,
                                              unsigned long long* __restrict__ clmask,
                                              float* __restrict__ out_gp,
                                              float* __restrict__ out_lab,
                                              float* __restrict__ out_newadj) {
  int sb = blockIdx.x, b = sb & 511, tid = threadIdx.x;
  __shared__ int cs[64];
  __shared__ int lab[64];
  __shared__ unsigned long long sm_[64];
  __shared__ unsigned long long nbs[64];
  __shared__ float o[4096];
  __shared__ int chg;

  for (int i = tid; i < 4096; i += 256) o[i] = 0.0f;
  bool mk = false;
  if (tid < 64) {
    cs[tid] = conc[sb * 64 + tid];
    nbs[tid] = nbr[b * 64 + tid];
    mk = maskf[b * 64 + tid] != 0.0f;
    lab[tid] = tid + 1;
  }
  if (tid == 0) chg = 0;
  __syncthreads();
  if (tid < 64) {
    unsigned long long nb = nbs[tid], s = 0ull;
    int c = cs[tid];
    while (nb) { int j = __ffsll(nb) - 1; if (cs[j] == c) s |= (1ull << j); nb &= nb - 1; }
    sm_[tid] = s;
  }
  __syncthreads();
  for (int it = 0; it < 64; ++it) {
    int m = 0;
    if (tid < 64) {
      m = lab[tid];
      unsigned long long t = sm_[tid];
      while (t) { int j = __ffsll(t) - 1; m = min(m, lab[j]); t &= t - 1; }
    }
    __syncthreads();
    if (tid < 64 && m < lab[tid]) { lab[tid] = m; chg = 1; }
    __syncthreads();
    if (chg == 0) break;
    __syncthreads();
    if (tid == 0) chg = 0;
  }
  if (tid < 64) {
    int lf = mk ? lab[tid] : 0;
    cs[tid] = lf;
    out_lab[sb * 64 + tid] = (float)lf;
    float pv = mk ? pp[sb * 64 + tid] : 1.0f;
#pragma unroll
    for (int d = 1; d < 64; d <<= 1) pv *= __shfl_xor(pv, d, 64);
    if (tid == 0) out_gp[sb] = pv;
  }
  __syncthreads();
  if (tid < 64) {
    unsigned long long cm = 0ull;
    for (int j = 0; j < 64; ++j)
      if (cs[j] == tid + 1) cm |= (1ull << j);
    clmask[sb * 64 + tid] = cm;
  }
  for (int p = tid; p < 4096; p += 256) {
    int i = p >> 6, j = p & 63;
    int li = cs[i], lj = cs[j];
    if (li > 0 && lj > 0 && ((nbs[i] >> j) & 1ull))
      o[(li - 1) * 64 + (lj - 1)] = 1.0f;
  }
  __syncthreads();
  float* dst = out_newadj + (size_t)sb * 4096;
  for (int i = tid; i < 1024; i += 256) {
    fx4 v = ((const fx4*)o)[i];
    __builtin_nontemporal_store(v, (fx4*)dst + i);
  }
}

// ---------------------------------------------------------------------------
// new_x[sb,c,:] = mean over cluster-(c+1) members of h[b].
// ---------------------------------------------------------------------------
__global__ __launch_bounds__(256) void k_newx(const float* __restrict__ h,
                                              const unsigned long long* __restrict__ clmask,
                                              float* __restrict__ out_newx) {
  int sb = blockIdx.x, b = sb & 511;
  int q = threadIdx.x & 63, cp = threadIdx.x >> 6;
  const float* hb = h + (size_t)b * 16384;
  for (int step = 0; step < 16; ++step) {
    int c = cp * 16 + step;
    unsigned long long m = clmask[sb * 64 + c];
    float4 acc = make_float4(0.f, 0.f, 0.f, 0.f);
    unsigned long long t = m;
    while (t) {
      int j = __ffsll(t) - 1; t &= t - 1;
      float4 v = *(const float4*)&hb[j * 256 + q * 4];
      acc.x += v.x; acc.y += v.y; acc.z += v.z; acc.w += v.w;
    }
    int cnt = __popcll(m);
    float cf = (float)(cnt > 0 ? cnt : 1);
    fx4 r;
    r.x = acc.x / cf; r.y = acc.y / cf; r.z = acc.z / cf; r.w = acc.w / cf;
    __builtin_nontemporal_store(r, (fx4*)&out_newx[((size_t)sb * 64 + c) * 256 + q * 4]);
  }
}

// ---------------------------------------------------------------------------
extern "C" void kernel_launch(void* const* d_in, const int* in_sizes, int n_in,
                              void* d_out, int out_size, void* d_ws, size_t ws_size,
                              hipStream_t stream) {
  (void)in_sizes; (void)n_in; (void)out_size; (void)ws_size;
  const float* x   = (const float*)d_in[0];
  const float* adj = (const float*)d_in[1];
  const void*  mp  = d_in[2];
  const float* W1  = (const float*)d_in[3];
  const float* b1  = (const float*)d_in[4];
  const float* W2  = (const float*)d_in[5];
  const float* b2  = (const float*)d_in[6];
  const float* cen = (const float*)d_in[7];

  char* ws = (char*)d_ws;
  unsigned short* Ahat3 = (unsigned short*)(ws + 0);                 // 12,582,912
  unsigned short* Wg1   = (unsigned short*)(ws + 12582912);          // 196,608
  unsigned short* Wg2   = (unsigned short*)(ws + 12779520);          // 393,216
  unsigned short* cen3  = (unsigned short*)(ws + 13172736);          // 49,152
  float* ccbuf          = (float*)(ws + 13221888);                   // 128
  unsigned long long* nbr = (unsigned long long*)(ws + 13222016);    // 262,144
  float* maskf          = (float*)(ws + 13484160);                   // 131,072
  int*   conc           = (int*)(ws + 13615232);                     // 524,288
  float* pp             = (float*)(ws + 14139520);                   // 524,288
  unsigned long long* clmask = (unsigned long long*)(ws + 14663808); // 1,048,576
  float* bufB           = (float*)(ws + 16777216);                   // 33,554,432 (h)

  float* out        = (float*)d_out;
  float* out_newx   = out;                 // 2048*64*256
  float* out_newadj = out + 33554432;      // 2048*64*64
  float* out_gp     = out + 41943040;      // 2048
  float* out_lab    = out + 41945088;      // 2048*64
  float* bufA       = out;                 // h1 scratch; overwritten by k_newx last

  hipLaunchKernelGGL(k_dm,    dim3(128), dim3(256), 0, stream, mp, maskf);
  hipLaunchKernelGGL(k_prep,  dim3(512), dim3(256), 0, stream, adj, Ahat3, nbr);
  hipLaunchKernelGGL(k_setup, dim3(148), dim3(256), 0, stream, W1, W2, cen, Wg1, Wg2, cen3, ccbuf);
  hipLaunchKernelGGL(k_layer, dim3(512), dim3(256), 0, stream, x,    Wg1, b1, Ahat3, maskf, bufA, 4);
  hipLaunchKernelGGL(k_layer, dim3(512), dim3(256), 0, stream, bufA, Wg2, b2, Ahat3, maskf, bufB, 8);
  hipLaunchKernelGGL(k_cdist, dim3(512), dim3(256), 0, stream, bufB, cen3, ccbuf, conc, pp);
  hipLaunchKernelGGL(k_post,  dim3(2048), dim3(256), 0, stream, conc, pp, maskf, nbr,
                     clmask, out_gp, out_lab, out_newadj);
  hipLaunchKernelGGL(k_newx,  dim3(2048), dim3(256), 0, stream, bufB, clmask, out_newx);
}

// Round 6
// 180.592 us; speedup vs baseline: 1.8475x; 1.0694x over previous
//
#include <hip/hip_runtime.h>

// Problem constants
#define B_    512
#define SB_   2048

static constexpr float TINYF = 1.17549435e-38f;
typedef float fx4  __attribute__((ext_vector_type(4)));
typedef short bf16x8 __attribute__((ext_vector_type(8)));
typedef float f32x4 __attribute__((ext_vector_type(4)));
typedef unsigned short u16x4 __attribute__((ext_vector_type(4)));

// ---------------------------------------------------------------------------
// Threefry-2x32, key = (0, 42), partitionable path: bits(i) = y0^y1 of
// cipher(hi=0, lo=i).
// ---------------------------------------------------------------------------
__device__ __forceinline__ unsigned tf_bits(unsigned lo) {
  const unsigned ks0 = 0u, ks1 = 42u, ks2 = 0x1BD11BF0u;
  unsigned x0 = 0u + ks0;
  unsigned x1 = lo + ks1;
#define TFR(r) { x0 += x1; x1 = (x1 << r) | (x1 >> (32 - r)); x1 ^= x0; }
  TFR(13) TFR(15) TFR(26) TFR(6)
  x0 += ks1; x1 += ks2 + 1u;
  TFR(17) TFR(29) TFR(16) TFR(24)
  x0 += ks2; x1 += ks0 + 2u;
  TFR(13) TFR(15) TFR(26) TFR(6)
  x0 += ks0; x1 += ks1 + 3u;
  TFR(17) TFR(29) TFR(16) TFR(24)
  x0 += ks1; x1 += ks2 + 4u;
  TFR(13) TFR(15) TFR(26) TFR(6)
  x0 += ks2; x1 += ks0 + 5u;
#undef TFR
  return x0 ^ x1;
}

// Exact fp32 -> 3x bf16 split (truncation; v == v1+v2+v3 exactly for normals)
__device__ __forceinline__ void split3(float v, unsigned& b1, unsigned& b2, unsigned& b3) {
  unsigned u1 = __float_as_uint(v) & 0xFFFF0000u;
  float r1 = v - __uint_as_float(u1);
  unsigned u2 = __float_as_uint(r1) & 0xFFFF0000u;
  float r2 = r1 - __uint_as_float(u2);
  unsigned u3 = __float_as_uint(r2) & 0xFFFF0000u;
  b1 = u1 >> 16; b2 = u2 >> 16; b3 = u3 >> 16;
}

// plane s of the split (recompute chain; s is compile-time after unroll)
__device__ __forceinline__ unsigned short planeOf(float v, int s) {
  unsigned u1 = __float_as_uint(v) & 0xFFFF0000u;
  if (s == 0) return (unsigned short)(u1 >> 16);
  float r1 = v - __uint_as_float(u1);
  unsigned u2 = __float_as_uint(r1) & 0xFFFF0000u;
  if (s == 1) return (unsigned short)(u2 >> 16);
  float r2 = r1 - __uint_as_float(u2);
  return (unsigned short)((__float_as_uint(r2) & 0xFFFF0000u) >> 16);
}

// 6-product split accumulation: keeps (0,0),(0,1),(1,0),(0,2),(1,1),(2,0);
// dropped terms <= 2^-27 relative (below fp32 accum rounding).
#define MF6(A0, A1, A2, Bv0, Bv1, Bv2, ACC)                                   \
  ACC = __builtin_amdgcn_mfma_f32_16x16x32_bf16(A0, Bv0, ACC, 0, 0, 0);       \
  ACC = __builtin_amdgcn_mfma_f32_16x16x32_bf16(A0, Bv1, ACC, 0, 0, 0);       \
  ACC = __builtin_amdgcn_mfma_f32_16x16x32_bf16(A1, Bv0, ACC, 0, 0, 0);       \
  ACC = __builtin_amdgcn_mfma_f32_16x16x32_bf16(A0, Bv2, ACC, 0, 0, 0);       \
  ACC = __builtin_amdgcn_mfma_f32_16x16x32_bf16(A1, Bv1, ACC, 0, 0, 0);       \
  ACC = __builtin_amdgcn_mfma_f32_16x16x32_bf16(A2, Bv0, ACC, 0, 0, 0);

// ---------------------------------------------------------------------------
// Merged init: every block does per-batch prep (Ahat split planes + nbr);
// blocks 0-127 also convert maskf (with dtype autodetect); blocks 128-275
// also do W/centroid setup roles.
// ---------------------------------------------------------------------------
__global__ __launch_bounds__(256) void k_init(const float* __restrict__ adj,
                                              const void* __restrict__ mptr,
                                              const float* __restrict__ W1,
                                              const float* __restrict__ W2,
                                              const float* __restrict__ cen,
                                              unsigned short* __restrict__ Ahat3,
                                              unsigned long long* __restrict__ nbr,
                                              float* __restrict__ maskf,
                                              unsigned short* __restrict__ Wg1,
                                              unsigned short* __restrict__ Wg2,
                                              unsigned short* __restrict__ cen3,
                                              float* __restrict__ ccbuf) {
  __shared__ float adjS[4096];
  __shared__ float AhS[64][65];
  __shared__ float dis[64];
  int b = blockIdx.x, tid = threadIdx.x;

  // ---- prep for batch b ----
  const float* ab = adj + (size_t)b * 4096;
  for (int i = tid; i < 4096; i += 256) adjS[i] = ab[i];
  __syncthreads();
  if (tid < 64) {
    float s = 0.0f;
    unsigned long long m = 0ull;
    for (int j = 0; j < 64; ++j) {
      float v = adjS[j * 64 + tid];            // symmetric
      s += (j == tid) ? (v + 1.0f) : v;
      if (v != 0.0f) m |= (1ull << j);
    }
    dis[tid] = 1.0f / sqrtf(fmaxf(s, 1.0f));
    nbr[b * 64 + tid] = m;
  }
  __syncthreads();
  for (int i = tid; i < 4096; i += 256) {
    int r = i >> 6, c = i & 63;
    float a = adjS[i] + ((r == c) ? 1.0f : 0.0f);
    AhS[r][c] = (dis[r] * a) * dis[c];
  }
  __syncthreads();
  unsigned short* dst = Ahat3 + (size_t)b * 12288;
  for (int ch = tid; ch < 1536; ch += 256) {
    int l15v = ch & 15, lgv = (ch >> 4) & 3, q2 = (ch >> 6) & 3, mt = (ch >> 8) & 1, s = ch >> 9;
    bf16x8 hv;
#pragma unroll
    for (int jj = 0; jj < 8; ++jj)
      hv[jj] = (short)planeOf(AhS[16 * q2 + l15v][32 * mt + 8 * lgv + jj], s);
    *(bf16x8*)&dst[(size_t)ch * 8] = hv;
  }

  // ---- maskf (blocks 0-127) ----
  if (b < 128) {
    __shared__ int s_ni, s_nf;
    if (tid == 0) { s_ni = 0; s_nf = 0; }
    __syncthreads();
    const unsigned* wp = (const unsigned*)mptr;
    int ni = 0, nf = 0;
    for (int i = tid; i < 2048; i += 256) {
      unsigned v = wp[i];
      if (v > 1u) ni = 1;
      if (v != 0u && v != 0x3f800000u) nf = 1;
    }
    if (ni) atomicOr(&s_ni, 1);
    if (nf) atomicOr(&s_nf, 1);
    __syncthreads();
    int fl = s_ni ? (s_nf ? 2 : 1) : 0;
    int i = b * 256 + tid;
    float r;
    if (fl == 0)      r = ((const int*)mptr)[i] ? 1.0f : 0.0f;
    else if (fl == 1) r = (((const float*)mptr)[i] != 0.0f) ? 1.0f : 0.0f;
    else              r = ((const unsigned char*)mptr)[i] ? 1.0f : 0.0f;
    maskf[i] = r;
  }

  // ---- setup roles (blocks 128-275) ----
  int bi = b - 128;
  if (bi >= 0 && bi < 148) {
    if (bi < 144) {
      const float* W; unsigned short* Wg; int nk, s, ks, g;
      if (bi < 48) { W = W1; Wg = Wg1; nk = 4; s = bi >> 4; ks = (bi >> 2) & 3; g = bi & 3; }
      else { int t = bi - 48; W = W2; Wg = Wg2; nk = 8; s = t >> 5; ks = (t >> 2) & 7; g = t & 3; }
      int n = tid;
      bf16x8 hv;
#pragma unroll
      for (int jj = 0; jj < 8; ++jj) {
        float v = W[(size_t)(ks * 32 + g * 8 + jj) * 256 + n];
        hv[jj] = (short)planeOf(v, s);
      }
      *(bf16x8*)&Wg[((((size_t)s * nk + ks) * 4 + g) * 256 + n) * 8] = hv;
    } else if (bi == 144) {
      int k = tid >> 3, l8 = tid & 7;
      float s = 0.0f;
      for (int m = 0; m < 32; ++m) { float v = cen[k * 256 + l8 + 8 * m]; s += v * v; }
#pragma unroll
      for (int d = 1; d < 8; d <<= 1) s += __shfl_xor(s, d, 64);
      if (l8 == 0) ccbuf[k] = s;
    } else {
      int s = bi - 145;
      for (int u = 0; u < 4; ++u) {
        int idx = tid + 256 * u;
        int ks = idx >> 7, c = (idx >> 6) & 1, rem = idx & 63;
        int l15v = rem >> 2, lgv = rem & 3;
        bf16x8 hv;
#pragma unroll
        for (int jj = 0; jj < 8; ++jj)
          hv[jj] = (short)planeOf(cen[(size_t)(16 * c + l15v) * 256 + 32 * ks + 8 * lgv + jj], s);
        *(bf16x8*)&cen3[(size_t)s * 8192 + (size_t)idx * 8] = hv;
      }
    }
  }
}

// ---------------------------------------------------------------------------
// MFMA layer: out = relu(maskf * (Ahat @ (A @ W) + bias)), fp32 via 3-way
// bf16 split (6 products). GEMM1 -> T staged through LDS one split-plane at
// a time (union with Ap) -> GEMM2 vs Ahat3 with (sA,sB) product budget
// {3,2,1} per sB plane.
// ---------------------------------------------------------------------------
__global__ __launch_bounds__(256, 2) void k_layer(const float* __restrict__ A,
                                                  const unsigned short* __restrict__ Wg,
                                                  const float* __restrict__ bias,
                                                  const unsigned short* __restrict__ Ahat3,
                                                  const float* __restrict__ maskf,
                                                  float* __restrict__ out, int nk) {
  __shared__ char smem[36864];                 // union: Ap (25.3 KB) / Tbuf (36.9 KB)
  __shared__ float biaS[256];
  __shared__ float maskS[64];
  unsigned short (*Ap)[3][2112] = (unsigned short(*)[3][2112])smem;  // [2][3][2112]
  unsigned short (*Tbuf)[72]    = (unsigned short(*)[72])smem;       // [256][72]

  int b = blockIdx.x, tid = threadIdx.x;
  int w = tid >> 6, l = tid & 63;
  int l15 = l & 15, lg = l >> 4;
  int K = nk * 32;
  const float* Ab = A + (size_t)b * 64 * K;
  biaS[tid] = bias[tid];
  if (tid < 64) maskS[tid] = maskf[b * 64 + tid];

  int srow = tid >> 2, sg = tid & 3;
  const float* sp = Ab + (size_t)srow * K + sg * 8;

  // stage K-step 0 into buffer 0
  {
    float4 v0 = *(const float4*)(sp);
    float4 v1 = *(const float4*)(sp + 4);
    float vv[8] = {v0.x, v0.y, v0.z, v0.w, v1.x, v1.y, v1.z, v1.w};
    bf16x8 p1, p2, p3;
#pragma unroll
    for (int jj = 0; jj < 8; ++jj) {
      unsigned h1, h2, h3; split3(vv[jj], h1, h2, h3);
      p1[jj] = (short)h1; p2[jj] = (short)h2; p3[jj] = (short)h3;
    }
    int off = sg * 528 + srow * 8;
    *(bf16x8*)&Ap[0][0][off] = p1;
    *(bf16x8*)&Ap[0][1][off] = p2;
    *(bf16x8*)&Ap[0][2][off] = p3;
  }
  __syncthreads();

  f32x4 acc1[4][4];
#pragma unroll
  for (int q = 0; q < 4; ++q)
#pragma unroll
    for (int c = 0; c < 4; ++c) acc1[q][c] = (f32x4){0.f, 0.f, 0.f, 0.f};

  const size_t wss = (size_t)nk * 8192;  // split-plane stride in Wg (shorts)

  for (int ks = 0; ks < nk; ++ks) {
    int cur = ks & 1;
    float4 v0, v1;
    bool pf = (ks + 1 < nk);
    if (pf) {
      v0 = *(const float4*)(sp + (ks + 1) * 32);
      v1 = *(const float4*)(sp + (ks + 1) * 32 + 4);
    }
    bf16x8 af[4][3];
#pragma unroll
    for (int q = 0; q < 4; ++q) {
      int off = lg * 528 + (16 * q + l15) * 8;
#pragma unroll
      for (int s = 0; s < 3; ++s) af[q][s] = *(const bf16x8*)&Ap[cur][s][off];
    }
#pragma unroll
    for (int c = 0; c < 4; ++c) {
      size_t wbase = (((size_t)ks * 4 + lg) * 256 + (64 * w + 16 * c + l15)) * 8;
      bf16x8 b0 = *(const bf16x8*)&Wg[wbase];
      bf16x8 b1 = *(const bf16x8*)&Wg[wbase + wss];
      bf16x8 b2 = *(const bf16x8*)&Wg[wbase + 2 * wss];
#pragma unroll
      for (int q = 0; q < 4; ++q) {
        MF6(af[q][0], af[q][1], af[q][2], b0, b1, b2, acc1[q][c]);
      }
    }
    if (pf) {
      float vv[8] = {v0.x, v0.y, v0.z, v0.w, v1.x, v1.y, v1.z, v1.w};
      bf16x8 p1, p2, p3;
#pragma unroll
      for (int jj = 0; jj < 8; ++jj) {
        unsigned h1, h2, h3; split3(vv[jj], h1, h2, h3);
        p1[jj] = (short)h1; p2[jj] = (short)h2; p3[jj] = (short)h3;
      }
      int off = sg * 528 + srow * 8;
      *(bf16x8*)&Ap[cur ^ 1][0][off] = p1;
      *(bf16x8*)&Ap[cur ^ 1][1][off] = p2;
      *(bf16x8*)&Ap[cur ^ 1][2][off] = p3;
    }
    __syncthreads();
  }

  // GEMM#2 phased over T split-planes sB; product budget nA = 3 - sB.
  f32x4 acc2[4][4];
#pragma unroll
  for (int q = 0; q < 4; ++q)
#pragma unroll
    for (int c = 0; c < 4; ++c) acc2[q][c] = (f32x4){0.f, 0.f, 0.f, 0.f};

  const unsigned short* Ah = Ahat3 + (size_t)b * 12288;
#pragma unroll
  for (int sB = 0; sB < 3; ++sB) {
    const int nA = 3 - sB;
    __syncthreads();                     // prior-phase reads (and GEMM1 Ap reads) done
#pragma unroll
    for (int q = 0; q < 4; ++q)
#pragma unroll
      for (int c = 0; c < 4; ++c) {
        u16x4 pv;
#pragma unroll
        for (int r = 0; r < 4; ++r) pv[r] = planeOf(acc1[q][c][r], sB);
        *(u16x4*)&Tbuf[64 * w + 16 * c + l15][16 * q + 4 * lg] = pv;
      }
    __syncthreads();
#pragma unroll
    for (int mt = 0; mt < 2; ++mt) {
      bf16x8 bf[4];
#pragma unroll
      for (int c = 0; c < 4; ++c)
        bf[c] = *(const bf16x8*)&Tbuf[64 * w + 16 * c + l15][32 * mt + 8 * lg];
#pragma unroll
      for (int q2 = 0; q2 < 4; ++q2) {
        bf16x8 afr[3];
#pragma unroll
        for (int sA = 0; sA < 3; ++sA)
          if (sA < nA)
            afr[sA] = *(const bf16x8*)&Ah[((((size_t)(sA * 2 + mt) * 4 + q2) * 4 + lg) * 16 + l15) * 8];
#pragma unroll
        for (int c = 0; c < 4; ++c)
#pragma unroll
          for (int sA = 0; sA < 3; ++sA)
            if (sA < nA)
              acc2[q2][c] = __builtin_amdgcn_mfma_f32_16x16x32_bf16(afr[sA], bf[c], acc2[q2][c], 0, 0, 0);
      }
    }
  }

  // epilogue: (acc + bias) * mask, relu
#pragma unroll
  for (int q2 = 0; q2 < 4; ++q2) {
#pragma unroll
    for (int c = 0; c < 4; ++c) {
      int n = 64 * w + 16 * c + l15;
      float bv = biaS[n];
#pragma unroll
      for (int r = 0; r < 4; ++r) {
        int row = 16 * q2 + 4 * lg + r;
        float val = (acc2[q2][c][r] + bv) * maskS[row];
        out[((size_t)b * 64 + row) * 256 + n] = fmaxf(val, 0.0f);
      }
    }
  }
}

// ---------------------------------------------------------------------------
// cdist + softmin + Gumbel-max: MFMA h@cenT with XOR-swizzled h in LDS,
// 4-wave K-split + LDS reduce; fp32 d2/softmax/sampling tail unchanged.
// ---------------------------------------------------------------------------
__global__ __launch_bounds__(256) void k_cdist(const float* __restrict__ h,
                                               const unsigned short* __restrict__ cen3,
                                               const float* __restrict__ ccbuf,
                                               int* __restrict__ conc,
                                               float* __restrict__ pp) {
  __shared__ float hS[16384];          // 64 KB, rows XOR-swizzled by ((row&7)<<4)
  __shared__ float Dred[4][64][36];    // 36.9 KB
  __shared__ float hhp[64][4];
  __shared__ float lgp[64][33];
  __shared__ float mxs[64], lgden[64];

  int b = blockIdx.x, tid = threadIdx.x;
  int w = tid >> 6, l = tid & 63, l15 = l & 15, lg = l >> 4;
  const float* hb = h + (size_t)b * 16384;

#pragma unroll
  for (int i = 0; i < 16; ++i) {
    int g = tid + 256 * i;
    float4 v = *(const float4*)&hb[(size_t)g * 4];
    int row = g >> 6;
    int fb = ((g & 63) * 16) ^ ((row & 7) << 4);
    *(float4*)((char*)&hS[row * 256] + fb) = v;
  }
  __syncthreads();

#define LD4(row, fbyte) (*(const float4*)((const char*)&hS[(row) * 256] + ((fbyte) ^ (((row) & 7) << 4))))

  {
    int row = tid & 63, qt = tid >> 6;
    float s = 0.0f;
    for (int u = 0; u < 16; ++u) {
      float4 v = LD4(row, qt * 256 + u * 16);
      s += v.x * v.x + v.y * v.y + v.z * v.z + v.w * v.w;
    }
    hhp[row][qt] = s;
  }

  f32x4 acc[4][2];
#pragma unroll
  for (int qt = 0; qt < 4; ++qt)
#pragma unroll
    for (int c = 0; c < 2; ++c) acc[qt][c] = (f32x4){0.f, 0.f, 0.f, 0.f};

#pragma unroll
  for (int ks2 = 0; ks2 < 2; ++ks2) {
    int ks = 2 * w + ks2;
#pragma unroll
    for (int qt = 0; qt < 4; ++qt) {
      int row = 16 * qt + l15;
      int fb = (32 * ks + 8 * lg) * 4;
      float4 v0 = LD4(row, fb);
      float4 v1 = LD4(row, fb + 16);
      float vv[8] = {v0.x, v0.y, v0.z, v0.w, v1.x, v1.y, v1.z, v1.w};
      bf16x8 a0, a1, a2;
#pragma unroll
      for (int jj = 0; jj < 8; ++jj) {
        unsigned h1, h2, h3; split3(vv[jj], h1, h2, h3);
        a0[jj] = (short)h1; a1[jj] = (short)h2; a2[jj] = (short)h3;
      }
#pragma unroll
      for (int c = 0; c < 2; ++c) {
        const unsigned short* cb = cen3 + ((size_t)(ks * 2 + c) * 64 + l15 * 4 + lg) * 8;
        bf16x8 b0 = *(const bf16x8*)cb;
        bf16x8 b1 = *(const bf16x8*)(cb + 8192);
        bf16x8 b2 = *(const bf16x8*)(cb + 16384);
        MF6(a0, a1, a2, b0, b1, b2, acc[qt][c]);
      }
    }
  }

#pragma unroll
  for (int qt = 0; qt < 4; ++qt)
#pragma unroll
    for (int c = 0; c < 2; ++c)
#pragma unroll
      for (int r = 0; r < 4; ++r)
        Dred[w][16 * qt + 4 * lg + r][16 * c + l15] = acc[qt][c][r];
  __syncthreads();

  {
    int n = tid >> 2, kq = tid & 3;
    float hh = (hhp[n][0] + hhp[n][1]) + (hhp[n][2] + hhp[n][3]);
#pragma unroll
    for (int j = 0; j < 8; ++j) {
      int k = kq * 8 + j;
      float dot = (Dred[0][n][k] + Dred[1][n][k]) + (Dred[2][n][k] + Dred[3][n][k]);
      float d2 = (hh + ccbuf[k]) - 2.0f * dot;
      lgp[n][k] = -10.0f * sqrtf(fmaxf(d2, 1e-12f));
    }
  }
  __syncthreads();

  if (tid < 64) {
    float mx = -1e30f;
    for (int k = 0; k < 32; ++k) mx = fmaxf(mx, lgp[tid][k]);
    float den = 0.0f;
    for (int k = 0; k < 32; ++k) den += expf(lgp[tid][k] - mx);
    mxs[tid] = mx; lgden[tid] = logf(den);
  }
  __syncthreads();
  for (int p = tid; p < 2048; p += 256) {
    int n = p >> 5, k = p & 31;
    lgp[n][k] = (lgp[n][k] - mxs[n]) - lgden[n];   // logp
  }
  __syncthreads();

  int hw = tid >> 5, k = tid & 31;
  for (int pass = 0; pass < 8; ++pass) {
    int n = hw * 8 + pass;
    float lp = lgp[n][k];
#pragma unroll
    for (int s4 = 0; s4 < 4; ++s4) {
      unsigned flat = (unsigned)(s4 * 32768 + b * 64 + n) * 32u + (unsigned)k;
      unsigned bits = tf_bits(flat);
      float fu = __uint_as_float((bits >> 9) | 0x3f800000u) - 1.0f;
      float u = fmaxf(TINYF, fu * (1.0f - TINYF) + TINYF);
      float g = -logf(-logf(u));
      float v = lp + g;
      int bi = k;
#pragma unroll
      for (int d = 1; d < 32; d <<= 1) {        // max, first-index ties
        float ov = __shfl_xor(v, d, 32);
        int oi = __shfl_xor(bi, d, 32);
        if (ov > v || (ov == v && oi < bi)) { v = ov; bi = oi; }
      }
      if (k == 0) {
        conc[s4 * 32768 + b * 64 + n] = bi;
        pp[s4 * 32768 + b * 64 + n] = expf(lgp[n][bi]);
      }
    }
  }
#undef LD4
}

// ---------------------------------------------------------------------------
// Per (s,b): CC min-label fixpoint + graph_prob + labels + pooled adjacency
// + fused scatter-mean new_x (clmask stays in LDS).
// ---------------------------------------------------------------------------
__global__ __launch_bounds__(256) void k_postx(const int* __restrict__ conc,
                                               const float* __restrict__ pp,
                                               const float* __restrict__ maskf,
                                               const unsigned long long* __restrict__ nbr,
                                               const float* __restrict__ h,
                                               float* __restrict__ out_gp,
                                               float* __restrict__ out_lab,
                                               float* __restrict__ out_newadj,
                                               float* __restrict__ out_newx) {
  int sb = blockIdx.x, b = sb & 511, tid = threadIdx.x;
  __shared__ int cs[64];
  __shared__ int lab[64];
  __shared__ unsigned long long sm_[64];
  __shared__ unsigned long long nbs[64];
  __shared__ unsigned long long clmaskS[64];
  __shared__ float o[4096];
  __shared__ int chg;

  for (int i = tid; i < 4096; i += 256) o[i] = 0.0f;
  bool mk = false;
  if (tid < 64) {
    cs[tid] = conc[sb * 64 + tid];
    nbs[tid] = nbr[b * 64 + tid];
    mk = maskf[b * 64 + tid] != 0.0f;
    lab[tid] = tid + 1;
  }
  if (tid == 0) chg = 0;
  __syncthreads();
  if (tid < 64) {
    unsigned long long nb = nbs[tid], s = 0ull;
    int c = cs[tid];
    while (nb) { int j = __ffsll(nb) - 1; if (cs[j] == c) s |= (1ull << j); nb &= nb - 1; }
    sm_[tid] = s;
  }
  __syncthreads();
  for (int it = 0; it < 64; ++it) {
    int m = 0;
    if (tid < 64) {
      m = lab[tid];
      unsigned long long t = sm_[tid];
      while (t) { int j = __ffsll(t) - 1; m = min(m, lab[j]); t &= t - 1; }
    }
    __syncthreads();
    if (tid < 64 && m < lab[tid]) { lab[tid] = m; chg = 1; }
    __syncthreads();
    if (chg == 0) break;
    __syncthreads();
    if (tid == 0) chg = 0;
  }
  if (tid < 64) {
    int lf = mk ? lab[tid] : 0;
    cs[tid] = lf;
    out_lab[sb * 64 + tid] = (float)lf;
    float pv = mk ? pp[sb * 64 + tid] : 1.0f;
#pragma unroll
    for (int d = 1; d < 64; d <<= 1) pv *= __shfl_xor(pv, d, 64);
    if (tid == 0) out_gp[sb] = pv;
  }
  __syncthreads();
  if (tid < 64) {
    unsigned long long cm = 0ull;
    for (int j = 0; j < 64; ++j)
      if (cs[j] == tid + 1) cm |= (1ull << j);
    clmaskS[tid] = cm;
  }
  for (int p = tid; p < 4096; p += 256) {
    int i = p >> 6, j = p & 63;
    int li = cs[i], lj = cs[j];
    if (li > 0 && lj > 0 && ((nbs[i] >> j) & 1ull))
      o[(li - 1) * 64 + (lj - 1)] = 1.0f;
  }
  __syncthreads();
  float* dst = out_newadj + (size_t)sb * 4096;
  for (int i = tid; i < 1024; i += 256) {
    fx4 v = ((const fx4*)o)[i];
    __builtin_nontemporal_store(v, (fx4*)dst + i);
  }

  // fused new_x: mean over cluster-(c+1) members of h[b]
  int q = tid & 63, cp = tid >> 6;
  const float* hb = h + (size_t)b * 16384;
  for (int step = 0; step < 16; ++step) {
    int c = cp * 16 + step;
    unsigned long long m = clmaskS[c];
    float4 acc = make_float4(0.f, 0.f, 0.f, 0.f);
    unsigned long long t = m;
    while (t) {
      int j = __ffsll(t) - 1; t &= t - 1;
      float4 v = *(const float4*)&hb[j * 256 + q * 4];
      acc.x += v.x; acc.y += v.y; acc.z += v.z; acc.w += v.w;
    }
    int cnt = __popcll(m);
    float cf = (float)(cnt > 0 ? cnt : 1);
    fx4 r;
    r.x = acc.x / cf; r.y = acc.y / cf; r.z = acc.z / cf; r.w = acc.w / cf;
    __builtin_nontemporal_store(r, (fx4*)&out_newx[((size_t)sb * 64 + c) * 256 + q * 4]);
  }
}

// ---------------------------------------------------------------------------
extern "C" void kernel_launch(void* const* d_in, const int* in_sizes, int n_in,
                              void* d_out, int out_size, void* d_ws, size_t ws_size,
                              hipStream_t stream) {
  (void)in_sizes; (void)n_in; (void)out_size; (void)ws_size;
  const float* x   = (const float*)d_in[0];
  const float* adj = (const float*)d_in[1];
  const void*  mp  = d_in[2];
  const float* W1  = (const float*)d_in[3];
  const float* b1  = (const float*)d_in[4];
  const float* W2  = (const float*)d_in[5];
  const float* b2  = (const float*)d_in[6];
  const float* cen = (const float*)d_in[7];

  char* ws = (char*)d_ws;
  unsigned short* Ahat3 = (unsigned short*)(ws + 0);                 // 12,582,912
  unsigned short* Wg1   = (unsigned short*)(ws + 12582912);          // 196,608
  unsigned short* Wg2   = (unsigned short*)(ws + 12779520);          // 393,216
  unsigned short* cen3  = (unsigned short*)(ws + 13172736);          // 49,152
  float* ccbuf          = (float*)(ws + 13221888);                   // 128
  unsigned long long* nbr = (unsigned long long*)(ws + 13222016);    // 262,144
  float* maskf          = (float*)(ws + 13484160);                   // 131,072
  int*   conc           = (int*)(ws + 13615232);                     // 524,288
  float* pp             = (float*)(ws + 14139520);                   // 524,288
  float* bufB           = (float*)(ws + 16777216);                   // 33,554,432 (h)

  float* out        = (float*)d_out;
  float* out_newx   = out;                 // 2048*64*256
  float* out_newadj = out + 33554432;      // 2048*64*64
  float* out_gp     = out + 41943040;      // 2048
  float* out_lab    = out + 41945088;      // 2048*64
  float* bufA       = out;                 // h1 scratch; overwritten by k_postx last

  hipLaunchKernelGGL(k_init,  dim3(512), dim3(256), 0, stream, adj, mp, W1, W2, cen,
                     Ahat3, nbr, maskf, Wg1, Wg2, cen3, ccbuf);
  hipLaunchKernelGGL(k_layer, dim3(512), dim3(256), 0, stream, x,    Wg1, b1, Ahat3, maskf, bufA, 4);
  hipLaunchKernelGGL(k_layer, dim3(512), dim3(256), 0, stream, bufA, Wg2, b2, Ahat3, maskf, bufB, 8);
  hipLaunchKernelGGL(k_cdist, dim3(512), dim3(256), 0, stream, bufB, cen3, ccbuf, conc, pp);
  hipLaunchKernelGGL(k_postx, dim3(2048), dim3(256), 0, stream, conc, pp, maskf, nbr, bufB,
                     out_gp, out_lab, out_newadj, out_newx);
}

// Round 7
// 180.142 us; speedup vs baseline: 1.8521x; 1.0025x over previous
//
#include <hip/hip_runtime.h>

#define B_    512

static constexpr float TINYF = 1.17549435e-38f;
typedef float fx4  __attribute__((ext_vector_type(4)));
typedef short bf16x8 __attribute__((ext_vector_type(8)));
typedef float f32x4 __attribute__((ext_vector_type(4)));
typedef unsigned short u16x4 __attribute__((ext_vector_type(4)));

// ---------------------------------------------------------------------------
// Threefry-2x32, key = (0, 42), partitionable path: bits(i) = y0^y1 of
// cipher(hi=0, lo=i).
// ---------------------------------------------------------------------------
__device__ __forceinline__ unsigned tf_bits(unsigned lo) {
  const unsigned ks0 = 0u, ks1 = 42u, ks2 = 0x1BD11BF0u;
  unsigned x0 = 0u + ks0;
  unsigned x1 = lo + ks1;
#define TFR(r) { x0 += x1; x1 = (x1 << r) | (x1 >> (32 - r)); x1 ^= x0; }
  TFR(13) TFR(15) TFR(26) TFR(6)
  x0 += ks1; x1 += ks2 + 1u;
  TFR(17) TFR(29) TFR(16) TFR(24)
  x0 += ks2; x1 += ks0 + 2u;
  TFR(13) TFR(15) TFR(26) TFR(6)
  x0 += ks0; x1 += ks1 + 3u;
  TFR(17) TFR(29) TFR(16) TFR(24)
  x0 += ks1; x1 += ks2 + 4u;
  TFR(13) TFR(15) TFR(26) TFR(6)
  x0 += ks2; x1 += ks0 + 5u;
#undef TFR
  return x0 ^ x1;
}

// Exact fp32 -> 3x bf16 split (truncation; v == v1+v2+v3 exactly for normals)
__device__ __forceinline__ void split3(float v, unsigned& b1, unsigned& b2, unsigned& b3) {
  unsigned u1 = __float_as_uint(v) & 0xFFFF0000u;
  float r1 = v - __uint_as_float(u1);
  unsigned u2 = __float_as_uint(r1) & 0xFFFF0000u;
  float r2 = r1 - __uint_as_float(u2);
  unsigned u3 = __float_as_uint(r2) & 0xFFFF0000u;
  b1 = u1 >> 16; b2 = u2 >> 16; b3 = u3 >> 16;
}

// plane s of the split
__device__ __forceinline__ unsigned short planeOf(float v, int s) {
  unsigned u1 = __float_as_uint(v) & 0xFFFF0000u;
  if (s == 0) return (unsigned short)(u1 >> 16);
  float r1 = v - __uint_as_float(u1);
  unsigned u2 = __float_as_uint(r1) & 0xFFFF0000u;
  if (s == 1) return (unsigned short)(u2 >> 16);
  float r2 = r1 - __uint_as_float(u2);
  return (unsigned short)((__float_as_uint(r2) & 0xFFFF0000u) >> 16);
}

// 6-product split accumulation (drops terms <= 2^-27 relative)
#define MF6(A0, A1, A2, Bv0, Bv1, Bv2, ACC)                                   \
  ACC = __builtin_amdgcn_mfma_f32_16x16x32_bf16(A0, Bv0, ACC, 0, 0, 0);       \
  ACC = __builtin_amdgcn_mfma_f32_16x16x32_bf16(A0, Bv1, ACC, 0, 0, 0);       \
  ACC = __builtin_amdgcn_mfma_f32_16x16x32_bf16(A1, Bv0, ACC, 0, 0, 0);       \
  ACC = __builtin_amdgcn_mfma_f32_16x16x32_bf16(A0, Bv2, ACC, 0, 0, 0);       \
  ACC = __builtin_amdgcn_mfma_f32_16x16x32_bf16(A1, Bv1, ACC, 0, 0, 0);       \
  ACC = __builtin_amdgcn_mfma_f32_16x16x32_bf16(A2, Bv0, ACC, 0, 0, 0);

// ---------------------------------------------------------------------------
// Setup: W1/W2 split planes, centroid norms, centroid split planes.
// ---------------------------------------------------------------------------
__global__ void k_setup(const float* __restrict__ W1, const float* __restrict__ W2,
                        const float* __restrict__ cen,
                        unsigned short* __restrict__ Wg1, unsigned short* __restrict__ Wg2,
                        unsigned short* __restrict__ cen3, float* __restrict__ ccbuf) {
  int bi = blockIdx.x, tid = threadIdx.x;
  if (bi < 144) {
    const float* W; unsigned short* Wg; int nk, s, ks, g;
    if (bi < 48) { W = W1; Wg = Wg1; nk = 4; s = bi >> 4; ks = (bi >> 2) & 3; g = bi & 3; }
    else { int t = bi - 48; W = W2; Wg = Wg2; nk = 8; s = t >> 5; ks = (t >> 2) & 7; g = t & 3; }
    int n = tid;
    bf16x8 hv;
#pragma unroll
    for (int jj = 0; jj < 8; ++jj) {
      float v = W[(size_t)(ks * 32 + g * 8 + jj) * 256 + n];
      hv[jj] = (short)planeOf(v, s);
    }
    *(bf16x8*)&Wg[((((size_t)s * nk + ks) * 4 + g) * 256 + n) * 8] = hv;
  } else if (bi == 144) {
    int k = tid >> 3, l8 = tid & 7;
    float s = 0.0f;
    for (int m = 0; m < 32; ++m) { float v = cen[k * 256 + l8 + 8 * m]; s += v * v; }
#pragma unroll
    for (int d = 1; d < 8; d <<= 1) s += __shfl_xor(s, d, 64);
    if (l8 == 0) ccbuf[k] = s;
  } else {
    int s = bi - 145;
    for (int u = 0; u < 4; ++u) {
      int idx = tid + 256 * u;
      int ks = idx >> 7, c = (idx >> 6) & 1, rem = idx & 63;
      int l15v = rem >> 2, lgv = rem & 3;
      bf16x8 hv;
#pragma unroll
      for (int jj = 0; jj < 8; ++jj)
        hv[jj] = (short)planeOf(cen[(size_t)(16 * c + l15v) * 256 + 32 * ks + 8 * lgv + jj], s);
      *(bf16x8*)&cen3[(size_t)s * 8192 + (size_t)idx * 8] = hv;
    }
  }
}

// ---------------------------------------------------------------------------
// Layer core: hdst = relu(maskS * (Ahat @ (A @ W) + biaS)).  A from global
// (SRCL=false) or from hbuf LDS (SRCL=true).  Ahat from LDS split planes.
// ---------------------------------------------------------------------------
template<bool SRCL>
__device__ __forceinline__ void layer_core(const float* __restrict__ Aglob,
                                           const float (*hsrc)[260],
                                           float (*hdst)[260],
                                           const unsigned short* __restrict__ Wg, int nk,
                                           const unsigned short* AhP,
                                           const float* biaS, const float* maskS,
                                           char* U, int tid) {
  unsigned short (*Ap)[3][2112] = (unsigned short(*)[3][2112])U;  // [2][3][2112]
  unsigned short (*Tbuf)[72]    = (unsigned short(*)[72])U;       // [256][72]
  int w = tid >> 6, l = tid & 63;
  int l15 = l & 15, lg = l >> 4;
  int K = nk * 32;
  int srow = tid >> 2, sg = tid & 3;
  const float* sp = SRCL ? (const float*)nullptr : (Aglob + (size_t)srow * K + sg * 8);

  // stage K-step 0 into buffer 0
  {
    float vv[8];
    if (SRCL) {
      float4 v0 = *(const float4*)&hsrc[srow][sg * 8];
      float4 v1 = *(const float4*)&hsrc[srow][sg * 8 + 4];
      vv[0] = v0.x; vv[1] = v0.y; vv[2] = v0.z; vv[3] = v0.w;
      vv[4] = v1.x; vv[5] = v1.y; vv[6] = v1.z; vv[7] = v1.w;
    } else {
      float4 v0 = *(const float4*)(sp);
      float4 v1 = *(const float4*)(sp + 4);
      vv[0] = v0.x; vv[1] = v0.y; vv[2] = v0.z; vv[3] = v0.w;
      vv[4] = v1.x; vv[5] = v1.y; vv[6] = v1.z; vv[7] = v1.w;
    }
    bf16x8 p1, p2, p3;
#pragma unroll
    for (int jj = 0; jj < 8; ++jj) {
      unsigned h1, h2, h3; split3(vv[jj], h1, h2, h3);
      p1[jj] = (short)h1; p2[jj] = (short)h2; p3[jj] = (short)h3;
    }
    int off = sg * 528 + srow * 8;
    *(bf16x8*)&Ap[0][0][off] = p1;
    *(bf16x8*)&Ap[0][1][off] = p2;
    *(bf16x8*)&Ap[0][2][off] = p3;
  }
  __syncthreads();

  f32x4 acc1[4][4];
#pragma unroll
  for (int q = 0; q < 4; ++q)
#pragma unroll
    for (int c = 0; c < 4; ++c) acc1[q][c] = (f32x4){0.f, 0.f, 0.f, 0.f};

  const size_t wss = (size_t)nk * 8192;

  for (int ks = 0; ks < nk; ++ks) {
    int cur = ks & 1;
    float vv[8];
    bool pf = (ks + 1 < nk);
    if (pf) {
      if (SRCL) {
        float4 v0 = *(const float4*)&hsrc[srow][(ks + 1) * 32 + sg * 8];
        float4 v1 = *(const float4*)&hsrc[srow][(ks + 1) * 32 + sg * 8 + 4];
        vv[0] = v0.x; vv[1] = v0.y; vv[2] = v0.z; vv[3] = v0.w;
        vv[4] = v1.x; vv[5] = v1.y; vv[6] = v1.z; vv[7] = v1.w;
      } else {
        float4 v0 = *(const float4*)(sp + (ks + 1) * 32);
        float4 v1 = *(const float4*)(sp + (ks + 1) * 32 + 4);
        vv[0] = v0.x; vv[1] = v0.y; vv[2] = v0.z; vv[3] = v0.w;
        vv[4] = v1.x; vv[5] = v1.y; vv[6] = v1.z; vv[7] = v1.w;
      }
    }
    bf16x8 af[4][3];
#pragma unroll
    for (int q = 0; q < 4; ++q) {
      int off = lg * 528 + (16 * q + l15) * 8;
#pragma unroll
      for (int s = 0; s < 3; ++s) af[q][s] = *(const bf16x8*)&Ap[cur][s][off];
    }
#pragma unroll
    for (int c = 0; c < 4; ++c) {
      size_t wbase = (((size_t)ks * 4 + lg) * 256 + (64 * w + 16 * c + l15)) * 8;
      bf16x8 b0 = *(const bf16x8*)&Wg[wbase];
      bf16x8 b1 = *(const bf16x8*)&Wg[wbase + wss];
      bf16x8 b2 = *(const bf16x8*)&Wg[wbase + 2 * wss];
#pragma unroll
      for (int q = 0; q < 4; ++q) {
        MF6(af[q][0], af[q][1], af[q][2], b0, b1, b2, acc1[q][c]);
      }
    }
    if (pf) {
      bf16x8 p1, p2, p3;
#pragma unroll
      for (int jj = 0; jj < 8; ++jj) {
        unsigned h1, h2, h3; split3(vv[jj], h1, h2, h3);
        p1[jj] = (short)h1; p2[jj] = (short)h2; p3[jj] = (short)h3;
      }
      int off = sg * 528 + srow * 8;
      *(bf16x8*)&Ap[cur ^ 1][0][off] = p1;
      *(bf16x8*)&Ap[cur ^ 1][1][off] = p2;
      *(bf16x8*)&Ap[cur ^ 1][2][off] = p3;
    }
    __syncthreads();
  }

  // GEMM#2 phased over T split-planes sB; product budget nA = 3 - sB.
  f32x4 acc2[4][4];
#pragma unroll
  for (int q = 0; q < 4; ++q)
#pragma unroll
    for (int c = 0; c < 4; ++c) acc2[q][c] = (f32x4){0.f, 0.f, 0.f, 0.f};

#pragma unroll
  for (int sB = 0; sB < 3; ++sB) {
    const int nA = 3 - sB;
    __syncthreads();
#pragma unroll
    for (int q = 0; q < 4; ++q)
#pragma unroll
      for (int c = 0; c < 4; ++c) {
        u16x4 pv;
#pragma unroll
        for (int r = 0; r < 4; ++r) pv[r] = planeOf(acc1[q][c][r], sB);
        *(u16x4*)&Tbuf[64 * w + 16 * c + l15][16 * q + 4 * lg] = pv;
      }
    __syncthreads();
#pragma unroll
    for (int mt = 0; mt < 2; ++mt) {
      bf16x8 bf[4];
#pragma unroll
      for (int c = 0; c < 4; ++c)
        bf[c] = *(const bf16x8*)&Tbuf[64 * w + 16 * c + l15][32 * mt + 8 * lg];
#pragma unroll
      for (int q2 = 0; q2 < 4; ++q2) {
        bf16x8 afr[3];
#pragma unroll
        for (int sA = 0; sA < 3; ++sA)
          if (sA < nA)
            afr[sA] = *(const bf16x8*)&AhP[((((size_t)(sA * 2 + mt) * 4 + q2) * 4 + lg) * 16 + l15) * 8];
#pragma unroll
        for (int c = 0; c < 4; ++c)
#pragma unroll
          for (int sA = 0; sA < 3; ++sA)
            if (sA < nA)
              acc2[q2][c] = __builtin_amdgcn_mfma_f32_16x16x32_bf16(afr[sA], bf[c], acc2[q2][c], 0, 0, 0);
      }
    }
  }

  // epilogue into hdst (LDS)
#pragma unroll
  for (int q2 = 0; q2 < 4; ++q2) {
#pragma unroll
    for (int c = 0; c < 4; ++c) {
      int n = 64 * w + 16 * c + l15;
      float bv = biaS[n];
#pragma unroll
      for (int r = 0; r < 4; ++r) {
        int row = 16 * q2 + 4 * lg + r;
        hdst[row][n] = fmaxf((acc2[q2][c][r] + bv) * maskS[row], 0.0f);
      }
    }
  }
}

// ---------------------------------------------------------------------------
// Mega kernel: per-batch block does prep -> layer1 -> layer2 -> cdist+sample
// -> per-wave CC/newadj/newx.  All intermediates stay in LDS.
// ---------------------------------------------------------------------------
__global__ __launch_bounds__(256, 1) void k_mega(
    const float* __restrict__ x, const float* __restrict__ adj,
    const void* __restrict__ mp,
    const float* __restrict__ b1v, const float* __restrict__ b2v,
    const unsigned short* __restrict__ Wg1, const unsigned short* __restrict__ Wg2,
    const unsigned short* __restrict__ cen3, const float* __restrict__ ccbuf,
    float* __restrict__ out_newx, float* __restrict__ out_newadj,
    float* __restrict__ out_gp, float* __restrict__ out_lab) {
  __shared__ float hbuf[64][260];            // 66,560 (h1 then h; stride 260 -> b128-optimal banks)
  __shared__ unsigned short AhP[12288];      // 24,576 Ahat split planes
  __shared__ float maskS[64];
  __shared__ float biaS[256];
  __shared__ unsigned long long nbrS[64];
  __shared__ int concS[4][64];
  __shared__ float ppS[4][64];
  __shared__ float hhp[64][4];
  __shared__ float mxs[64], lgden[64];
  __shared__ int labFS[4][64];
  __shared__ int s_ni, s_nf;
  __shared__ __align__(16) char U[46592];    // union: prep 33.3K / layers 36.9K / cdist 45.3K / post 16.4K

  int b = blockIdx.x, tid = threadIdx.x;

  // ===== phase 0: prep (Ahat planes, nbr, maskf, bias1) =====
  {
    float* adjS = (float*)U;
    float (*AhS)[65] = (float(*)[65])(U + 16384);
    float* dis = (float*)(U + 33024);
    if (tid == 0) { s_ni = 0; s_nf = 0; }
    const float* ab = adj + (size_t)b * 4096;
    for (int i = tid; i < 4096; i += 256) adjS[i] = ab[i];
    {
      const unsigned* wp = (const unsigned*)mp;
      int ni = 0, nf = 0;
      for (int i = tid; i < 2048; i += 256) {
        unsigned v = wp[i];
        if (v > 1u) ni = 1;
        if (v != 0u && v != 0x3f800000u) nf = 1;
      }
      if (ni) atomicOr(&s_ni, 1);
      if (nf) atomicOr(&s_nf, 1);
    }
    biaS[tid] = b1v[tid];
    __syncthreads();
    if (tid < 64) {
      float s = 0.0f;
      unsigned long long m = 0ull;
      for (int j = 0; j < 64; ++j) {
        float v = adjS[j * 64 + tid];          // symmetric
        s += (j == tid) ? (v + 1.0f) : v;
        if (v != 0.0f) m |= (1ull << j);
      }
      dis[tid] = 1.0f / sqrtf(fmaxf(s, 1.0f));
      nbrS[tid] = m;
      int fl = s_ni ? (s_nf ? 2 : 1) : 0;
      int i = b * 64 + tid;
      float r;
      if (fl == 0)      r = ((const int*)mp)[i] ? 1.0f : 0.0f;
      else if (fl == 1) r = (((const float*)mp)[i] != 0.0f) ? 1.0f : 0.0f;
      else              r = ((const unsigned char*)mp)[i] ? 1.0f : 0.0f;
      maskS[tid] = r;
    }
    __syncthreads();
    for (int i = tid; i < 4096; i += 256) {
      int r = i >> 6, c = i & 63;
      float a = adjS[i] + ((r == c) ? 1.0f : 0.0f);
      AhS[r][c] = (dis[r] * a) * dis[c];
    }
    __syncthreads();
    for (int ch = tid; ch < 1536; ch += 256) {
      int l15v = ch & 15, lgv = (ch >> 4) & 3, q2 = (ch >> 6) & 3, mt = (ch >> 8) & 1, s = ch >> 9;
      bf16x8 hv;
#pragma unroll
      for (int jj = 0; jj < 8; ++jj)
        hv[jj] = (short)planeOf(AhS[16 * q2 + l15v][32 * mt + 8 * lgv + jj], s);
      *(bf16x8*)&AhP[(size_t)ch * 8] = hv;
    }
    __syncthreads();
  }

  // ===== phase 1: layer1 (x -> h1 in hbuf) =====
  layer_core<false>(x + (size_t)b * 64 * 128, nullptr, hbuf, Wg1, 4, AhP, biaS, maskS, U, tid);
  __syncthreads();
  biaS[tid] = b2v[tid];

  // ===== phase 2: layer2 (hbuf -> h in hbuf) =====
  layer_core<true>(nullptr, (const float(*)[260])hbuf, hbuf, Wg2, 8, AhP, biaS, maskS, U, tid);
  __syncthreads();

  // ===== phase 3: cdist + softmin + Gumbel-max sampling =====
  {
    float (*Dred)[64][36] = (float(*)[64][36])U;        // 36,864
    float (*lgp)[33] = (float(*)[33])(U + 36864);       // 8,448
    int w = tid >> 6, l = tid & 63, l15 = l & 15, lg = l >> 4;

    {
      int row = tid & 63, qt = tid >> 6;
      float s = 0.0f;
      for (int u = 0; u < 16; ++u) {
        float4 v = *(const float4*)&hbuf[row][qt * 64 + u * 4];
        s += v.x * v.x + v.y * v.y + v.z * v.z + v.w * v.w;
      }
      hhp[row][qt] = s;
    }

    f32x4 acc[4][2];
#pragma unroll
    for (int qt = 0; qt < 4; ++qt)
#pragma unroll
      for (int c = 0; c < 2; ++c) acc[qt][c] = (f32x4){0.f, 0.f, 0.f, 0.f};

#pragma unroll
    for (int ks2 = 0; ks2 < 2; ++ks2) {
      int ks = 2 * w + ks2;
#pragma unroll
      for (int qt = 0; qt < 4; ++qt) {
        int row = 16 * qt + l15;
        float4 v0 = *(const float4*)&hbuf[row][32 * ks + 8 * lg];
        float4 v1 = *(const float4*)&hbuf[row][32 * ks + 8 * lg + 4];
        float vv[8] = {v0.x, v0.y, v0.z, v0.w, v1.x, v1.y, v1.z, v1.w};
        bf16x8 a0, a1, a2;
#pragma unroll
        for (int jj = 0; jj < 8; ++jj) {
          unsigned h1, h2, h3; split3(vv[jj], h1, h2, h3);
          a0[jj] = (short)h1; a1[jj] = (short)h2; a2[jj] = (short)h3;
        }
#pragma unroll
        for (int c = 0; c < 2; ++c) {
          const unsigned short* cb = cen3 + ((size_t)(ks * 2 + c) * 64 + l15 * 4 + lg) * 8;
          bf16x8 b0 = *(const bf16x8*)cb;
          bf16x8 b1 = *(const bf16x8*)(cb + 8192);
          bf16x8 b2 = *(const bf16x8*)(cb + 16384);
          MF6(a0, a1, a2, b0, b1, b2, acc[qt][c]);
        }
      }
    }

#pragma unroll
    for (int qt = 0; qt < 4; ++qt)
#pragma unroll
      for (int c = 0; c < 2; ++c)
#pragma unroll
        for (int r = 0; r < 4; ++r)
          Dred[w][16 * qt + 4 * lg + r][16 * c + l15] = acc[qt][c][r];
    __syncthreads();

    {
      int n = tid >> 2, kq = tid & 3;
      float hh = (hhp[n][0] + hhp[n][1]) + (hhp[n][2] + hhp[n][3]);
#pragma unroll
      for (int j = 0; j < 8; ++j) {
        int k = kq * 8 + j;
        float dot = (Dred[0][n][k] + Dred[1][n][k]) + (Dred[2][n][k] + Dred[3][n][k]);
        float d2 = (hh + ccbuf[k]) - 2.0f * dot;
        lgp[n][k] = -10.0f * sqrtf(fmaxf(d2, 1e-12f));
      }
    }
    __syncthreads();

    if (tid < 64) {
      float mx = -1e30f;
      for (int k = 0; k < 32; ++k) mx = fmaxf(mx, lgp[tid][k]);
      float den = 0.0f;
      for (int k = 0; k < 32; ++k) den += expf(lgp[tid][k] - mx);
      mxs[tid] = mx; lgden[tid] = logf(den);
    }
    __syncthreads();
    for (int p = tid; p < 2048; p += 256) {
      int n = p >> 5, k = p & 31;
      lgp[n][k] = (lgp[n][k] - mxs[n]) - lgden[n];
    }
    __syncthreads();

    int hw = tid >> 5, k = tid & 31;
    for (int pass = 0; pass < 8; ++pass) {
      int n = hw * 8 + pass;
      float lp = lgp[n][k];
#pragma unroll
      for (int s4 = 0; s4 < 4; ++s4) {
        unsigned flat = (unsigned)(s4 * 32768 + b * 64 + n) * 32u + (unsigned)k;
        unsigned bits = tf_bits(flat);
        float fu = __uint_as_float((bits >> 9) | 0x3f800000u) - 1.0f;
        float u = fmaxf(TINYF, fu * (1.0f - TINYF) + TINYF);
        float g = -logf(-logf(u));
        float v = lp + g;
        int bi = k;
#pragma unroll
        for (int d = 1; d < 32; d <<= 1) {      // max, first-index ties
          float ov = __shfl_xor(v, d, 32);
          int oi = __shfl_xor(bi, d, 32);
          if (ov > v || (ov == v && oi < bi)) { v = ov; bi = oi; }
        }
        if (k == 0) {
          concS[s4][n] = bi;
          ppS[s4][n] = expf(lgp[n][bi]);
        }
      }
    }
    __syncthreads();
  }

  // ===== phase 4: per-wave (sample = wave) CC + outputs =====
  {
    unsigned char (*o)[4096] = (unsigned char(*)[4096])U;  // 16,384
    int s = tid >> 6, lane = tid & 63;
    int sbo = s * 512 + b;
    int c0 = concS[s][lane];
    bool mk = maskS[lane] != 0.0f;
    unsigned long long nb = nbrS[lane];
    unsigned long long sm = 0ull;
    {
      unsigned long long t = nb;
      while (t) { int j = __ffsll(t) - 1; if (concS[s][j] == c0) sm |= (1ull << j); t &= t - 1; }
    }
    labFS[s][lane] = lane + 1;                  // wave-lockstep Jacobi fixpoint
    for (int it = 0; it < 64; ++it) {
      int m = labFS[s][lane];
      unsigned long long t = sm;
      while (t) { int j = __ffsll(t) - 1; m = min(m, labFS[s][j]); t &= t - 1; }
      bool ch = m < labFS[s][lane];
      if (ch) labFS[s][lane] = m;
      if (!__any(ch)) break;
    }
    int lf = mk ? labFS[s][lane] : 0;
    out_lab[(size_t)sbo * 64 + lane] = (float)lf;
    float pv = mk ? ppS[s][lane] : 1.0f;
#pragma unroll
    for (int d = 1; d < 64; d <<= 1) pv *= __shfl_xor(pv, d, 64);
    if (lane == 0) out_gp[sbo] = pv;
    labFS[s][lane] = lf;                        // final masked labels (lockstep)
    // cluster bitmask: lane acts as cluster id
    unsigned long long cm = 0ull;
    for (int j = 0; j < 64; ++j)
      if (labFS[s][j] == lane + 1) cm |= (1ull << j);
    // pooled adjacency (byte bitmap per sample)
    {
      unsigned* op = (unsigned*)o[s];
#pragma unroll
      for (int u = 0; u < 16; ++u) op[u * 64 + lane] = 0u;
      int li = lf;
      if (li > 0) {
        unsigned long long t = nb;
        while (t) {
          int j = __ffsll(t) - 1; t &= t - 1;
          int lj = labFS[s][j];
          if (lj > 0) o[s][(li - 1) * 64 + (lj - 1)] = 1;
        }
      }
      float* dA = out_newadj + (size_t)sbo * 4096;
#pragma unroll
      for (int u = 0; u < 16; ++u) {
        int base = u * 256 + lane * 4;
        fx4 v;
        v.x = o[s][base + 0] ? 1.0f : 0.0f;
        v.y = o[s][base + 1] ? 1.0f : 0.0f;
        v.z = o[s][base + 2] ? 1.0f : 0.0f;
        v.w = o[s][base + 3] ? 1.0f : 0.0f;
        __builtin_nontemporal_store(v, (fx4*)&dA[base]);
      }
    }
    // scatter-mean new_x from hbuf
    float* dX = out_newx + (size_t)sbo * 64 * 256;
    for (int c = 0; c < 64; ++c) {
      unsigned long long m = __shfl(cm, c, 64);
      float4 acc = make_float4(0.f, 0.f, 0.f, 0.f);
      unsigned long long t = m;
      while (t) {
        int j = __ffsll(t) - 1; t &= t - 1;
        float4 v = *(const float4*)&hbuf[j][lane * 4];
        acc.x += v.x; acc.y += v.y; acc.z += v.z; acc.w += v.w;
      }
      int cnt = __popcll(m);
      float cf = (float)(cnt > 0 ? cnt : 1);
      fx4 r;
      r.x = acc.x / cf; r.y = acc.y / cf; r.z = acc.z / cf; r.w = acc.w / cf;
      __builtin_nontemporal_store(r, (fx4*)&dX[(size_t)c * 256 + lane * 4]);
    }
  }
}

// ---------------------------------------------------------------------------
extern "C" void kernel_launch(void* const* d_in, const int* in_sizes, int n_in,
                              void* d_out, int out_size, void* d_ws, size_t ws_size,
                              hipStream_t stream) {
  (void)in_sizes; (void)n_in; (void)out_size; (void)ws_size;
  const float* x   = (const float*)d_in[0];
  const float* adj = (const float*)d_in[1];
  const void*  mp  = d_in[2];
  const float* W1  = (const float*)d_in[3];
  const float* b1  = (const float*)d_in[4];
  const float* W2  = (const float*)d_in[5];
  const float* b2  = (const float*)d_in[6];
  const float* cen = (const float*)d_in[7];

  char* ws = (char*)d_ws;
  unsigned short* Wg1  = (unsigned short*)(ws + 0);        // 196,608
  unsigned short* Wg2  = (unsigned short*)(ws + 196608);   // 393,216
  unsigned short* cen3 = (unsigned short*)(ws + 589824);   // 49,152
  float* ccbuf         = (float*)(ws + 638976);            // 128

  float* out        = (float*)d_out;
  float* out_newx   = out;                 // 2048*64*256
  float* out_newadj = out + 33554432;      // 2048*64*64
  float* out_gp     = out + 41943040;      // 2048
  float* out_lab    = out + 41945088;      // 2048*64

  hipLaunchKernelGGL(k_setup, dim3(148), dim3(256), 0, stream, W1, W2, cen, Wg1, Wg2, cen3, ccbuf);
  hipLaunchKernelGGL(k_mega,  dim3(512), dim3(256), 0, stream, x, adj, mp, b1, b2,
                     Wg1, Wg2, cen3, ccbuf, out_newx, out_newadj, out_gp, out_lab);
}

// Round 8
// 170.335 us; speedup vs baseline: 1.9588x; 1.0576x over previous
//
#include <hip/hip_runtime.h>

#define B_    512

static constexpr float TINYF = 1.17549435e-38f;
typedef float fx4  __attribute__((ext_vector_type(4)));
typedef short bf16x8 __attribute__((ext_vector_type(8)));
typedef float f32x4 __attribute__((ext_vector_type(4)));
typedef unsigned short u16x4 __attribute__((ext_vector_type(4)));

// Contraction-pinned fp32 ops (RN, no fma fusion possible across these).
__device__ __forceinline__ float fmul_s(float a, float b) { float r; asm("v_mul_f32 %0, %1, %2" : "=v"(r) : "v"(a), "v"(b)); return r; }
__device__ __forceinline__ float fadd_s(float a, float b) { float r; asm("v_add_f32 %0, %1, %2" : "=v"(r) : "v"(a), "v"(b)); return r; }
__device__ __forceinline__ float fsub_s(float a, float b) { float r; asm("v_sub_f32 %0, %1, %2" : "=v"(r) : "v"(a), "v"(b)); return r; }

// ---------------------------------------------------------------------------
// Threefry-2x32, key = (0, 42), partitionable path.
// ---------------------------------------------------------------------------
__device__ __forceinline__ unsigned tf_bits(unsigned lo) {
  const unsigned ks0 = 0u, ks1 = 42u, ks2 = 0x1BD11BF0u;
  unsigned x0 = 0u + ks0;
  unsigned x1 = lo + ks1;
#define TFR(r) { x0 += x1; x1 = (x1 << r) | (x1 >> (32 - r)); x1 ^= x0; }
  TFR(13) TFR(15) TFR(26) TFR(6)
  x0 += ks1; x1 += ks2 + 1u;
  TFR(17) TFR(29) TFR(16) TFR(24)
  x0 += ks2; x1 += ks0 + 2u;
  TFR(13) TFR(15) TFR(26) TFR(6)
  x0 += ks0; x1 += ks1 + 3u;
  TFR(17) TFR(29) TFR(16) TFR(24)
  x0 += ks1; x1 += ks2 + 4u;
  TFR(13) TFR(15) TFR(26) TFR(6)
  x0 += ks2; x1 += ks0 + 5u;
#undef TFR
  return x0 ^ x1;
}

// Exact fp32 -> 3x bf16 split (truncation)
__device__ __forceinline__ void split3(float v, unsigned& b1, unsigned& b2, unsigned& b3) {
  unsigned u1 = __float_as_uint(v) & 0xFFFF0000u;
  float r1 = v - __uint_as_float(u1);
  unsigned u2 = __float_as_uint(r1) & 0xFFFF0000u;
  float r2 = r1 - __uint_as_float(u2);
  unsigned u3 = __float_as_uint(r2) & 0xFFFF0000u;
  b1 = u1 >> 16; b2 = u2 >> 16; b3 = u3 >> 16;
}

__device__ __forceinline__ unsigned short planeOf(float v, int s) {
  unsigned u1 = __float_as_uint(v) & 0xFFFF0000u;
  if (s == 0) return (unsigned short)(u1 >> 16);
  float r1 = v - __uint_as_float(u1);
  unsigned u2 = __float_as_uint(r1) & 0xFFFF0000u;
  if (s == 1) return (unsigned short)(u2 >> 16);
  float r2 = r1 - __uint_as_float(u2);
  return (unsigned short)((__float_as_uint(r2) & 0xFFFF0000u) >> 16);
}

// 6-product split accumulation (drops terms <= 2^-27 relative)
#define MF6(A0, A1, A2, Bv0, Bv1, Bv2, ACC)                                   \
  ACC = __builtin_amdgcn_mfma_f32_16x16x32_bf16(A0, Bv0, ACC, 0, 0, 0);       \
  ACC = __builtin_amdgcn_mfma_f32_16x16x32_bf16(A0, Bv1, ACC, 0, 0, 0);       \
  ACC = __builtin_amdgcn_mfma_f32_16x16x32_bf16(A1, Bv0, ACC, 0, 0, 0);       \
  ACC = __builtin_amdgcn_mfma_f32_16x16x32_bf16(A0, Bv2, ACC, 0, 0, 0);       \
  ACC = __builtin_amdgcn_mfma_f32_16x16x32_bf16(A1, Bv1, ACC, 0, 0, 0);       \
  ACC = __builtin_amdgcn_mfma_f32_16x16x32_bf16(A2, Bv0, ACC, 0, 0, 0);

// ---------------------------------------------------------------------------
// Setup: W1/W2 split planes, centroid norms, centroid split planes.
// ---------------------------------------------------------------------------
__global__ void k_setup(const float* __restrict__ W1, const float* __restrict__ W2,
                        const float* __restrict__ cen,
                        unsigned short* __restrict__ Wg1, unsigned short* __restrict__ Wg2,
                        unsigned short* __restrict__ cen3, float* __restrict__ ccbuf) {
  int bi = blockIdx.x, tid = threadIdx.x;
  if (bi < 144) {
    const float* W; unsigned short* Wg; int nk, s, ks, g;
    if (bi < 48) { W = W1; Wg = Wg1; nk = 4; s = bi >> 4; ks = (bi >> 2) & 3; g = bi & 3; }
    else { int t = bi - 48; W = W2; Wg = Wg2; nk = 8; s = t >> 5; ks = (t >> 2) & 7; g = t & 3; }
    int n = tid;
    bf16x8 hv;
#pragma unroll
    for (int jj = 0; jj < 8; ++jj) {
      float v = W[(size_t)(ks * 32 + g * 8 + jj) * 256 + n];
      hv[jj] = (short)planeOf(v, s);
    }
    *(bf16x8*)&Wg[((((size_t)s * nk + ks) * 4 + g) * 256 + n) * 8] = hv;
  } else if (bi == 144) {
    int k = tid >> 3, l8 = tid & 7;
    float s = 0.0f;
    for (int m = 0; m < 32; ++m) { float v = cen[k * 256 + l8 + 8 * m]; s += v * v; }
#pragma unroll
    for (int d = 1; d < 8; d <<= 1) s += __shfl_xor(s, d, 64);
    if (l8 == 0) ccbuf[k] = s;
  } else {
    int s = bi - 145;
    for (int u = 0; u < 4; ++u) {
      int idx = tid + 256 * u;
      int ks = idx >> 7, c = (idx >> 6) & 1, rem = idx & 63;
      int l15v = rem >> 2, lgv = rem & 3;
      bf16x8 hv;
#pragma unroll
      for (int jj = 0; jj < 8; ++jj)
        hv[jj] = (short)planeOf(cen[(size_t)(16 * c + l15v) * 256 + 32 * ks + 8 * lgv + jj], s);
      *(bf16x8*)&cen3[(size_t)s * 8192 + (size_t)idx * 8] = hv;
    }
  }
}

// ---------------------------------------------------------------------------
// Layer core (global->global): out = relu(maskS * (Ahat @ (A @ W) + biaS)).
// Identical MFMA/split arithmetic to rounds 5-7.
// ---------------------------------------------------------------------------
__device__ __forceinline__ void layer_core(const float* __restrict__ A,
                                           const unsigned short* __restrict__ Wg,
                                           const unsigned short* AhP,
                                           const float* biaS, const float* maskS,
                                           float* __restrict__ out, int nk,
                                           char* U, int b, int tid) {
  unsigned short (*Ap)[3][2112] = (unsigned short(*)[3][2112])U;  // [2][3][2112]
  unsigned short (*Tbuf)[72]    = (unsigned short(*)[72])U;       // [256][72]
  int w = tid >> 6, l = tid & 63;
  int l15 = l & 15, lg = l >> 4;
  int K = nk * 32;
  int srow = tid >> 2, sg = tid & 3;
  const float* sp = A + (size_t)srow * K + sg * 8;

  // stage K-step 0 into buffer 0
  {
    float4 v0 = *(const float4*)(sp);
    float4 v1 = *(const float4*)(sp + 4);
    float vv[8] = {v0.x, v0.y, v0.z, v0.w, v1.x, v1.y, v1.z, v1.w};
    bf16x8 p1, p2, p3;
#pragma unroll
    for (int jj = 0; jj < 8; ++jj) {
      unsigned h1, h2, h3; split3(vv[jj], h1, h2, h3);
      p1[jj] = (short)h1; p2[jj] = (short)h2; p3[jj] = (short)h3;
    }
    int off = sg * 528 + srow * 8;
    *(bf16x8*)&Ap[0][0][off] = p1;
    *(bf16x8*)&Ap[0][1][off] = p2;
    *(bf16x8*)&Ap[0][2][off] = p3;
  }
  __syncthreads();

  f32x4 acc1[4][4];
#pragma unroll
  for (int q = 0; q < 4; ++q)
#pragma unroll
    for (int c = 0; c < 4; ++c) acc1[q][c] = (f32x4){0.f, 0.f, 0.f, 0.f};

  const size_t wss = (size_t)nk * 8192;

  for (int ks = 0; ks < nk; ++ks) {
    int cur = ks & 1;
    float4 v0, v1;
    bool pf = (ks + 1 < nk);
    if (pf) {
      v0 = *(const float4*)(sp + (ks + 1) * 32);
      v1 = *(const float4*)(sp + (ks + 1) * 32 + 4);
    }
    bf16x8 af[4][3];
#pragma unroll
    for (int q = 0; q < 4; ++q) {
      int off = lg * 528 + (16 * q + l15) * 8;
#pragma unroll
      for (int s = 0; s < 3; ++s) af[q][s] = *(const bf16x8*)&Ap[cur][s][off];
    }
#pragma unroll
    for (int c = 0; c < 4; ++c) {
      size_t wbase = (((size_t)ks * 4 + lg) * 256 + (64 * w + 16 * c + l15)) * 8;
      bf16x8 b0 = *(const bf16x8*)&Wg[wbase];
      bf16x8 b1 = *(const bf16x8*)&Wg[wbase + wss];
      bf16x8 b2 = *(const bf16x8*)&Wg[wbase + 2 * wss];
#pragma unroll
      for (int q = 0; q < 4; ++q) {
        MF6(af[q][0], af[q][1], af[q][2], b0, b1, b2, acc1[q][c]);
      }
    }
    if (pf) {
      float vv[8] = {v0.x, v0.y, v0.z, v0.w, v1.x, v1.y, v1.z, v1.w};
      bf16x8 p1, p2, p3;
#pragma unroll
      for (int jj = 0; jj < 8; ++jj) {
        unsigned h1, h2, h3; split3(vv[jj], h1, h2, h3);
        p1[jj] = (short)h1; p2[jj] = (short)h2; p3[jj] = (short)h3;
      }
      int off = sg * 528 + srow * 8;
      *(bf16x8*)&Ap[cur ^ 1][0][off] = p1;
      *(bf16x8*)&Ap[cur ^ 1][1][off] = p2;
      *(bf16x8*)&Ap[cur ^ 1][2][off] = p3;
    }
    __syncthreads();
  }

  // GEMM#2 phased over T split-planes sB; product budget nA = 3 - sB.
  f32x4 acc2[4][4];
#pragma unroll
  for (int q = 0; q < 4; ++q)
#pragma unroll
    for (int c = 0; c < 4; ++c) acc2[q][c] = (f32x4){0.f, 0.f, 0.f, 0.f};

#pragma unroll
  for (int sB = 0; sB < 3; ++sB) {
    const int nA = 3 - sB;
    __syncthreads();
#pragma unroll
    for (int q = 0; q < 4; ++q)
#pragma unroll
      for (int c = 0; c < 4; ++c) {
        u16x4 pv;
#pragma unroll
        for (int r = 0; r < 4; ++r) pv[r] = planeOf(acc1[q][c][r], sB);
        *(u16x4*)&Tbuf[64 * w + 16 * c + l15][16 * q + 4 * lg] = pv;
      }
    __syncthreads();
#pragma unroll
    for (int mt = 0; mt < 2; ++mt) {
      bf16x8 bf[4];
#pragma unroll
      for (int c = 0; c < 4; ++c)
        bf[c] = *(const bf16x8*)&Tbuf[64 * w + 16 * c + l15][32 * mt + 8 * lg];
#pragma unroll
      for (int q2 = 0; q2 < 4; ++q2) {
        bf16x8 afr[3];
#pragma unroll
        for (int sA = 0; sA < 3; ++sA)
          if (sA < nA)
            afr[sA] = *(const bf16x8*)&AhP[((((size_t)(sA * 2 + mt) * 4 + q2) * 4 + lg) * 16 + l15) * 8];
#pragma unroll
        for (int c = 0; c < 4; ++c)
#pragma unroll
          for (int sA = 0; sA < 3; ++sA)
            if (sA < nA)
              acc2[q2][c] = __builtin_amdgcn_mfma_f32_16x16x32_bf16(afr[sA], bf[c], acc2[q2][c], 0, 0, 0);
      }
    }
  }

  // epilogue: (acc + bias) * mask, relu -> global
#pragma unroll
  for (int q2 = 0; q2 < 4; ++q2) {
#pragma unroll
    for (int c = 0; c < 4; ++c) {
      int n = 64 * w + 16 * c + l15;
      float bv = biaS[n];
#pragma unroll
      for (int r = 0; r < 4; ++r) {
        int row = 16 * q2 + 4 * lg + r;
        float val = (acc2[q2][c][r] + bv) * maskS[row];
        out[((size_t)b * 64 + row) * 256 + n] = fmaxf(val, 0.0f);
      }
    }
  }
}

// ---------------------------------------------------------------------------
// Fused prep + layer1 + layer2.  63 KB LDS -> 2 blocks/CU, all 512 resident.
// ---------------------------------------------------------------------------
__global__ __launch_bounds__(256, 2) void k_fused(
    const float* __restrict__ x, const float* __restrict__ adj,
    const void* __restrict__ mp,
    const float* __restrict__ b1v, const float* __restrict__ b2v,
    const unsigned short* __restrict__ Wg1, const unsigned short* __restrict__ Wg2,
    unsigned long long* __restrict__ nbr, float* __restrict__ maskf,
    float* __restrict__ bufA, float* __restrict__ bufB) {
  __shared__ unsigned short AhP[12288];      // 24.6 KB
  __shared__ float biaS[256];
  __shared__ float maskS[64];
  __shared__ int s_ni, s_nf;
  __shared__ __align__(16) char U[36864];    // union: prep 33.3K / layers 36.9K

  int b = blockIdx.x, tid = threadIdx.x;

  // ===== phase 0: prep =====
  {
    float* adjS = (float*)U;
    float (*AhS)[65] = (float(*)[65])(U + 16384);
    float* dis = (float*)(U + 33024);
    if (tid == 0) { s_ni = 0; s_nf = 0; }
    const float* ab = adj + (size_t)b * 4096;
    for (int i = tid; i < 4096; i += 256) adjS[i] = ab[i];
    {
      const unsigned* wp = (const unsigned*)mp;
      int ni = 0, nf = 0;
      for (int i = tid; i < 2048; i += 256) {
        unsigned v = wp[i];
        if (v > 1u) ni = 1;
        if (v != 0u && v != 0x3f800000u) nf = 1;
      }
      if (ni) atomicOr(&s_ni, 1);
      if (nf) atomicOr(&s_nf, 1);
    }
    biaS[tid] = b1v[tid];
    __syncthreads();
    if (tid < 64) {
      float s = 0.0f;
      unsigned long long m = 0ull;
      for (int j = 0; j < 64; ++j) {
        float v = adjS[j * 64 + tid];          // symmetric
        s += (j == tid) ? (v + 1.0f) : v;
        if (v != 0.0f) m |= (1ull << j);
      }
      dis[tid] = 1.0f / sqrtf(fmaxf(s, 1.0f));
      nbr[b * 64 + tid] = m;
      int fl = s_ni ? (s_nf ? 2 : 1) : 0;
      int i = b * 64 + tid;
      float r;
      if (fl == 0)      r = ((const int*)mp)[i] ? 1.0f : 0.0f;
      else if (fl == 1) r = (((const float*)mp)[i] != 0.0f) ? 1.0f : 0.0f;
      else              r = ((const unsigned char*)mp)[i] ? 1.0f : 0.0f;
      maskS[tid] = r;
      maskf[i] = r;
    }
    __syncthreads();
    for (int i = tid; i < 4096; i += 256) {
      int r = i >> 6, c = i & 63;
      float a = adjS[i] + ((r == c) ? 1.0f : 0.0f);
      AhS[r][c] = (dis[r] * a) * dis[c];
    }
    __syncthreads();
    for (int ch = tid; ch < 1536; ch += 256) {
      int l15v = ch & 15, lgv = (ch >> 4) & 3, q2 = (ch >> 6) & 3, mt = (ch >> 8) & 1, s = ch >> 9;
      bf16x8 hv;
#pragma unroll
      for (int jj = 0; jj < 8; ++jj)
        hv[jj] = (short)planeOf(AhS[16 * q2 + l15v][32 * mt + 8 * lgv + jj], s);
      *(bf16x8*)&AhP[(size_t)ch * 8] = hv;
    }
    __syncthreads();
  }

  // ===== phase 1: layer1 (x -> bufA) =====
  layer_core(x + (size_t)b * 64 * 128, Wg1, AhP, biaS, maskS, bufA, 4, U, b, tid);
  __syncthreads();
  biaS[tid] = b2v[tid];

  // ===== phase 2: layer2 (bufA -> bufB) =====
  layer_core(bufA + (size_t)b * 64 * 256, Wg2, AhP, biaS, maskS, bufB, 8, U, b, tid);
}

// ---------------------------------------------------------------------------
// cdist + softmin + Gumbel-max sampling + per-wave CC/newadj/newx/gp/lab.
// cdist structure identical to round 6; fp bits pinned at the 3 contractable
// spots (hh accumulation, d2, sampling u).
// ---------------------------------------------------------------------------
__global__ __launch_bounds__(256) void k_cdsp(const float* __restrict__ h,
                                              const unsigned short* __restrict__ cen3,
                                              const float* __restrict__ ccbuf,
                                              const float* __restrict__ maskf,
                                              const unsigned long long* __restrict__ nbr,
                                              float* __restrict__ out_newx,
                                              float* __restrict__ out_newadj,
                                              float* __restrict__ out_gp,
                                              float* __restrict__ out_lab) {
  __shared__ float hS[16384];          // 64 KB, rows XOR-swizzled by ((row&7)<<4)
  __shared__ float Dred[4][64][36];    // 36.9 KB (reused as newadj bitmap in phase 4)
  __shared__ float hhp[64][4];
  __shared__ float lgp[64][33];
  __shared__ float mxs[64], lgden[64];
  __shared__ int concS[4][64];
  __shared__ float ppS[4][64];
  __shared__ int labFS[4][64];

  int b = blockIdx.x, tid = threadIdx.x;
  int w = tid >> 6, l = tid & 63, l15 = l & 15, lg = l >> 4;
  const float* hb = h + (size_t)b * 16384;

#pragma unroll
  for (int i = 0; i < 16; ++i) {
    int g = tid + 256 * i;
    float4 v = *(const float4*)&hb[(size_t)g * 4];
    int row = g >> 6;
    int fb = ((g & 63) * 16) ^ ((row & 7) << 4);
    *(float4*)((char*)&hS[row * 256] + fb) = v;
  }
  __syncthreads();

#define LD4(row, fbyte) (*(const float4*)((const char*)&hS[(row) * 256] + ((fbyte) ^ (((row) & 7) << 4))))

  {
    int row = tid & 63, qt = tid >> 6;
    float s = 0.0f;
    for (int u = 0; u < 16; ++u) {
      float4 v = LD4(row, qt * 256 + u * 16);
      float t = fadd_s(fadd_s(fadd_s(fmul_s(v.x, v.x), fmul_s(v.y, v.y)), fmul_s(v.z, v.z)), fmul_s(v.w, v.w));
      s = fadd_s(s, t);
    }
    hhp[row][qt] = s;
  }

  f32x4 acc[4][2];
#pragma unroll
  for (int qt = 0; qt < 4; ++qt)
#pragma unroll
    for (int c = 0; c < 2; ++c) acc[qt][c] = (f32x4){0.f, 0.f, 0.f, 0.f};

#pragma unroll
  for (int ks2 = 0; ks2 < 2; ++ks2) {
    int ks = 2 * w + ks2;
#pragma unroll
    for (int qt = 0; qt < 4; ++qt) {
      int row = 16 * qt + l15;
      int fb = (32 * ks + 8 * lg) * 4;
      float4 v0 = LD4(row, fb);
      float4 v1 = LD4(row, fb + 16);
      float vv[8] = {v0.x, v0.y, v0.z, v0.w, v1.x, v1.y, v1.z, v1.w};
      bf16x8 a0, a1, a2;
#pragma unroll
      for (int jj = 0; jj < 8; ++jj) {
        unsigned h1, h2, h3; split3(vv[jj], h1, h2, h3);
        a0[jj] = (short)h1; a1[jj] = (short)h2; a2[jj] = (short)h3;
      }
#pragma unroll
      for (int c = 0; c < 2; ++c) {
        const unsigned short* cb = cen3 + ((size_t)(ks * 2 + c) * 64 + l15 * 4 + lg) * 8;
        bf16x8 b0 = *(const bf16x8*)cb;
        bf16x8 b1 = *(const bf16x8*)(cb + 8192);
        bf16x8 b2 = *(const bf16x8*)(cb + 16384);
        MF6(a0, a1, a2, b0, b1, b2, acc[qt][c]);
      }
    }
  }

#pragma unroll
  for (int qt = 0; qt < 4; ++qt)
#pragma unroll
    for (int c = 0; c < 2; ++c)
#pragma unroll
      for (int r = 0; r < 4; ++r)
        Dred[w][16 * qt + 4 * lg + r][16 * c + l15] = acc[qt][c][r];
  __syncthreads();

  {
    int n = tid >> 2, kq = tid & 3;
    float hh = (hhp[n][0] + hhp[n][1]) + (hhp[n][2] + hhp[n][3]);
#pragma unroll
    for (int j = 0; j < 8; ++j) {
      int k = kq * 8 + j;
      float dot = (Dred[0][n][k] + Dred[1][n][k]) + (Dred[2][n][k] + Dred[3][n][k]);
      float d2 = fsub_s(fadd_s(hh, ccbuf[k]), fmul_s(2.0f, dot));
      lgp[n][k] = -10.0f * sqrtf(fmaxf(d2, 1e-12f));
    }
  }
  __syncthreads();

  if (tid < 64) {
    float mx = -1e30f;
    for (int k = 0; k < 32; ++k) mx = fmaxf(mx, lgp[tid][k]);
    float den = 0.0f;
    for (int k = 0; k < 32; ++k) den += expf(lgp[tid][k] - mx);
    mxs[tid] = mx; lgden[tid] = logf(den);
  }
  __syncthreads();
  for (int p = tid; p < 2048; p += 256) {
    int n = p >> 5, k = p & 31;
    lgp[n][k] = (lgp[n][k] - mxs[n]) - lgden[n];
  }
  __syncthreads();

  {
    int hw = tid >> 5, k = tid & 31;
    for (int pass = 0; pass < 8; ++pass) {
      int n = hw * 8 + pass;
      float lp = lgp[n][k];
#pragma unroll
      for (int s4 = 0; s4 < 4; ++s4) {
        unsigned flat = (unsigned)(s4 * 32768 + b * 64 + n) * 32u + (unsigned)k;
        unsigned bits = tf_bits(flat);
        float fu = __uint_as_float((bits >> 9) | 0x3f800000u) - 1.0f;
        float u = fmaxf(TINYF, fadd_s(fmul_s(fu, 1.0f - TINYF), TINYF));
        float g = -logf(-logf(u));
        float v = lp + g;
        int bi = k;
#pragma unroll
        for (int d = 1; d < 32; d <<= 1) {      // max, first-index ties
          float ov = __shfl_xor(v, d, 32);
          int oi = __shfl_xor(bi, d, 32);
          if (ov > v || (ov == v && oi < bi)) { v = ov; bi = oi; }
        }
        if (k == 0) {
          concS[s4][n] = bi;
          ppS[s4][n] = expf(lgp[n][bi]);
        }
      }
    }
  }
  __syncthreads();

  // ===== phase 4: per-wave (sample = wave) CC + outputs =====
  {
    unsigned char (*o)[4096] = (unsigned char(*)[4096])Dred;
    int s = w, lane = l;
    int sbo = s * 512 + b;
    int c0 = concS[s][lane];
    bool mk = maskf[b * 64 + lane] != 0.0f;
    unsigned long long nb = nbr[b * 64 + lane];
    unsigned long long sm = 0ull;
    {
      unsigned long long t = nb;
      while (t) { int j = __ffsll(t) - 1; if (concS[s][j] == c0) sm |= (1ull << j); t &= t - 1; }
    }
    labFS[s][lane] = lane + 1;                  // wave-lockstep Jacobi fixpoint
    for (int it = 0; it < 64; ++it) {
      int m = labFS[s][lane];
      unsigned long long t = sm;
      while (t) { int j = __ffsll(t) - 1; m = min(m, labFS[s][j]); t &= t - 1; }
      bool ch = m < labFS[s][lane];
      if (ch) labFS[s][lane] = m;
      if (!__any(ch)) break;
    }
    int lf = mk ? labFS[s][lane] : 0;
    out_lab[(size_t)sbo * 64 + lane] = (float)lf;
    float pv = mk ? ppS[s][lane] : 1.0f;
#pragma unroll
    for (int d = 1; d < 64; d <<= 1) pv *= __shfl_xor(pv, d, 64);
    if (lane == 0) out_gp[sbo] = pv;
    labFS[s][lane] = lf;                        // final masked labels (lockstep)
    unsigned long long cm = 0ull;
    for (int j = 0; j < 64; ++j)
      if (labFS[s][j] == lane + 1) cm |= (1ull << j);
    // pooled adjacency (byte bitmap per sample)
    {
      unsigned* op = (unsigned*)o[s];
#pragma unroll
      for (int u = 0; u < 16; ++u) op[u * 64 + lane] = 0u;
      if (lf > 0) {
        unsigned long long t = nb;
        while (t) {
          int j = __ffsll(t) - 1; t &= t - 1;
          int lj = labFS[s][j];
          if (lj > 0) o[s][(lf - 1) * 64 + (lj - 1)] = 1;
        }
      }
      float* dA = out_newadj + (size_t)sbo * 4096;
#pragma unroll
      for (int u = 0; u < 16; ++u) {
        int base = u * 256 + lane * 4;
        fx4 v;
        v.x = o[s][base + 0] ? 1.0f : 0.0f;
        v.y = o[s][base + 1] ? 1.0f : 0.0f;
        v.z = o[s][base + 2] ? 1.0f : 0.0f;
        v.w = o[s][base + 3] ? 1.0f : 0.0f;
        __builtin_nontemporal_store(v, (fx4*)&dA[base]);
      }
    }
    // scatter-mean new_x from hS
    float* dX = out_newx + (size_t)sbo * 16384;
    for (int c = 0; c < 64; ++c) {
      unsigned long long m = __shfl(cm, c, 64);
      float4 acc4 = make_float4(0.f, 0.f, 0.f, 0.f);
      unsigned long long t = m;
      while (t) {
        int j = __ffsll(t) - 1; t &= t - 1;
        float4 v = LD4(j, lane * 16);
        acc4.x += v.x; acc4.y += v.y; acc4.z += v.z; acc4.w += v.w;
      }
      int cnt = __popcll(m);
      float cf = (float)(cnt > 0 ? cnt : 1);
      fx4 r;
      r.x = acc4.x / cf; r.y = acc4.y / cf; r.z = acc4.z / cf; r.w = acc4.w / cf;
      __builtin_nontemporal_store(r, (fx4*)&dX[(size_t)c * 256 + lane * 4]);
    }
  }
#undef LD4
}

// ---------------------------------------------------------------------------
extern "C" void kernel_launch(void* const* d_in, const int* in_sizes, int n_in,
                              void* d_out, int out_size, void* d_ws, size_t ws_size,
                              hipStream_t stream) {
  (void)in_sizes; (void)n_in; (void)out_size; (void)ws_size;
  const float* x   = (const float*)d_in[0];
  const float* adj = (const float*)d_in[1];
  const void*  mp  = d_in[2];
  const float* W1  = (const float*)d_in[3];
  const float* b1  = (const float*)d_in[4];
  const float* W2  = (const float*)d_in[5];
  const float* b2  = (const float*)d_in[6];
  const float* cen = (const float*)d_in[7];

  char* ws = (char*)d_ws;
  unsigned short* Wg1  = (unsigned short*)(ws + 0);          // 196,608
  unsigned short* Wg2  = (unsigned short*)(ws + 196608);     // 393,216
  unsigned short* cen3 = (unsigned short*)(ws + 589824);     // 49,152
  float* ccbuf         = (float*)(ws + 638976);              // 128
  unsigned long long* nbr = (unsigned long long*)(ws + 655360);  // 262,144
  float* maskf         = (float*)(ws + 917504);              // 131,072
  float* bufA          = (float*)(ws + 2097152);             // 33,554,432 (h1)
  float* bufB          = (float*)(ws + 37748736);            // 33,554,432 (h)

  float* out        = (float*)d_out;
  float* out_newx   = out;                 // 2048*64*256
  float* out_newadj = out + 33554432;      // 2048*64*64
  float* out_gp     = out + 41943040;      // 2048
  float* out_lab    = out + 41945088;      // 2048*64

  hipLaunchKernelGGL(k_setup, dim3(148), dim3(256), 0, stream, W1, W2, cen, Wg1, Wg2, cen3, ccbuf);
  hipLaunchKernelGGL(k_fused, dim3(512), dim3(256), 0, stream, x, adj, mp, b1, b2,
                     Wg1, Wg2, nbr, maskf, bufA, bufB);
  hipLaunchKernelGGL(k_cdsp,  dim3(512), dim3(256), 0, stream, bufB, cen3, ccbuf, maskf, nbr,
                     out_newx, out_newadj, out_gp, out_lab);
}

// Round 9
// 149.768 us; speedup vs baseline: 2.2278x; 1.1373x over previous
//
#include <hip/hip_runtime.h>

#define B_    512

static constexpr float TINYF = 1.17549435e-38f;
typedef float fx4  __attribute__((ext_vector_type(4)));
typedef short bf16x8 __attribute__((ext_vector_type(8)));
typedef float f32x4 __attribute__((ext_vector_type(4)));
typedef unsigned short u16x4 __attribute__((ext_vector_type(4)));

// Contraction-pinned fp32 ops (RN, no fma fusion possible across these).
__device__ __forceinline__ float fmul_s(float a, float b) { float r; asm("v_mul_f32 %0, %1, %2" : "=v"(r) : "v"(a), "v"(b)); return r; }
__device__ __forceinline__ float fadd_s(float a, float b) { float r; asm("v_add_f32 %0, %1, %2" : "=v"(r) : "v"(a), "v"(b)); return r; }
__device__ __forceinline__ float fsub_s(float a, float b) { float r; asm("v_sub_f32 %0, %1, %2" : "=v"(r) : "v"(a), "v"(b)); return r; }

// ---------------------------------------------------------------------------
// Threefry-2x32, key = (0, 42), partitionable path.
// ---------------------------------------------------------------------------
__device__ __forceinline__ unsigned tf_bits(unsigned lo) {
  const unsigned ks0 = 0u, ks1 = 42u, ks2 = 0x1BD11BF0u;
  unsigned x0 = 0u + ks0;
  unsigned x1 = lo + ks1;
#define TFR(r) { x0 += x1; x1 = (x1 << r) | (x1 >> (32 - r)); x1 ^= x0; }
  TFR(13) TFR(15) TFR(26) TFR(6)
  x0 += ks1; x1 += ks2 + 1u;
  TFR(17) TFR(29) TFR(16) TFR(24)
  x0 += ks2; x1 += ks0 + 2u;
  TFR(13) TFR(15) TFR(26) TFR(6)
  x0 += ks0; x1 += ks1 + 3u;
  TFR(17) TFR(29) TFR(16) TFR(24)
  x0 += ks1; x1 += ks2 + 4u;
  TFR(13) TFR(15) TFR(26) TFR(6)
  x0 += ks2; x1 += ks0 + 5u;
#undef TFR
  return x0 ^ x1;
}

// Exact fp32 -> 3x bf16 split (truncation)
__device__ __forceinline__ void split3(float v, unsigned& b1, unsigned& b2, unsigned& b3) {
  unsigned u1 = __float_as_uint(v) & 0xFFFF0000u;
  float r1 = v - __uint_as_float(u1);
  unsigned u2 = __float_as_uint(r1) & 0xFFFF0000u;
  float r2 = r1 - __uint_as_float(u2);
  unsigned u3 = __float_as_uint(r2) & 0xFFFF0000u;
  b1 = u1 >> 16; b2 = u2 >> 16; b3 = u3 >> 16;
}

__device__ __forceinline__ unsigned short planeOf(float v, int s) {
  unsigned u1 = __float_as_uint(v) & 0xFFFF0000u;
  if (s == 0) return (unsigned short)(u1 >> 16);
  float r1 = v - __uint_as_float(u1);
  unsigned u2 = __float_as_uint(r1) & 0xFFFF0000u;
  if (s == 1) return (unsigned short)(u2 >> 16);
  float r2 = r1 - __uint_as_float(u2);
  return (unsigned short)((__float_as_uint(r2) & 0xFFFF0000u) >> 16);
}

// 6-product split accumulation (drops terms <= 2^-27 relative)
#define MF6(A0, A1, A2, Bv0, Bv1, Bv2, ACC)                                   \
  ACC = __builtin_amdgcn_mfma_f32_16x16x32_bf16(A0, Bv0, ACC, 0, 0, 0);       \
  ACC = __builtin_amdgcn_mfma_f32_16x16x32_bf16(A0, Bv1, ACC, 0, 0, 0);       \
  ACC = __builtin_amdgcn_mfma_f32_16x16x32_bf16(A1, Bv0, ACC, 0, 0, 0);       \
  ACC = __builtin_amdgcn_mfma_f32_16x16x32_bf16(A0, Bv2, ACC, 0, 0, 0);       \
  ACC = __builtin_amdgcn_mfma_f32_16x16x32_bf16(A1, Bv1, ACC, 0, 0, 0);       \
  ACC = __builtin_amdgcn_mfma_f32_16x16x32_bf16(A2, Bv0, ACC, 0, 0, 0);

// ---------------------------------------------------------------------------
// Setup: W1/W2 split planes, centroid norms, centroid split planes.
// ---------------------------------------------------------------------------
__global__ void k_setup(const float* __restrict__ W1, const float* __restrict__ W2,
                        const float* __restrict__ cen,
                        unsigned short* __restrict__ Wg1, unsigned short* __restrict__ Wg2,
                        unsigned short* __restrict__ cen3, float* __restrict__ ccbuf) {
  int bi = blockIdx.x, tid = threadIdx.x;
  if (bi < 144) {
    const float* W; unsigned short* Wg; int nk, s, ks, g;
    if (bi < 48) { W = W1; Wg = Wg1; nk = 4; s = bi >> 4; ks = (bi >> 2) & 3; g = bi & 3; }
    else { int t = bi - 48; W = W2; Wg = Wg2; nk = 8; s = t >> 5; ks = (t >> 2) & 7; g = t & 3; }
    int n = tid;
    bf16x8 hv;
#pragma unroll
    for (int jj = 0; jj < 8; ++jj) {
      float v = W[(size_t)(ks * 32 + g * 8 + jj) * 256 + n];
      hv[jj] = (short)planeOf(v, s);
    }
    *(bf16x8*)&Wg[((((size_t)s * nk + ks) * 4 + g) * 256 + n) * 8] = hv;
  } else if (bi == 144) {
    int k = tid >> 3, l8 = tid & 7;
    float s = 0.0f;
    for (int m = 0; m < 32; ++m) { float v = cen[k * 256 + l8 + 8 * m]; s += v * v; }
#pragma unroll
    for (int d = 1; d < 8; d <<= 1) s += __shfl_xor(s, d, 64);
    if (l8 == 0) ccbuf[k] = s;
  } else {
    int s = bi - 145;
    for (int u = 0; u < 4; ++u) {
      int idx = tid + 256 * u;
      int ks = idx >> 7, c = (idx >> 6) & 1, rem = idx & 63;
      int l15v = rem >> 2, lgv = rem & 3;
      bf16x8 hv;
#pragma unroll
      for (int jj = 0; jj < 8; ++jj)
        hv[jj] = (short)planeOf(cen[(size_t)(16 * c + l15v) * 256 + 32 * ks + 8 * lgv + jj], s);
      *(bf16x8*)&cen3[(size_t)s * 8192 + (size_t)idx * 8] = hv;
    }
  }
}

// ---------------------------------------------------------------------------
// Layer core (global->global): out = relu(maskS * (Ahat @ (A @ W) + biaS)).
// ---------------------------------------------------------------------------
__device__ __forceinline__ void layer_core(const float* __restrict__ A,
                                           const unsigned short* __restrict__ Wg,
                                           const unsigned short* AhP,
                                           const float* biaS, const float* maskS,
                                           float* __restrict__ out, int nk,
                                           char* U, int b, int tid) {
  unsigned short (*Ap)[3][2112] = (unsigned short(*)[3][2112])U;  // [2][3][2112]
  unsigned short (*Tbuf)[72]    = (unsigned short(*)[72])U;       // [256][72]
  int w = tid >> 6, l = tid & 63;
  int l15 = l & 15, lg = l >> 4;
  int K = nk * 32;
  int srow = tid >> 2, sg = tid & 3;
  const float* sp = A + (size_t)srow * K + sg * 8;

  // stage K-step 0 into buffer 0
  {
    float4 v0 = *(const float4*)(sp);
    float4 v1 = *(const float4*)(sp + 4);
    float vv[8] = {v0.x, v0.y, v0.z, v0.w, v1.x, v1.y, v1.z, v1.w};
    bf16x8 p1, p2, p3;
#pragma unroll
    for (int jj = 0; jj < 8; ++jj) {
      unsigned h1, h2, h3; split3(vv[jj], h1, h2, h3);
      p1[jj] = (short)h1; p2[jj] = (short)h2; p3[jj] = (short)h3;
    }
    int off = sg * 528 + srow * 8;
    *(bf16x8*)&Ap[0][0][off] = p1;
    *(bf16x8*)&Ap[0][1][off] = p2;
    *(bf16x8*)&Ap[0][2][off] = p3;
  }
  __syncthreads();

  f32x4 acc1[4][4];
#pragma unroll
  for (int q = 0; q < 4; ++q)
#pragma unroll
    for (int c = 0; c < 4; ++c) acc1[q][c] = (f32x4){0.f, 0.f, 0.f, 0.f};

  const size_t wss = (size_t)nk * 8192;

  for (int ks = 0; ks < nk; ++ks) {
    int cur = ks & 1;
    float4 v0, v1;
    bool pf = (ks + 1 < nk);
    if (pf) {
      v0 = *(const float4*)(sp + (ks + 1) * 32);
      v1 = *(const float4*)(sp + (ks + 1) * 32 + 4);
    }
    bf16x8 af[4][3];
#pragma unroll
    for (int q = 0; q < 4; ++q) {
      int off = lg * 528 + (16 * q + l15) * 8;
#pragma unroll
      for (int s = 0; s < 3; ++s) af[q][s] = *(const bf16x8*)&Ap[cur][s][off];
    }
#pragma unroll
    for (int c = 0; c < 4; ++c) {
      size_t wbase = (((size_t)ks * 4 + lg) * 256 + (64 * w + 16 * c + l15)) * 8;
      bf16x8 b0 = *(const bf16x8*)&Wg[wbase];
      bf16x8 b1 = *(const bf16x8*)&Wg[wbase + wss];
      bf16x8 b2 = *(const bf16x8*)&Wg[wbase + 2 * wss];
#pragma unroll
      for (int q = 0; q < 4; ++q) {
        MF6(af[q][0], af[q][1], af[q][2], b0, b1, b2, acc1[q][c]);
      }
    }
    if (pf) {
      float vv[8] = {v0.x, v0.y, v0.z, v0.w, v1.x, v1.y, v1.z, v1.w};
      bf16x8 p1, p2, p3;
#pragma unroll
      for (int jj = 0; jj < 8; ++jj) {
        unsigned h1, h2, h3; split3(vv[jj], h1, h2, h3);
        p1[jj] = (short)h1; p2[jj] = (short)h2; p3[jj] = (short)h3;
      }
      int off = sg * 528 + srow * 8;
      *(bf16x8*)&Ap[cur ^ 1][0][off] = p1;
      *(bf16x8*)&Ap[cur ^ 1][1][off] = p2;
      *(bf16x8*)&Ap[cur ^ 1][2][off] = p3;
    }
    __syncthreads();
  }

  // GEMM#2 phased over T split-planes sB; product budget nA = 3 - sB.
  f32x4 acc2[4][4];
#pragma unroll
  for (int q = 0; q < 4; ++q)
#pragma unroll
    for (int c = 0; c < 4; ++c) acc2[q][c] = (f32x4){0.f, 0.f, 0.f, 0.f};

#pragma unroll
  for (int sB = 0; sB < 3; ++sB) {
    const int nA = 3 - sB;
    __syncthreads();
#pragma unroll
    for (int q = 0; q < 4; ++q)
#pragma unroll
      for (int c = 0; c < 4; ++c) {
        u16x4 pv;
#pragma unroll
        for (int r = 0; r < 4; ++r) pv[r] = planeOf(acc1[q][c][r], sB);
        *(u16x4*)&Tbuf[64 * w + 16 * c + l15][16 * q + 4 * lg] = pv;
      }
    __syncthreads();
#pragma unroll
    for (int mt = 0; mt < 2; ++mt) {
      bf16x8 bf[4];
#pragma unroll
      for (int c = 0; c < 4; ++c)
        bf[c] = *(const bf16x8*)&Tbuf[64 * w + 16 * c + l15][32 * mt + 8 * lg];
#pragma unroll
      for (int q2 = 0; q2 < 4; ++q2) {
        bf16x8 afr[3];
#pragma unroll
        for (int sA = 0; sA < 3; ++sA)
          if (sA < nA)
            afr[sA] = *(const bf16x8*)&AhP[((((size_t)(sA * 2 + mt) * 4 + q2) * 4 + lg) * 16 + l15) * 8];
#pragma unroll
        for (int c = 0; c < 4; ++c)
#pragma unroll
          for (int sA = 0; sA < 3; ++sA)
            if (sA < nA)
              acc2[q2][c] = __builtin_amdgcn_mfma_f32_16x16x32_bf16(afr[sA], bf[c], acc2[q2][c], 0, 0, 0);
      }
    }
  }

  // epilogue: (acc + bias) * mask, relu -> global
#pragma unroll
  for (int q2 = 0; q2 < 4; ++q2) {
#pragma unroll
    for (int c = 0; c < 4; ++c) {
      int n = 64 * w + 16 * c + l15;
      float bv = biaS[n];
#pragma unroll
      for (int r = 0; r < 4; ++r) {
        int row = 16 * q2 + 4 * lg + r;
        float val = (acc2[q2][c][r] + bv) * maskS[row];
        out[((size_t)b * 64 + row) * 256 + n] = fmaxf(val, 0.0f);
      }
    }
  }
}

// ---------------------------------------------------------------------------
// Fused prep + layer1 + layer2.  63 KB LDS -> 2 blocks/CU.
// ---------------------------------------------------------------------------
__global__ __launch_bounds__(256, 2) void k_fused(
    const float* __restrict__ x, const float* __restrict__ adj,
    const void* __restrict__ mp,
    const float* __restrict__ b1v, const float* __restrict__ b2v,
    const unsigned short* __restrict__ Wg1, const unsigned short* __restrict__ Wg2,
    unsigned long long* __restrict__ nbr, float* __restrict__ maskf,
    float* __restrict__ bufA, float* __restrict__ bufB) {
  __shared__ unsigned short AhP[12288];      // 24.6 KB
  __shared__ float biaS[256];
  __shared__ float maskS[64];
  __shared__ int s_ni, s_nf;
  __shared__ __align__(16) char U[36864];    // union: prep 33.3K / layers 36.9K

  int b = blockIdx.x, tid = threadIdx.x;

  // ===== phase 0: prep =====
  {
    float* adjS = (float*)U;
    float (*AhS)[65] = (float(*)[65])(U + 16384);
    float* dis = (float*)(U + 33024);
    if (tid == 0) { s_ni = 0; s_nf = 0; }
    const float* ab = adj + (size_t)b * 4096;
    for (int i = tid; i < 4096; i += 256) adjS[i] = ab[i];
    {
      const unsigned* wp = (const unsigned*)mp;
      int ni = 0, nf = 0;
      for (int i = tid; i < 2048; i += 256) {
        unsigned v = wp[i];
        if (v > 1u) ni = 1;
        if (v != 0u && v != 0x3f800000u) nf = 1;
      }
      if (ni) atomicOr(&s_ni, 1);
      if (nf) atomicOr(&s_nf, 1);
    }
    biaS[tid] = b1v[tid];
    __syncthreads();
    if (tid < 64) {
      float s = 0.0f;
      unsigned long long m = 0ull;
      for (int j = 0; j < 64; ++j) {
        float v = adjS[j * 64 + tid];          // symmetric
        s += (j == tid) ? (v + 1.0f) : v;
        if (v != 0.0f) m |= (1ull << j);
      }
      dis[tid] = 1.0f / sqrtf(fmaxf(s, 1.0f));
      nbr[b * 64 + tid] = m;
      int fl = s_ni ? (s_nf ? 2 : 1) : 0;
      int i = b * 64 + tid;
      float r;
      if (fl == 0)      r = ((const int*)mp)[i] ? 1.0f : 0.0f;
      else if (fl == 1) r = (((const float*)mp)[i] != 0.0f) ? 1.0f : 0.0f;
      else              r = ((const unsigned char*)mp)[i] ? 1.0f : 0.0f;
      maskS[tid] = r;
      maskf[i] = r;
    }
    __syncthreads();
    for (int i = tid; i < 4096; i += 256) {
      int r = i >> 6, c = i & 63;
      float a = adjS[i] + ((r == c) ? 1.0f : 0.0f);
      AhS[r][c] = (dis[r] * a) * dis[c];
    }
    __syncthreads();
    for (int ch = tid; ch < 1536; ch += 256) {
      int l15v = ch & 15, lgv = (ch >> 4) & 3, q2 = (ch >> 6) & 3, mt = (ch >> 8) & 1, s = ch >> 9;
      bf16x8 hv;
#pragma unroll
      for (int jj = 0; jj < 8; ++jj)
        hv[jj] = (short)planeOf(AhS[16 * q2 + l15v][32 * mt + 8 * lgv + jj], s);
      *(bf16x8*)&AhP[(size_t)ch * 8] = hv;
    }
    __syncthreads();
  }

  // ===== phase 1: layer1 (x -> bufA) =====
  layer_core(x + (size_t)b * 64 * 128, Wg1, AhP, biaS, maskS, bufA, 4, U, b, tid);
  __syncthreads();
  biaS[tid] = b2v[tid];

  // ===== phase 2: layer2 (bufA -> bufB) =====
  layer_core(bufA + (size_t)b * 64 * 256, Wg2, AhP, biaS, maskS, bufB, 8, U, b, tid);
}

// ---------------------------------------------------------------------------
// cdist + softmin + Gumbel-max sampling + per-wave CC/newadj/newx/gp/lab.
// h read directly from global (L2-hot, written by k_fused).  49.9 KB LDS ->
// 3 blocks/CU.  Regular (L2-allocating) output stores.
// ---------------------------------------------------------------------------
__global__ __launch_bounds__(256, 3) void k_cdsp(const float* __restrict__ h,
                                                 const unsigned short* __restrict__ cen3,
                                                 const float* __restrict__ ccbuf,
                                                 const float* __restrict__ maskf,
                                                 const unsigned long long* __restrict__ nbr,
                                                 float* __restrict__ out_newx,
                                                 float* __restrict__ out_newadj,
                                                 float* __restrict__ out_gp,
                                                 float* __restrict__ out_lab) {
  __shared__ float Dred[4][64][36];    // 36.9 KB (reused as newadj bitmap in phase 4)
  __shared__ float hhp[64][4];
  __shared__ float lgp[64][33];
  __shared__ float mxs[64], lgden[64];
  __shared__ int concS[4][64];
  __shared__ float ppS[4][64];
  __shared__ int labFS[4][64];

  int b = blockIdx.x, tid = threadIdx.x;
  int w = tid >> 6, l = tid & 63, l15 = l & 15, lg = l >> 4;
  const float* hb = h + (size_t)b * 16384;

  // hh partials: thread t -> row t&63, f-quarter t>>6 (global reads, L2-hot)
  {
    int row = tid & 63, qt = tid >> 6;
    float s = 0.0f;
    for (int u = 0; u < 16; ++u) {
      float4 v = *(const float4*)&hb[row * 256 + qt * 64 + u * 4];
      float t = fadd_s(fadd_s(fadd_s(fmul_s(v.x, v.x), fmul_s(v.y, v.y)), fmul_s(v.z, v.z)), fmul_s(v.w, v.w));
      s = fadd_s(s, t);
    }
    hhp[row][qt] = s;
  }

  f32x4 acc[4][2];
#pragma unroll
  for (int qt = 0; qt < 4; ++qt)
#pragma unroll
    for (int c = 0; c < 2; ++c) acc[qt][c] = (f32x4){0.f, 0.f, 0.f, 0.f};

#pragma unroll
  for (int ks2 = 0; ks2 < 2; ++ks2) {
    int ks = 2 * w + ks2;
#pragma unroll
    for (int qt = 0; qt < 4; ++qt) {
      int row = 16 * qt + l15;
      float4 v0 = *(const float4*)&hb[row * 256 + 32 * ks + 8 * lg];
      float4 v1 = *(const float4*)&hb[row * 256 + 32 * ks + 8 * lg + 4];
      float vv[8] = {v0.x, v0.y, v0.z, v0.w, v1.x, v1.y, v1.z, v1.w};
      bf16x8 a0, a1, a2;
#pragma unroll
      for (int jj = 0; jj < 8; ++jj) {
        unsigned h1, h2, h3; split3(vv[jj], h1, h2, h3);
        a0[jj] = (short)h1; a1[jj] = (short)h2; a2[jj] = (short)h3;
      }
#pragma unroll
      for (int c = 0; c < 2; ++c) {
        const unsigned short* cb = cen3 + ((size_t)(ks * 2 + c) * 64 + l15 * 4 + lg) * 8;
        bf16x8 b0 = *(const bf16x8*)cb;
        bf16x8 b1 = *(const bf16x8*)(cb + 8192);
        bf16x8 b2 = *(const bf16x8*)(cb + 16384);
        MF6(a0, a1, a2, b0, b1, b2, acc[qt][c]);
      }
    }
  }

#pragma unroll
  for (int qt = 0; qt < 4; ++qt)
#pragma unroll
    for (int c = 0; c < 2; ++c)
#pragma unroll
      for (int r = 0; r < 4; ++r)
        Dred[w][16 * qt + 4 * lg + r][16 * c + l15] = acc[qt][c][r];
  __syncthreads();

  {
    int n = tid >> 2, kq = tid & 3;
    float hh = (hhp[n][0] + hhp[n][1]) + (hhp[n][2] + hhp[n][3]);
#pragma unroll
    for (int j = 0; j < 8; ++j) {
      int k = kq * 8 + j;
      float dot = (Dred[0][n][k] + Dred[1][n][k]) + (Dred[2][n][k] + Dred[3][n][k]);
      float d2 = fsub_s(fadd_s(hh, ccbuf[k]), fmul_s(2.0f, dot));
      lgp[n][k] = -10.0f * sqrtf(fmaxf(d2, 1e-12f));
    }
  }
  __syncthreads();

  if (tid < 64) {
    float mx = -1e30f;
    for (int k = 0; k < 32; ++k) mx = fmaxf(mx, lgp[tid][k]);
    float den = 0.0f;
    for (int k = 0; k < 32; ++k) den += expf(lgp[tid][k] - mx);
    mxs[tid] = mx; lgden[tid] = logf(den);
  }
  __syncthreads();
  for (int p = tid; p < 2048; p += 256) {
    int n = p >> 5, k = p & 31;
    lgp[n][k] = (lgp[n][k] - mxs[n]) - lgden[n];
  }
  __syncthreads();

  {
    int hw = tid >> 5, k = tid & 31;
    for (int pass = 0; pass < 8; ++pass) {
      int n = hw * 8 + pass;
      float lp = lgp[n][k];
#pragma unroll
      for (int s4 = 0; s4 < 4; ++s4) {
        unsigned flat = (unsigned)(s4 * 32768 + b * 64 + n) * 32u + (unsigned)k;
        unsigned bits = tf_bits(flat);
        float fu = __uint_as_float((bits >> 9) | 0x3f800000u) - 1.0f;
        float u = fmaxf(TINYF, fadd_s(fmul_s(fu, 1.0f - TINYF), TINYF));
        float g = -logf(-logf(u));
        float v = lp + g;
        int bi = k;
#pragma unroll
        for (int d = 1; d < 32; d <<= 1) {      // max, first-index ties
          float ov = __shfl_xor(v, d, 32);
          int oi = __shfl_xor(bi, d, 32);
          if (ov > v || (ov == v && oi < bi)) { v = ov; bi = oi; }
        }
        if (k == 0) {
          concS[s4][n] = bi;
          ppS[s4][n] = expf(lgp[n][bi]);
        }
      }
    }
  }
  __syncthreads();

  // ===== phase 4: per-wave (sample = wave) CC + outputs =====
  {
    unsigned char (*o)[4096] = (unsigned char(*)[4096])Dred;
    int s = w, lane = l;
    int sbo = s * 512 + b;
    int c0 = concS[s][lane];
    bool mk = maskf[b * 64 + lane] != 0.0f;
    unsigned long long nb = nbr[b * 64 + lane];
    unsigned long long sm = 0ull;
    {
      unsigned long long t = nb;
      while (t) { int j = __ffsll(t) - 1; if (concS[s][j] == c0) sm |= (1ull << j); t &= t - 1; }
    }
    labFS[s][lane] = lane + 1;                  // wave-lockstep Jacobi fixpoint
    for (int it = 0; it < 64; ++it) {
      int m = labFS[s][lane];
      unsigned long long t = sm;
      while (t) { int j = __ffsll(t) - 1; m = min(m, labFS[s][j]); t &= t - 1; }
      bool ch = m < labFS[s][lane];
      if (ch) labFS[s][lane] = m;
      if (!__any(ch)) break;
    }
    int lf = mk ? labFS[s][lane] : 0;
    out_lab[(size_t)sbo * 64 + lane] = (float)lf;
    float pv = mk ? ppS[s][lane] : 1.0f;
#pragma unroll
    for (int d = 1; d < 64; d <<= 1) pv *= __shfl_xor(pv, d, 64);
    if (lane == 0) out_gp[sbo] = pv;
    labFS[s][lane] = lf;                        // final masked labels (lockstep)
    unsigned long long cm = 0ull;
    for (int j = 0; j < 64; ++j)
      if (labFS[s][j] == lane + 1) cm |= (1ull << j);
    // pooled adjacency (byte bitmap per sample)
    {
      unsigned* op = (unsigned*)o[s];
#pragma unroll
      for (int u = 0; u < 16; ++u) op[u * 64 + lane] = 0u;
      if (lf > 0) {
        unsigned long long t = nb;
        while (t) {
          int j = __ffsll(t) - 1; t &= t - 1;
          int lj = labFS[s][j];
          if (lj > 0) o[s][(lf - 1) * 64 + (lj - 1)] = 1;
        }
      }
      float* dA = out_newadj + (size_t)sbo * 4096;
#pragma unroll
      for (int u = 0; u < 16; ++u) {
        int base = u * 256 + lane * 4;
        fx4 v;
        v.x = o[s][base + 0] ? 1.0f : 0.0f;
        v.y = o[s][base + 1] ? 1.0f : 0.0f;
        v.z = o[s][base + 2] ? 1.0f : 0.0f;
        v.w = o[s][base + 3] ? 1.0f : 0.0f;
        *(fx4*)&dA[base] = v;
      }
    }
    // scatter-mean new_x from global h (coalesced 1 KB lines, L2-hot)
    float* dX = out_newx + (size_t)sbo * 16384;
    for (int c = 0; c < 64; ++c) {
      unsigned long long m = __shfl(cm, c, 64);
      float4 acc4 = make_float4(0.f, 0.f, 0.f, 0.f);
      unsigned long long t = m;
      while (t) {
        int j = __ffsll(t) - 1; t &= t - 1;
        float4 v = *(const float4*)&hb[j * 256 + lane * 4];
        acc4.x += v.x; acc4.y += v.y; acc4.z += v.z; acc4.w += v.w;
      }
      int cnt = __popcll(m);
      float cf = (float)(cnt > 0 ? cnt : 1);
      fx4 r;
      r.x = acc4.x / cf; r.y = acc4.y / cf; r.z = acc4.z / cf; r.w = acc4.w / cf;
      *(fx4*)&dX[(size_t)c * 256 + lane * 4] = r;
    }
  }
}

// ---------------------------------------------------------------------------
extern "C" void kernel_launch(void* const* d_in, const int* in_sizes, int n_in,
                              void* d_out, int out_size, void* d_ws, size_t ws_size,
                              hipStream_t stream) {
  (void)in_sizes; (void)n_in; (void)out_size; (void)ws_size;
  const float* x   = (const float*)d_in[0];
  const float* adj = (const float*)d_in[1];
  const void*  mp  = d_in[2];
  const float* W1  = (const float*)d_in[3];
  const float* b1  = (const float*)d_in[4];
  const float* W2  = (const float*)d_in[5];
  const float* b2  = (const float*)d_in[6];
  const float* cen = (const float*)d_in[7];

  char* ws = (char*)d_ws;
  unsigned short* Wg1  = (unsigned short*)(ws + 0);          // 196,608
  unsigned short* Wg2  = (unsigned short*)(ws + 196608);     // 393,216
  unsigned short* cen3 = (unsigned short*)(ws + 589824);     // 49,152
  float* ccbuf         = (float*)(ws + 638976);              // 128
  unsigned long long* nbr = (unsigned long long*)(ws + 655360);  // 262,144
  float* maskf         = (float*)(ws + 917504);              // 131,072
  float* bufA          = (float*)(ws + 2097152);             // 33,554,432 (h1)
  float* bufB          = (float*)(ws + 37748736);            // 33,554,432 (h)

  float* out        = (float*)d_out;
  float* out_newx   = out;                 // 2048*64*256
  float* out_newadj = out + 33554432;      // 2048*64*64
  float* out_gp     = out + 41943040;      // 2048
  float* out_lab    = out + 41945088;      // 2048*64

  hipLaunchKernelGGL(k_setup, dim3(148), dim3(256), 0, stream, W1, W2, cen, Wg1, Wg2, cen3, ccbuf);
  hipLaunchKernelGGL(k_fused, dim3(512), dim3(256), 0, stream, x, adj, mp, b1, b2,
                     Wg1, Wg2, nbr, maskf, bufA, bufB);
  hipLaunchKernelGGL(k_cdsp,  dim3(512), dim3(256), 0, stream, bufB, cen3, ccbuf, maskf, nbr,
                     out_newx, out_newadj, out_gp, out_lab);
}